// Round 6
// baseline (359.194 us; speedup 1.0000x reference)
//
#include <hip/hip_runtime.h>
#include <hip/hip_bf16.h>

#define N_BUS 200000
#define N_GEN 50000
#define E_BB 1600000
#define E_GB 400000
#define E_BG 400000
#define H 32
#define NBINS 1024   // max coarse buckets (>= ceil(200000/256) = 782)
#define EPT 16       // edges per thread in partition (chunk = 4096)

#define NBK_BUS 782      // buckets for bus-dst relations
#define NBK_GEN 196      // buckets for gen-dst relations
#define CAP_BB 2560      // mean 2046 + >11 sigma
#define CAP_GB 768       // mean 512  + >11 sigma
#define CAP_BG 2560      // mean 2041 + >11 sigma

#define NB_PART_BB 391   // ceil(E_BB/4096)
#define NB_PART_GB 98
#define NB_PART_BG 98
#define NB_PART_ALL 587
#define NB_PREP 32
#define NB_TF_BUS 782
#define NB_TF_GEN 196
#define NB_TF_ALL 978
#define NB_FINE_ALL 1760 // 2*NBK_BUS + NBK_GEN
#define NB_PL_BUS 6250   // ceil(N_BUS/32)
#define NB_PL_GEN 1563

#define PNONE 0xFFFFFFFFu

typedef __attribute__((ext_vector_type(8))) short short8;
typedef __attribute__((ext_vector_type(4))) float floatx4;

__device__ inline unsigned short f2bf(float f) {
    __hip_bfloat16 h = __float2bfloat16(f);   // RNE
    return *reinterpret_cast<unsigned short*>(&h);
}
__device__ inline float bf2f(unsigned short u) {
    return __uint_as_float(((unsigned)u) << 16);
}

// ---------------------------------------------------------------------------
// Zero the 3 contiguous cursor arrays.
__global__ __launch_bounds__(256) void zero_kernel(unsigned* __restrict__ p) {
    int i = blockIdx.x * 256 + threadIdx.x;
    if (i < 3 * NBINS) p[i] = 0u;
}

// ---------------------------------------------------------------------------
// Partition into fixed-capacity buckets. Block-local LDS counting sort so the
// global pairs[] write streams out in position order. pairs = (dst&255)<<24|src.
__device__ __forceinline__ void part_body(int blk, const int* __restrict__ src,
                                          const int* __restrict__ dst, int nE,
                                          unsigned* __restrict__ cnt_g, int CAP,
                                          unsigned* __restrict__ pairs) {
    __shared__ unsigned hist[NBINS];
    __shared__ unsigned base[NBINS];    // global target base per bin
    __shared__ unsigned sbase[NBINS];   // block-local exclusive scan per bin
    __shared__ unsigned sh[256];
    __shared__ unsigned pairv[256 * EPT];
    __shared__ unsigned short bid[256 * EPT];
    const int tid = threadIdx.x;
    const int cbase = blk * (256 * EPT);
    const int total = min(256 * EPT, nE - cbase);

    unsigned es[EPT], ed[EPT];
#pragma unroll
    for (int q = 0; q < EPT; q++) {
        int i = cbase + q * 256 + tid;
        if (i < nE) { es[q] = (unsigned)src[i]; ed[q] = (unsigned)dst[i]; }
        else ed[q] = PNONE;
    }
    for (int i = tid; i < NBINS; i += 256) hist[i] = 0;
    __syncthreads();
#pragma unroll
    for (int q = 0; q < EPT; q++)
        if (ed[q] != PNONE) atomicAdd(&hist[ed[q] >> 8], 1u);
    __syncthreads();

    // Block-local exclusive scan over the 1024 bins (4 bins/thread).
    unsigned h4[4];
    unsigned s = 0;
#pragma unroll
    for (int k2 = 0; k2 < 4; k2++) { h4[k2] = hist[tid * 4 + k2]; s += h4[k2]; }
    sh[tid] = s;
    __syncthreads();
#pragma unroll
    for (int d = 1; d < 256; d <<= 1) {
        unsigned t = (tid >= d) ? sh[tid - d] : 0u;
        __syncthreads();
        sh[tid] += t;
        __syncthreads();
    }
    unsigned run = sh[tid] - s;
#pragma unroll
    for (int k2 = 0; k2 < 4; k2++) {
        int b = tid * 4 + k2;
        sbase[b] = run;
        base[b] = h4[k2] ? ((unsigned)b * CAP + atomicAdd(&cnt_g[b], h4[k2])) : 0u;
        hist[b] = 0;  // reuse as local cursor
        run += h4[k2];
    }
    __syncthreads();

    // Place pairs into the block-sorted LDS staging.
#pragma unroll
    for (int q = 0; q < EPT; q++) {
        if (ed[q] != PNONE) {
            unsigned b = ed[q] >> 8;
            unsigned off = atomicAdd(&hist[b], 1u);
            unsigned p = sbase[b] + off;
            pairv[p] = ((ed[q] & 255u) << 24) | es[q];
            bid[p] = (unsigned short)b;
        }
    }
    __syncthreads();

    // Stream out: consecutive p within a bucket -> consecutive global addr.
    for (int p = tid; p < total; p += 256) {
        unsigned b = bid[p];
        pairs[base[b] + ((unsigned)p - sbase[b])] = pairv[p];
    }
}

// ---------------------------------------------------------------------------
// Prep body (grid-striding over NB_PREP*256 threads): bf16 MFMA B-fragments +
// fused biases + fused head matrices.
__device__ __forceinline__ void prep_body(int pb,
    const float* __restrict__ l1_bb_Wl, const float* __restrict__ l1_bb_bl, const float* __restrict__ l1_bb_Wr,
    const float* __restrict__ l1_gb_Wl, const float* __restrict__ l1_gb_bl, const float* __restrict__ l1_gb_Wr,
    const float* __restrict__ l1_bg_Wl, const float* __restrict__ l1_bg_bl, const float* __restrict__ l1_bg_Wr,
    const float* __restrict__ l2_bb_Wl, const float* __restrict__ l2_bb_bl, const float* __restrict__ l2_bb_Wr,
    const float* __restrict__ l2_gb_Wl, const float* __restrict__ l2_gb_bl, const float* __restrict__ l2_gb_Wr,
    const float* __restrict__ l2_bg_Wl, const float* __restrict__ l2_bg_bl, const float* __restrict__ l2_bg_Wr,
    const float* __restrict__ lin0_bus_W, const float* __restrict__ lin0_bus_b,
    const float* __restrict__ linf_bus_W, const float* __restrict__ linf_bus_b,
    const float* __restrict__ lin0_gen_W, const float* __restrict__ lin0_gen_b,
    const float* __restrict__ linf_gen_W, const float* __restrict__ linf_gen_b,
    unsigned short* __restrict__ Wf1b, float* __restrict__ B1b,
    unsigned short* __restrict__ Wf1g, float* __restrict__ B1g,
    unsigned short* __restrict__ Wf2b, float* __restrict__ B2b,
    unsigned short* __restrict__ Wf2g, float* __restrict__ B2g,
    float* __restrict__ WeB, float* __restrict__ beB,
    float* __restrict__ WeG, float* __restrict__ beG)
{
    int t0 = pb * 256 + threadIdx.x;
    const int NT = NB_PREP * 256;

    // L1 bus: KT=2, NTN=6
    for (int f = t0; f < 2 * 6 * 64 * 8; f += NT) {
        int j = f & 7, l = (f >> 3) & 63, tile = f >> 9;
        int nt = tile % 6, kt = tile / 6;
        int k = kt * 32 + (l >> 4) * 8 + j, n = nt * 16 + (l & 15);
        float v;
        if (n < 32) v = l1_bb_Wl[k * 32 + n];
        else if (n < 64) v = l1_bg_Wl[k * 32 + n - 32];
        else v = l1_bb_Wr[k * 32 + n - 64] + l1_gb_Wr[k * 32 + n - 64];
        Wf1b[f] = f2bf(v);
    }
    // L1 gen: KT=2, NTN=4
    for (int f = t0; f < 2 * 4 * 64 * 8; f += NT) {
        int j = f & 7, l = (f >> 3) & 63, tile = f >> 9;
        int nt = tile % 4, kt = tile / 4;
        int k = kt * 32 + (l >> 4) * 8 + j, n = nt * 16 + (l & 15);
        float v = (n < 32) ? l1_gb_Wl[k * 32 + n] : l1_bg_Wr[k * 32 + n - 32];
        Wf1g[f] = f2bf(v);
    }
    // L2 bus: KT=1, NTN=6
    for (int f = t0; f < 6 * 64 * 8; f += NT) {
        int j = f & 7, l = (f >> 3) & 63, nt = f >> 9;
        int k = (l >> 4) * 8 + j, n = nt * 16 + (l & 15);
        float v;
        if (n < 32) v = l2_bb_Wl[k * 32 + n];
        else if (n < 64) v = l2_bg_Wl[k * 32 + n - 32];
        else v = l2_bb_Wr[k * 32 + n - 64] + l2_gb_Wr[k * 32 + n - 64];
        Wf2b[f] = f2bf(v);
    }
    // L2 gen: KT=1, NTN=4
    for (int f = t0; f < 4 * 64 * 8; f += NT) {
        int j = f & 7, l = (f >> 3) & 63, nt = f >> 9;
        int k = (l >> 4) * 8 + j, n = nt * 16 + (l & 15);
        float v = (n < 32) ? l2_gb_Wl[k * 32 + n] : l2_bg_Wr[k * 32 + n - 32];
        Wf2g[f] = f2bf(v);
    }
    if (t0 < 96) {
        B1b[t0] = (t0 < 64) ? 0.0f : l1_bb_bl[t0 - 64] + l1_gb_bl[t0 - 64];
        B2b[t0] = (t0 < 64) ? 0.0f : l2_bb_bl[t0 - 64] + l2_gb_bl[t0 - 64];
    }
    if (t0 < 64) {
        B1g[t0] = (t0 < 32) ? 0.0f : l1_bg_bl[t0 - 32];
        B2g[t0] = (t0 < 32) ? 0.0f : l2_bg_bl[t0 - 32];
    }
    // Fused head: bus We (32x4) + be(4); gen We (32x2) + be(2)
    if (t0 < 128) {
        int k = t0 >> 2, c = t0 & 3;
        float s = 0.0f;
        for (int m = 0; m < 32; m++) s += lin0_bus_W[k * 32 + m] * linf_bus_W[m * 4 + c];
        WeB[t0] = s;
    }
    if (t0 >= 128 && t0 < 132) {
        int c = t0 - 128;
        float s = linf_bus_b[c];
        for (int m = 0; m < 32; m++) s += lin0_bus_b[m] * linf_bus_W[m * 4 + c];
        beB[c] = s;
    }
    if (t0 >= 132 && t0 < 196) {
        int i = t0 - 132, k = i >> 1, c = i & 1;
        float s = 0.0f;
        for (int m = 0; m < 32; m++) s += lin0_gen_W[k * 32 + m] * linf_gen_W[m * 2 + c];
        WeG[i] = s;
    }
    if (t0 >= 196 && t0 < 198) {
        int c = t0 - 196;
        float s = linf_gen_b[c];
        for (int m = 0; m < 32; m++) s += lin0_gen_b[m] * linf_gen_W[m * 2 + c];
        beG[c] = s;
    }
}

// Merged [part | prep] launch.
__global__ __launch_bounds__(256) void prep_part_kernel(
    const int* __restrict__ sbb, const int* __restrict__ dbb, unsigned* __restrict__ cbb, unsigned* __restrict__ pbb,
    const int* __restrict__ sgb, const int* __restrict__ dgb, unsigned* __restrict__ cgb, unsigned* __restrict__ pgb,
    const int* __restrict__ sbg, const int* __restrict__ dbg, unsigned* __restrict__ cbg, unsigned* __restrict__ pbg,
    const float* __restrict__ l1_bb_Wl, const float* __restrict__ l1_bb_bl, const float* __restrict__ l1_bb_Wr,
    const float* __restrict__ l1_gb_Wl, const float* __restrict__ l1_gb_bl, const float* __restrict__ l1_gb_Wr,
    const float* __restrict__ l1_bg_Wl, const float* __restrict__ l1_bg_bl, const float* __restrict__ l1_bg_Wr,
    const float* __restrict__ l2_bb_Wl, const float* __restrict__ l2_bb_bl, const float* __restrict__ l2_bb_Wr,
    const float* __restrict__ l2_gb_Wl, const float* __restrict__ l2_gb_bl, const float* __restrict__ l2_gb_Wr,
    const float* __restrict__ l2_bg_Wl, const float* __restrict__ l2_bg_bl, const float* __restrict__ l2_bg_Wr,
    const float* __restrict__ lin0_bus_W, const float* __restrict__ lin0_bus_b,
    const float* __restrict__ linf_bus_W, const float* __restrict__ linf_bus_b,
    const float* __restrict__ lin0_gen_W, const float* __restrict__ lin0_gen_b,
    const float* __restrict__ linf_gen_W, const float* __restrict__ linf_gen_b,
    unsigned short* __restrict__ Wf1b, float* __restrict__ B1b,
    unsigned short* __restrict__ Wf1g, float* __restrict__ B1g,
    unsigned short* __restrict__ Wf2b, float* __restrict__ B2b,
    unsigned short* __restrict__ Wf2g, float* __restrict__ B2g,
    float* __restrict__ WeB, float* __restrict__ beB,
    float* __restrict__ WeG, float* __restrict__ beG)
{
    int b = blockIdx.x;
    if (b < NB_PART_BB) part_body(b, sbb, dbb, E_BB, cbb, CAP_BB, pbb);
    else if (b < NB_PART_BB + NB_PART_GB) part_body(b - NB_PART_BB, sgb, dgb, E_GB, cgb, CAP_GB, pgb);
    else if (b < NB_PART_ALL) part_body(b - NB_PART_BB - NB_PART_GB, sbg, dbg, E_BG, cbg, CAP_BG, pbg);
    else prep_body(b - NB_PART_ALL,
                   l1_bb_Wl, l1_bb_bl, l1_bb_Wr, l1_gb_Wl, l1_gb_bl, l1_gb_Wr,
                   l1_bg_Wl, l1_bg_bl, l1_bg_Wr, l2_bb_Wl, l2_bb_bl, l2_bb_Wr,
                   l2_gb_Wl, l2_gb_bl, l2_gb_Wr, l2_bg_Wl, l2_bg_bl, l2_bg_Wr,
                   lin0_bus_W, lin0_bus_b, linf_bus_W, linf_bus_b,
                   lin0_gen_W, lin0_gen_b, linf_gen_W, linf_gen_b,
                   Wf1b, B1b, Wf1g, B1g, Wf2b, B2b, Wf2g, B2g, WeB, beB, WeG, beG);
}

// ---------------------------------------------------------------------------
// Fine CSR: one block per bucket, LDS carved from shared buffer.
// rs[node] packed: (global row start << 9) | degree  (start < 2^21, deg < 512).
__device__ __forceinline__ void fine_body(int b, const unsigned* __restrict__ cnt_g, int CAP,
                                          const unsigned* __restrict__ pairs,
                                          unsigned* __restrict__ rs,
                                          unsigned* __restrict__ esrc, int nDst,
                                          char* __restrict__ lds) {
    unsigned* cnt = (unsigned*)lds;            // 1 KB
    unsigned* sh = (unsigned*)(lds + 1024);    // 1 KB
    unsigned* stg = (unsigned*)(lds + 2048);   // 10 KB (>= max CAP)
    const int tid = threadIdx.x;
    const unsigned start = (unsigned)b * CAP;
    const unsigned m = cnt_g[b];
    const unsigned end = start + m;

    cnt[tid] = 0;
    __syncthreads();
    for (unsigned k = start + tid; k < end; k += 256)
        atomicAdd(&cnt[pairs[k] >> 24], 1u);
    __syncthreads();
    unsigned c = cnt[tid];
    sh[tid] = c;
    __syncthreads();
#pragma unroll
    for (int d = 1; d < 256; d <<= 1) {
        unsigned t = (tid >= d) ? sh[tid - d] : 0u;
        __syncthreads();
        sh[tid] += t;
        __syncthreads();
    }
    int gd = b * 256 + tid;
    unsigned rowstart = start + sh[tid] - c;
    if (gd < nDst) rs[gd] = (rowstart << 9) | (c < 511u ? c : 511u);
    cnt[tid] = sh[tid] - c;  // block-local exclusive offset -> cursor
    __syncthreads();
    for (unsigned k = start + tid; k < end; k += 256) {
        unsigned p = pairs[k];
        unsigned off = atomicAdd(&cnt[p >> 24], 1u);
        stg[off] = p & 0x00FFFFFFu;
    }
    __syncthreads();
    for (unsigned p = tid; p < m; p += 256) esrc[start + p] = stg[p];
}

// ---------------------------------------------------------------------------
// Shared MFMA tail for the 256-row layer-1 transform.
template <int K, int NOUT, int XS>
__device__ __forceinline__ void mfma_tail(
    int rows, int base,
    const unsigned short* __restrict__ Wf, const float* __restrict__ bias,
    unsigned short* __restrict__ y0, unsigned short* __restrict__ y1, float* __restrict__ h,
    short* lx, float* lo)
{
    constexpr int KT = K / 32, NTN = NOUT / 16, NCH = NOUT / 32;
    constexpr int OS = 34;     // floats
    const int tid = threadIdx.x;
    const int w = tid >> 6, l = tid & 63, quad = l >> 4, ln = l & 15;

    // B fragments + bias
    short8 bf[KT][NTN];
    const short8* wf8 = (const short8*)Wf;
#pragma unroll
    for (int kt = 0; kt < KT; kt++)
#pragma unroll
        for (int nt = 0; nt < NTN; nt++)
            bf[kt][nt] = wf8[(kt * NTN + nt) * 64 + l];
    float bv[NTN];
#pragma unroll
    for (int nt = 0; nt < NTN; nt++) bv[nt] = bias[nt * 16 + ln];

    // ---- MFMA: wave w owns rows [w*64, w*64+64) ----
    floatx4 acc[4][NTN];
#pragma unroll
    for (int mt = 0; mt < 4; mt++)
#pragma unroll
        for (int nt = 0; nt < NTN; nt++) {
            floatx4 c0 = {bv[nt], bv[nt], bv[nt], bv[nt]};
            acc[mt][nt] = c0;
        }
#pragma unroll
    for (int mt = 0; mt < 4; mt++) {
        const int row = w * 64 + mt * 16 + ln;  // A[m = lane&15][k = quad*8+j]
#pragma unroll
        for (int kt = 0; kt < KT; kt++) {
            short8 af = *(const short8*)&lx[row * XS + kt * 32 + quad * 8];
#pragma unroll
            for (int nt = 0; nt < NTN; nt++)
                acc[mt][nt] = __builtin_amdgcn_mfma_f32_16x16x32_bf16(
                    af, bf[kt][nt], acc[mt][nt], 0, 0, 0);
        }
    }

    // ---- epilogue: per-32-col chunk LDS transpose -> coalesced stores ----
    // C/D layout: col = lane&15, row = quad*4 + reg.
#pragma unroll
    for (int c = 0; c < NCH; c++) {
        __syncthreads();
#pragma unroll
        for (int mt = 0; mt < 4; mt++)
#pragma unroll
            for (int d = 0; d < 2; d++) {
                int nt = 2 * c + d;
#pragma unroll
                for (int r = 0; r < 4; r++)
                    lo[(w * 64 + mt * 16 + quad * 4 + r) * OS + d * 16 + ln] = acc[mt][nt][r];
            }
        __syncthreads();
        const int T4 = rows * 8;
        if (c == NCH - 1) {  // h chunk, fp32
            float* og = h + (size_t)base * 32;
            for (int q = tid; q < T4; q += 256) {
                int r = q >> 3, cc = (q & 7) * 4;
                const float* p = &lo[r * OS + cc];
                *(float4*)(og + q * 4) = make_float4(p[0], p[1], p[2], p[3]);
            }
        } else {  // y chunk, bf16
            unsigned short* og = ((c == 0) ? y0 : y1) + (size_t)base * 32;
            for (int q = tid; q < T4; q += 256) {
                int r = q >> 3, cc = (q & 7) * 4;
                const float* p = &lo[r * OS + cc];
                short4 s4;
                s4.x = (short)f2bf(p[0]); s4.y = (short)f2bf(p[1]);
                s4.z = (short)f2bf(p[2]); s4.w = (short)f2bf(p[3]);
                *(short4*)(og + q * 4) = s4;
            }
        }
    }
}

// Node transform body: stage x from global fp32 -> bf16 (layer 1).
template <int K, int NOUT>
__device__ __forceinline__ void transform_body(
    int blk, const float* x, int n,
    const unsigned short* __restrict__ Wf, const float* __restrict__ bias,
    unsigned short* __restrict__ y0, unsigned short* __restrict__ y1, float* h,
    char* ldsraw)
{
    constexpr int XS = K + 8;  // shorts
    short* lx = (short*)ldsraw;
    const int tid = threadIdx.x;
    const int base = blk * 256;
    const int rows = min(256, n - base);

    {
        const float4* xg = (const float4*)(x + (size_t)base * K);
        const int T4 = rows * (K / 4);
        for (int q = tid; q < T4; q += 256) {
            float4 v = xg[q];
            int r = q / (K / 4), c = (q % (K / 4)) * 4;
            short4 s4;
            s4.x = (short)f2bf(v.x); s4.y = (short)f2bf(v.y);
            s4.z = (short)f2bf(v.z); s4.w = (short)f2bf(v.w);
            *(short4*)&lx[r * XS + c] = s4;
        }
    }
    __syncthreads();
    mfma_tail<K, NOUT, XS>(rows, base, Wf, bias, y0, y1, h, (short*)ldsraw, (float*)ldsraw);
}

// Merged [tf1 | fine] launch.
__global__ __launch_bounds__(256) void tf1_fine_kernel(
    const float* xb, const unsigned short* __restrict__ Wfb, const float* __restrict__ Bb,
    unsigned short* __restrict__ yb0, unsigned short* __restrict__ yb1, float* hb,
    const float* xg, const unsigned short* __restrict__ Wfg, const float* __restrict__ Bg,
    unsigned short* __restrict__ yg0, float* hg,
    const unsigned* __restrict__ cbb, const unsigned* __restrict__ pbb, unsigned* __restrict__ rsbb, unsigned* __restrict__ ebb,
    const unsigned* __restrict__ cgb, const unsigned* __restrict__ pgb, unsigned* __restrict__ rsgb, unsigned* __restrict__ egb,
    const unsigned* __restrict__ cbg, const unsigned* __restrict__ pbg, unsigned* __restrict__ rsbg, unsigned* __restrict__ ebg)
{
    constexpr int XB = 256 * (64 + 8) * 2, OB = 256 * 34 * 4;
    __shared__ __align__(16) char ldsraw[(XB > OB) ? XB : OB];
    int b = blockIdx.x;
    if (b < NB_TF_BUS)
        transform_body<64, 96>(b, xb, N_BUS, Wfb, Bb, yb0, yb1, hb, ldsraw);
    else if (b < NB_TF_ALL)
        transform_body<64, 64>(b - NB_TF_BUS, xg, N_GEN, Wfg, Bg, yg0, nullptr, hg, ldsraw);
    else {
        int f = b - NB_TF_ALL;
        if (f < NBK_BUS) fine_body(f, cbb, CAP_BB, pbb, rsbb, ebb, N_BUS, ldsraw);
        else if (f < 2 * NBK_BUS) fine_body(f - NBK_BUS, cgb, CAP_GB, pgb, rsgb, egb, N_BUS, ldsraw);
        else fine_body(f - 2 * NBK_BUS, cbg, CAP_BG, pbg, rsbg, ebg, N_GEN, ldsraw);
    }
}

// ---------------------------------------------------------------------------
// One relation's mean-aggregate into a float4 (cols j..j+3); 4-deep pipeline
// with next-quad index prefetch.
__device__ __forceinline__ void agg_one(
    unsigned u, const unsigned* __restrict__ e,
    const unsigned short* __restrict__ y, int j, float4& r)
{
    unsigned k0 = u >> 9;
    unsigned c = u & 511u;
    unsigned k1 = k0 + c;
    float4 a0 = make_float4(0.f, 0.f, 0.f, 0.f);
    float4 a1 = a0, a2 = a0, a3 = a0;
    unsigned k = k0;
    if (k + 4 <= k1) {
        unsigned s0 = e[k], s1 = e[k + 1], s2 = e[k + 2], s3 = e[k + 3];
        for (; k + 8 <= k1; k += 4) {
            unsigned t0 = e[k + 4], t1 = e[k + 5], t2 = e[k + 6], t3 = e[k + 7];
            ushort4 v0 = *(const ushort4*)(y + (size_t)s0 * H + j);
            ushort4 v1 = *(const ushort4*)(y + (size_t)s1 * H + j);
            ushort4 v2 = *(const ushort4*)(y + (size_t)s2 * H + j);
            ushort4 v3 = *(const ushort4*)(y + (size_t)s3 * H + j);
            a0.x += bf2f(v0.x); a0.y += bf2f(v0.y); a0.z += bf2f(v0.z); a0.w += bf2f(v0.w);
            a1.x += bf2f(v1.x); a1.y += bf2f(v1.y); a1.z += bf2f(v1.z); a1.w += bf2f(v1.w);
            a2.x += bf2f(v2.x); a2.y += bf2f(v2.y); a2.z += bf2f(v2.z); a2.w += bf2f(v2.w);
            a3.x += bf2f(v3.x); a3.y += bf2f(v3.y); a3.z += bf2f(v3.z); a3.w += bf2f(v3.w);
            s0 = t0; s1 = t1; s2 = t2; s3 = t3;
        }
        {
            ushort4 v0 = *(const ushort4*)(y + (size_t)s0 * H + j);
            ushort4 v1 = *(const ushort4*)(y + (size_t)s1 * H + j);
            ushort4 v2 = *(const ushort4*)(y + (size_t)s2 * H + j);
            ushort4 v3 = *(const ushort4*)(y + (size_t)s3 * H + j);
            a0.x += bf2f(v0.x); a0.y += bf2f(v0.y); a0.z += bf2f(v0.z); a0.w += bf2f(v0.w);
            a1.x += bf2f(v1.x); a1.y += bf2f(v1.y); a1.z += bf2f(v1.z); a1.w += bf2f(v1.w);
            a2.x += bf2f(v2.x); a2.y += bf2f(v2.y); a2.z += bf2f(v2.z); a2.w += bf2f(v2.w);
            a3.x += bf2f(v3.x); a3.y += bf2f(v3.y); a3.z += bf2f(v3.z); a3.w += bf2f(v3.w);
            k += 4;
        }
    }
    for (; k < k1; ++k) {
        unsigned s = e[k];
        const ushort4 v = *(const ushort4*)(y + (size_t)s * H + j);
        a0.x += bf2f(v.x); a0.y += bf2f(v.y); a0.z += bf2f(v.z); a0.w += bf2f(v.w);
    }
    a0.x += a1.x + a2.x + a3.x; a0.y += a1.y + a2.y + a3.y;
    a0.z += a1.z + a2.z + a3.z; a0.w += a1.w + a2.w + a3.w;
    float inv = 1.0f / (float)(c > 1u ? c : 1u);
    r.x += a0.x * inv; r.y += a0.y * inv; r.z += a0.z * inv; r.w += a0.w * inv;
}

// ---------------------------------------------------------------------------
// FUSED layer-1 pull + layer-2 transform: 32 nodes/block (pull structure kept
// intact -- full TLP), then a block-local [32 x 32] @ [32 x NOUT] MFMA tile.
// Eliminates the x2 round-trip (32 MB) and the whole tf2b serial stage.
// Wave w: m-tile = w&1, n-group = w>>1; acc[i] is n-tile 2i+ngrp, so each
// 32-col output chunk c takes exactly acc[c] from every wave.
template <int NTA, bool HASB>
__device__ __forceinline__ void pull_tf_body(
    int blk, int n,
    const unsigned* __restrict__ rsA, const unsigned* __restrict__ eA, const unsigned short* __restrict__ yA,
    const unsigned* __restrict__ rsB, const unsigned* __restrict__ eB, const unsigned short* __restrict__ yB,
    float* __restrict__ h,
    const unsigned short* __restrict__ Wf, const float* __restrict__ bias,
    unsigned short* __restrict__ z0, unsigned short* __restrict__ z1,
    short* __restrict__ lx, float* __restrict__ lo)
{
    constexpr int XS = 40;   // lx row stride (shorts)
    constexpr int OS = 34;   // lo row stride (floats)
    const int tid = threadIdx.x;
    const int row = tid >> 3;
    const int j = (tid & 7) * 4;
    const int base = blk * 32;
    const int node = base + row;
    const bool act = node < n;

    float4 r = make_float4(0.f, 0.f, 0.f, 0.f);
    if (act) {
        r = *(const float4*)(h + (size_t)node * H + j);  // root term
        agg_one(rsA[node], eA, yA, j, r);
        if (HASB) agg_one(rsB[node], eB, yB, j, r);
    }
    short4 s4;
    s4.x = (short)f2bf(fmaxf(r.x, 0.f));
    s4.y = (short)f2bf(fmaxf(r.y, 0.f));
    s4.z = (short)f2bf(fmaxf(r.z, 0.f));
    s4.w = (short)f2bf(fmaxf(r.w, 0.f));
    *(short4*)&lx[row * XS + j] = s4;
    __syncthreads();

    // ---- MFMA ----
    const int w = tid >> 6, l = tid & 63, quad = l >> 4, ln = l & 15;
    const int mt = w & 1, ngrp = w >> 1;
    const short8* wf8 = (const short8*)Wf;
    floatx4 acc[NTA];
    short8 af = *(const short8*)&lx[(mt * 16 + ln) * XS + quad * 8];
#pragma unroll
    for (int i = 0; i < NTA; i++) {
        int nt = 2 * i + ngrp;
        float bv = bias[nt * 16 + ln];
        floatx4 c0 = {bv, bv, bv, bv};
        acc[i] = __builtin_amdgcn_mfma_f32_16x16x32_bf16(af, wf8[nt * 64 + l], c0, 0, 0, 0);
    }

    // ---- epilogue: per-32-col chunk LDS transpose -> coalesced stores ----
    const int rows = min(32, n - base);
    const int orow = tid >> 3, oc = (tid & 7) * 4;
#pragma unroll
    for (int c = 0; c < NTA; c++) {
        __syncthreads();
#pragma unroll
        for (int rr = 0; rr < 4; rr++)
            lo[(mt * 16 + quad * 4 + rr) * OS + ngrp * 16 + ln] = acc[c][rr];
        __syncthreads();
        if (orow < rows) {
            const float* p = &lo[orow * OS + oc];
            if (c == NTA - 1) {  // h chunk, fp32 (block-owned rows: in-place OK)
                *(float4*)(h + (size_t)(base + orow) * H + oc) =
                    make_float4(p[0], p[1], p[2], p[3]);
            } else {             // y2 chunk, bf16
                unsigned short* og = (c == 0) ? z0 : z1;
                short4 o;
                o.x = (short)f2bf(p[0]); o.y = (short)f2bf(p[1]);
                o.z = (short)f2bf(p[2]); o.w = (short)f2bf(p[3]);
                *(short4*)(og + (size_t)(base + orow) * H + oc) = o;
            }
        }
    }
}

__global__ __launch_bounds__(256) void pull_tf2_kernel(
    const unsigned* __restrict__ rsbb, const unsigned* __restrict__ ebb, const unsigned short* __restrict__ ybb,
    const unsigned* __restrict__ rsgb, const unsigned* __restrict__ egb, const unsigned short* __restrict__ ygb,
    float* __restrict__ hb, const unsigned short* __restrict__ Wfb, const float* __restrict__ Bb,
    unsigned short* __restrict__ y2bb, unsigned short* __restrict__ y2bg,
    const unsigned* __restrict__ rsbg, const unsigned* __restrict__ ebg, const unsigned short* __restrict__ ybg,
    float* __restrict__ hg, const unsigned short* __restrict__ Wfg, const float* __restrict__ Bg,
    unsigned short* __restrict__ y2gb)
{
    __shared__ __align__(16) short lx[32 * 40];
    __shared__ __align__(16) float lo[32 * 34];
    int b = blockIdx.x;
    if (b < NB_PL_BUS)
        pull_tf_body<3, true>(b, N_BUS, rsbb, ebb, ybb, rsgb, egb, ygb,
                              hb, Wfb, Bb, y2bb, y2bg, lx, lo);
    else
        pull_tf_body<2, false>(b - NB_PL_BUS, N_GEN, rsbg, ebg, ybg,
                               nullptr, nullptr, nullptr,
                               hg, Wfg, Bg, y2gb, nullptr, lx, lo);
}

// ---------------------------------------------------------------------------
// Final pull + fused head -> d_out (8 threads/node, unchanged structure).
__device__ __forceinline__ void pull_head_body(
    int blk, bool hasB, int n,
    const unsigned* __restrict__ rsA, const unsigned* __restrict__ eA, const unsigned short* __restrict__ yA,
    const unsigned* __restrict__ rsB, const unsigned* __restrict__ eB, const unsigned short* __restrict__ yB,
    const float* __restrict__ h,
    const float* __restrict__ We, const float* __restrict__ be, int DOUT, float* __restrict__ outp)
{
    const int tid = threadIdx.x;
    unsigned node = blk * 32u + (tid >> 3);
    int j = (tid & 7) * 4;
    if (node >= (unsigned)n) return;

    float4 r = *(const float4*)(h + (size_t)node * H + j);  // root term

    agg_one(rsA[node], eA, yA, j, r);
    if (hasB) agg_one(rsB[node], eB, yB, j, r);

    float p0 = fmaxf(r.x, 0.f), p1 = fmaxf(r.y, 0.f), p2 = fmaxf(r.z, 0.f), p3 = fmaxf(r.w, 0.f);
    float tot[4];
#pragma unroll
    for (int c = 0; c < 4; c++) {
        if (c < DOUT) {
            tot[c] = p0 * We[(j + 0) * DOUT + c] + p1 * We[(j + 1) * DOUT + c]
                   + p2 * We[(j + 2) * DOUT + c] + p3 * We[(j + 3) * DOUT + c];
        } else tot[c] = 0.f;
    }
#pragma unroll
    for (int mask = 1; mask <= 4; mask <<= 1) {
#pragma unroll
        for (int c = 0; c < 4; c++) tot[c] += __shfl_xor(tot[c], mask);
    }
    if ((tid & 7) == 0) {
        if (DOUT == 4) {
            *(float4*)(outp + (size_t)node * 4) =
                make_float4(tot[0] + be[0], tot[1] + be[1], tot[2] + be[2], tot[3] + be[3]);
        } else {
            *(float2*)(outp + (size_t)node * 2) = make_float2(tot[0] + be[0], tot[1] + be[1]);
        }
    }
}

__global__ __launch_bounds__(256) void pull_head_kernel(
    const unsigned* __restrict__ rsbb, const unsigned* __restrict__ ebb, const unsigned short* __restrict__ y2bb,
    const unsigned* __restrict__ rsgb, const unsigned* __restrict__ egb, const unsigned short* __restrict__ y2gb,
    const float* __restrict__ hb, const float* __restrict__ WeB, const float* __restrict__ beB,
    const unsigned* __restrict__ rsbg, const unsigned* __restrict__ ebg, const unsigned short* __restrict__ y2bg,
    const float* __restrict__ hg, const float* __restrict__ WeG, const float* __restrict__ beG,
    float* __restrict__ outp)
{
    int b = blockIdx.x;
    if (b < NB_PL_BUS)
        pull_head_body(b, true, N_BUS, rsbb, ebb, y2bb, rsgb, egb, y2gb, hb, WeB, beB, 4, outp);
    else
        pull_head_body(b - NB_PL_BUS, false, N_GEN, rsbg, ebg, y2bg, nullptr, nullptr, nullptr,
                       hg, WeG, beG, 2, outp + (size_t)N_BUS * 4);
}

// ---------------------------------------------------------------------------
extern "C" void kernel_launch(void* const* d_in, const int* in_sizes, int n_in,
                              void* d_out, int out_size, void* d_ws, size_t ws_size,
                              hipStream_t stream) {
    const float* x_bus = (const float*)d_in[0];
    const float* x_gen = (const float*)d_in[1];
    const int* src_bb = (const int*)d_in[2];
    const int* dst_bb = (const int*)d_in[3];
    const int* src_gb = (const int*)d_in[4];
    const int* dst_gb = (const int*)d_in[5];
    const int* src_bg = (const int*)d_in[6];
    const int* dst_bg = (const int*)d_in[7];
    const float* l1_bb_Wl = (const float*)d_in[8];
    const float* l1_bb_bl = (const float*)d_in[9];
    const float* l1_bb_Wr = (const float*)d_in[10];
    const float* l1_gb_Wl = (const float*)d_in[11];
    const float* l1_gb_bl = (const float*)d_in[12];
    const float* l1_gb_Wr = (const float*)d_in[13];
    const float* l1_bg_Wl = (const float*)d_in[14];
    const float* l1_bg_bl = (const float*)d_in[15];
    const float* l1_bg_Wr = (const float*)d_in[16];
    const float* l2_bb_Wl = (const float*)d_in[17];
    const float* l2_bb_bl = (const float*)d_in[18];
    const float* l2_bb_Wr = (const float*)d_in[19];
    const float* l2_gb_Wl = (const float*)d_in[20];
    const float* l2_gb_bl = (const float*)d_in[21];
    const float* l2_gb_Wr = (const float*)d_in[22];
    const float* l2_bg_Wl = (const float*)d_in[23];
    const float* l2_bg_bl = (const float*)d_in[24];
    const float* l2_bg_Wr = (const float*)d_in[25];
    const float* lin0_bus_W = (const float*)d_in[26];
    const float* lin0_bus_b = (const float*)d_in[27];
    const float* linf_bus_W = (const float*)d_in[28];
    const float* linf_bus_b = (const float*)d_in[29];
    const float* lin0_gen_W = (const float*)d_in[30];
    const float* lin0_gen_b = (const float*)d_in[31];
    const float* linf_gen_W = (const float*)d_in[32];
    const float* linf_gen_b = (const float*)d_in[33];

    // Workspace layout (~125 MB).
    char* ws = (char*)d_ws;
    size_t off = 0;
    auto alloc = [&](size_t bytes) {
        char* p = ws + off;
        off += (bytes + 255) & ~(size_t)255;
        return p;
    };
    unsigned* rs_bb = (unsigned*)alloc((size_t)N_BUS * 4);
    unsigned* rs_gb = (unsigned*)alloc((size_t)N_BUS * 4);
    unsigned* rs_bg = (unsigned*)alloc((size_t)N_GEN * 4);
    unsigned* cur_bb = (unsigned*)alloc(NBINS * 4);   // three cursor arrays contiguous
    unsigned* cur_gb = (unsigned*)alloc(NBINS * 4);
    unsigned* cur_bg = (unsigned*)alloc(NBINS * 4);
    unsigned* e_bb = (unsigned*)alloc((size_t)NBK_BUS * CAP_BB * 4);
    unsigned* e_gb = (unsigned*)alloc((size_t)NBK_BUS * CAP_GB * 4);
    unsigned* e_bg = (unsigned*)alloc((size_t)NBK_GEN * CAP_BG * 4);
    unsigned* p_bb = (unsigned*)alloc((size_t)NBK_BUS * CAP_BB * 4);
    unsigned* p_gb = (unsigned*)alloc((size_t)NBK_BUS * CAP_GB * 4);
    unsigned* p_bg = (unsigned*)alloc((size_t)NBK_GEN * CAP_BG * 4);
    unsigned short* y_bb = (unsigned short*)alloc((size_t)N_BUS * H * 2);  // bf16
    unsigned short* y_bg = (unsigned short*)alloc((size_t)N_BUS * H * 2);  // bf16
    unsigned short* y_gb = (unsigned short*)alloc((size_t)N_GEN * H * 2);  // bf16
    unsigned short* y2_bb = (unsigned short*)alloc((size_t)N_BUS * H * 2); // layer-2 y
    unsigned short* y2_bg = (unsigned short*)alloc((size_t)N_BUS * H * 2);
    unsigned short* y2_gb = (unsigned short*)alloc((size_t)N_GEN * H * 2);
    float* h_bus = (float*)alloc((size_t)N_BUS * H * 4);
    float* h_gen = (float*)alloc((size_t)N_GEN * H * 4);
    unsigned short* Wf1b = (unsigned short*)alloc(2 * 6 * 64 * 8 * 2);
    float* B1b = (float*)alloc(96 * 4);
    unsigned short* Wf1g = (unsigned short*)alloc(2 * 4 * 64 * 8 * 2);
    float* B1g = (float*)alloc(64 * 4);
    unsigned short* Wf2b = (unsigned short*)alloc(6 * 64 * 8 * 2);
    float* B2b = (float*)alloc(96 * 4);
    unsigned short* Wf2g = (unsigned short*)alloc(4 * 64 * 8 * 2);
    float* B2g = (float*)alloc(64 * 4);
    float* WeB = (float*)alloc(128 * 4);
    float* beB = (float*)alloc(4 * 4);
    float* WeG = (float*)alloc(64 * 4);
    float* beG = (float*)alloc(2 * 4);

    // L0: zero the three contiguous cursor arrays.
    zero_kernel<<<12, 256, 0, stream>>>(cur_bb);

    // L1: [part | prep].
    prep_part_kernel<<<NB_PART_ALL + NB_PREP, 256, 0, stream>>>(
        src_bb, dst_bb, cur_bb, p_bb, src_gb, dst_gb, cur_gb, p_gb,
        src_bg, dst_bg, cur_bg, p_bg,
        l1_bb_Wl, l1_bb_bl, l1_bb_Wr, l1_gb_Wl, l1_gb_bl, l1_gb_Wr,
        l1_bg_Wl, l1_bg_bl, l1_bg_Wr, l2_bb_Wl, l2_bb_bl, l2_bb_Wr,
        l2_gb_Wl, l2_gb_bl, l2_gb_Wr, l2_bg_Wl, l2_bg_bl, l2_bg_Wr,
        lin0_bus_W, lin0_bus_b, linf_bus_W, linf_bus_b,
        lin0_gen_W, lin0_gen_b, linf_gen_W, linf_gen_b,
        Wf1b, B1b, Wf1g, B1g, Wf2b, B2b, Wf2g, B2g, WeB, beB, WeG, beG);

    // L2: [tf1 | fine].
    tf1_fine_kernel<<<NB_TF_ALL + NB_FINE_ALL, 256, 0, stream>>>(
        x_bus, Wf1b, B1b, y_bb, y_bg, h_bus, x_gen, Wf1g, B1g, y_gb, h_gen,
        cur_bb, p_bb, rs_bb, e_bb, cur_gb, p_gb, rs_gb, e_gb, cur_bg, p_bg, rs_bg, e_bg);

    // L3: FUSED layer-1 pull + layer-2 transform (32-node blocks, in-block MFMA).
    pull_tf2_kernel<<<NB_PL_BUS + NB_PL_GEN, 256, 0, stream>>>(
        rs_bb, e_bb, y_bb, rs_gb, e_gb, y_gb, h_bus, Wf2b, B2b, y2_bb, y2_bg,
        rs_bg, e_bg, y_bg, h_gen, Wf2g, B2g, y2_gb);

    // L4: layer-2 pull + fused head -> d_out.
    pull_head_kernel<<<NB_PL_BUS + NB_PL_GEN, 256, 0, stream>>>(
        rs_bb, e_bb, y2_bb, rs_gb, e_gb, y2_gb, h_bus, WeB, beB,
        rs_bg, e_bg, y2_bg, h_gen, WeG, beG, (float*)d_out);
}

// Round 7
// 349.978 us; speedup vs baseline: 1.0263x; 1.0263x over previous
//
#include <hip/hip_runtime.h>
#include <hip/hip_bf16.h>

#define N_BUS 200000
#define N_GEN 50000
#define E_BB 1600000
#define E_GB 400000
#define E_BG 400000
#define H 32
#define NBINS 1024   // max coarse buckets (>= ceil(200000/256) = 782)
#define EPT 16       // edges per thread in partition (chunk = 4096)

#define NBK_BUS 782      // buckets for bus-dst relations
#define NBK_GEN 196      // buckets for gen-dst relations
#define CAP_BB 2560      // mean 2046 + >11 sigma
#define CAP_GB 768       // mean 512  + >11 sigma
#define CAP_BG 2560      // mean 2041 + >11 sigma

#define NB_PART_BB 391   // ceil(E_BB/4096)
#define NB_PART_GB 98
#define NB_PART_BG 98
#define NB_PART_ALL 587
#define NB_PREP 32
#define NB_TF1_BUS 1563  // ceil(200000/128)
#define NB_TF1_GEN 391   // ceil(50000/128)
#define NB_TF1_ALL 1954
#define NB_FINE_ALL 1760 // 2*NBK_BUS + NBK_GEN
#define NB_PL_BUS 6250   // ceil(N_BUS/32)
#define NB_PL_GEN 1563

#define PNONE 0xFFFFFFFFu

typedef __attribute__((ext_vector_type(8))) short short8;
typedef __attribute__((ext_vector_type(4))) float floatx4;

__device__ inline unsigned short f2bf(float f) {
    __hip_bfloat16 h = __float2bfloat16(f);   // RNE
    return *reinterpret_cast<unsigned short*>(&h);
}
__device__ inline float bf2f(unsigned short u) {
    return __uint_as_float(((unsigned)u) << 16);
}

// ---------------------------------------------------------------------------
// Block-wide exclusive scan over one unsigned per thread (256 threads).
// Wave-level shfl scan + 4-entry cross-wave LDS; ONE barrier (vs 20).
__device__ __forceinline__ unsigned block_excl_scan(unsigned s, unsigned* wsum) {
    const int lane = threadIdx.x & 63, wv = threadIdx.x >> 6;
    unsigned scan = s;
#pragma unroll
    for (int d = 1; d < 64; d <<= 1) {
        unsigned t = __shfl_up(scan, d, 64);
        if (lane >= d) scan += t;
    }
    if (lane == 63) wsum[wv] = scan;
    __syncthreads();
    unsigned base = 0;
    for (int i = 0; i < wv; i++) base += wsum[i];
    return base + scan - s;   // exclusive prefix for this thread's value
}

// ---------------------------------------------------------------------------
// Zero the 3 contiguous cursor arrays.
__global__ __launch_bounds__(256) void zero_kernel(unsigned* __restrict__ p) {
    int i = blockIdx.x * 256 + threadIdx.x;
    if (i < 3 * NBINS) p[i] = 0u;
}

// ---------------------------------------------------------------------------
// Partition into fixed-capacity buckets. Block-local LDS counting sort so the
// global pairs[] write streams out in position order. pairs = (dst&255)<<24|src.
__device__ __forceinline__ void part_body(int blk, const int* __restrict__ src,
                                          const int* __restrict__ dst, int nE,
                                          unsigned* __restrict__ cnt_g, int CAP,
                                          unsigned* __restrict__ pairs) {
    __shared__ unsigned hist[NBINS];
    __shared__ unsigned base[NBINS];    // global target base per bin
    __shared__ unsigned sbase[NBINS];   // block-local exclusive scan per bin
    __shared__ unsigned wsum[4];
    __shared__ unsigned pairv[256 * EPT];
    __shared__ unsigned short bid[256 * EPT];
    const int tid = threadIdx.x;
    const int cbase = blk * (256 * EPT);
    const int total = min(256 * EPT, nE - cbase);

    unsigned es[EPT], ed[EPT];
#pragma unroll
    for (int q = 0; q < EPT; q++) {
        int i = cbase + q * 256 + tid;
        if (i < nE) { es[q] = (unsigned)src[i]; ed[q] = (unsigned)dst[i]; }
        else ed[q] = PNONE;
    }
    for (int i = tid; i < NBINS; i += 256) hist[i] = 0;
    __syncthreads();
#pragma unroll
    for (int q = 0; q < EPT; q++)
        if (ed[q] != PNONE) atomicAdd(&hist[ed[q] >> 8], 1u);
    __syncthreads();

    // Block-local exclusive scan over the 1024 bins (4 bins/thread, wave scan).
    unsigned h4[4];
    unsigned s = 0;
#pragma unroll
    for (int k2 = 0; k2 < 4; k2++) { h4[k2] = hist[tid * 4 + k2]; s += h4[k2]; }
    unsigned run = block_excl_scan(s, wsum);
#pragma unroll
    for (int k2 = 0; k2 < 4; k2++) {
        int b = tid * 4 + k2;
        sbase[b] = run;
        base[b] = h4[k2] ? ((unsigned)b * CAP + atomicAdd(&cnt_g[b], h4[k2])) : 0u;
        hist[b] = 0;  // reuse as local cursor
        run += h4[k2];
    }
    __syncthreads();

    // Place pairs into the block-sorted LDS staging.
#pragma unroll
    for (int q = 0; q < EPT; q++) {
        if (ed[q] != PNONE) {
            unsigned b = ed[q] >> 8;
            unsigned off = atomicAdd(&hist[b], 1u);
            unsigned p = sbase[b] + off;
            pairv[p] = ((ed[q] & 255u) << 24) | es[q];
            bid[p] = (unsigned short)b;
        }
    }
    __syncthreads();

    // Stream out: consecutive p within a bucket -> consecutive global addr.
    for (int p = tid; p < total; p += 256) {
        unsigned b = bid[p];
        pairs[base[b] + ((unsigned)p - sbase[b])] = pairv[p];
    }
}

// ---------------------------------------------------------------------------
// Prep body (grid-striding over NB_PREP*256 threads): bf16 MFMA B-fragments +
// fused biases + fused head matrices.
__device__ __forceinline__ void prep_body(int pb,
    const float* __restrict__ l1_bb_Wl, const float* __restrict__ l1_bb_bl, const float* __restrict__ l1_bb_Wr,
    const float* __restrict__ l1_gb_Wl, const float* __restrict__ l1_gb_bl, const float* __restrict__ l1_gb_Wr,
    const float* __restrict__ l1_bg_Wl, const float* __restrict__ l1_bg_bl, const float* __restrict__ l1_bg_Wr,
    const float* __restrict__ l2_bb_Wl, const float* __restrict__ l2_bb_bl, const float* __restrict__ l2_bb_Wr,
    const float* __restrict__ l2_gb_Wl, const float* __restrict__ l2_gb_bl, const float* __restrict__ l2_gb_Wr,
    const float* __restrict__ l2_bg_Wl, const float* __restrict__ l2_bg_bl, const float* __restrict__ l2_bg_Wr,
    const float* __restrict__ lin0_bus_W, const float* __restrict__ lin0_bus_b,
    const float* __restrict__ linf_bus_W, const float* __restrict__ linf_bus_b,
    const float* __restrict__ lin0_gen_W, const float* __restrict__ lin0_gen_b,
    const float* __restrict__ linf_gen_W, const float* __restrict__ linf_gen_b,
    unsigned short* __restrict__ Wf1b, float* __restrict__ B1b,
    unsigned short* __restrict__ Wf1g, float* __restrict__ B1g,
    unsigned short* __restrict__ Wf2b, float* __restrict__ B2b,
    unsigned short* __restrict__ Wf2g, float* __restrict__ B2g,
    float* __restrict__ WeB, float* __restrict__ beB,
    float* __restrict__ WeG, float* __restrict__ beG)
{
    int t0 = pb * 256 + threadIdx.x;
    const int NT = NB_PREP * 256;

    // L1 bus: KT=2, NTN=6
    for (int f = t0; f < 2 * 6 * 64 * 8; f += NT) {
        int j = f & 7, l = (f >> 3) & 63, tile = f >> 9;
        int nt = tile % 6, kt = tile / 6;
        int k = kt * 32 + (l >> 4) * 8 + j, n = nt * 16 + (l & 15);
        float v;
        if (n < 32) v = l1_bb_Wl[k * 32 + n];
        else if (n < 64) v = l1_bg_Wl[k * 32 + n - 32];
        else v = l1_bb_Wr[k * 32 + n - 64] + l1_gb_Wr[k * 32 + n - 64];
        Wf1b[f] = f2bf(v);
    }
    // L1 gen: KT=2, NTN=4
    for (int f = t0; f < 2 * 4 * 64 * 8; f += NT) {
        int j = f & 7, l = (f >> 3) & 63, tile = f >> 9;
        int nt = tile % 4, kt = tile / 4;
        int k = kt * 32 + (l >> 4) * 8 + j, n = nt * 16 + (l & 15);
        float v = (n < 32) ? l1_gb_Wl[k * 32 + n] : l1_bg_Wr[k * 32 + n - 32];
        Wf1g[f] = f2bf(v);
    }
    // L2 bus: KT=1, NTN=6
    for (int f = t0; f < 6 * 64 * 8; f += NT) {
        int j = f & 7, l = (f >> 3) & 63, nt = f >> 9;
        int k = (l >> 4) * 8 + j, n = nt * 16 + (l & 15);
        float v;
        if (n < 32) v = l2_bb_Wl[k * 32 + n];
        else if (n < 64) v = l2_bg_Wl[k * 32 + n - 32];
        else v = l2_bb_Wr[k * 32 + n - 64] + l2_gb_Wr[k * 32 + n - 64];
        Wf2b[f] = f2bf(v);
    }
    // L2 gen: KT=1, NTN=4
    for (int f = t0; f < 4 * 64 * 8; f += NT) {
        int j = f & 7, l = (f >> 3) & 63, nt = f >> 9;
        int k = (l >> 4) * 8 + j, n = nt * 16 + (l & 15);
        float v = (n < 32) ? l2_gb_Wl[k * 32 + n] : l2_bg_Wr[k * 32 + n - 32];
        Wf2g[f] = f2bf(v);
    }
    if (t0 < 96) {
        B1b[t0] = (t0 < 64) ? 0.0f : l1_bb_bl[t0 - 64] + l1_gb_bl[t0 - 64];
        B2b[t0] = (t0 < 64) ? 0.0f : l2_bb_bl[t0 - 64] + l2_gb_bl[t0 - 64];
    }
    if (t0 < 64) {
        B1g[t0] = (t0 < 32) ? 0.0f : l1_bg_bl[t0 - 32];
        B2g[t0] = (t0 < 32) ? 0.0f : l2_bg_bl[t0 - 32];
    }
    // Fused head: bus We (32x4) + be(4); gen We (32x2) + be(2)
    if (t0 < 128) {
        int k = t0 >> 2, c = t0 & 3;
        float s = 0.0f;
        for (int m = 0; m < 32; m++) s += lin0_bus_W[k * 32 + m] * linf_bus_W[m * 4 + c];
        WeB[t0] = s;
    }
    if (t0 >= 128 && t0 < 132) {
        int c = t0 - 128;
        float s = linf_bus_b[c];
        for (int m = 0; m < 32; m++) s += lin0_bus_b[m] * linf_bus_W[m * 4 + c];
        beB[c] = s;
    }
    if (t0 >= 132 && t0 < 196) {
        int i = t0 - 132, k = i >> 1, c = i & 1;
        float s = 0.0f;
        for (int m = 0; m < 32; m++) s += lin0_gen_W[k * 32 + m] * linf_gen_W[m * 2 + c];
        WeG[i] = s;
    }
    if (t0 >= 196 && t0 < 198) {
        int c = t0 - 196;
        float s = linf_gen_b[c];
        for (int m = 0; m < 32; m++) s += lin0_gen_b[m] * linf_gen_W[m * 2 + c];
        beG[c] = s;
    }
}

// Merged [part | prep] launch.
__global__ __launch_bounds__(256) void prep_part_kernel(
    const int* __restrict__ sbb, const int* __restrict__ dbb, unsigned* __restrict__ cbb, unsigned* __restrict__ pbb,
    const int* __restrict__ sgb, const int* __restrict__ dgb, unsigned* __restrict__ cgb, unsigned* __restrict__ pgb,
    const int* __restrict__ sbg, const int* __restrict__ dbg, unsigned* __restrict__ cbg, unsigned* __restrict__ pbg,
    const float* __restrict__ l1_bb_Wl, const float* __restrict__ l1_bb_bl, const float* __restrict__ l1_bb_Wr,
    const float* __restrict__ l1_gb_Wl, const float* __restrict__ l1_gb_bl, const float* __restrict__ l1_gb_Wr,
    const float* __restrict__ l1_bg_Wl, const float* __restrict__ l1_bg_bl, const float* __restrict__ l1_bg_Wr,
    const float* __restrict__ l2_bb_Wl, const float* __restrict__ l2_bb_bl, const float* __restrict__ l2_bb_Wr,
    const float* __restrict__ l2_gb_Wl, const float* __restrict__ l2_gb_bl, const float* __restrict__ l2_gb_Wr,
    const float* __restrict__ l2_bg_Wl, const float* __restrict__ l2_bg_bl, const float* __restrict__ l2_bg_Wr,
    const float* __restrict__ lin0_bus_W, const float* __restrict__ lin0_bus_b,
    const float* __restrict__ linf_bus_W, const float* __restrict__ linf_bus_b,
    const float* __restrict__ lin0_gen_W, const float* __restrict__ lin0_gen_b,
    const float* __restrict__ linf_gen_W, const float* __restrict__ linf_gen_b,
    unsigned short* __restrict__ Wf1b, float* __restrict__ B1b,
    unsigned short* __restrict__ Wf1g, float* __restrict__ B1g,
    unsigned short* __restrict__ Wf2b, float* __restrict__ B2b,
    unsigned short* __restrict__ Wf2g, float* __restrict__ B2g,
    float* __restrict__ WeB, float* __restrict__ beB,
    float* __restrict__ WeG, float* __restrict__ beG)
{
    int b = blockIdx.x;
    if (b < NB_PART_BB) part_body(b, sbb, dbb, E_BB, cbb, CAP_BB, pbb);
    else if (b < NB_PART_BB + NB_PART_GB) part_body(b - NB_PART_BB, sgb, dgb, E_GB, cgb, CAP_GB, pgb);
    else if (b < NB_PART_ALL) part_body(b - NB_PART_BB - NB_PART_GB, sbg, dbg, E_BG, cbg, CAP_BG, pbg);
    else prep_body(b - NB_PART_ALL,
                   l1_bb_Wl, l1_bb_bl, l1_bb_Wr, l1_gb_Wl, l1_gb_bl, l1_gb_Wr,
                   l1_bg_Wl, l1_bg_bl, l1_bg_Wr, l2_bb_Wl, l2_bb_bl, l2_bb_Wr,
                   l2_gb_Wl, l2_gb_bl, l2_gb_Wr, l2_bg_Wl, l2_bg_bl, l2_bg_Wr,
                   lin0_bus_W, lin0_bus_b, linf_bus_W, linf_bus_b,
                   lin0_gen_W, lin0_gen_b, linf_gen_W, linf_gen_b,
                   Wf1b, B1b, Wf1g, B1g, Wf2b, B2b, Wf2g, B2g, WeB, beB, WeG, beG);
}

// ---------------------------------------------------------------------------
// Fine CSR: one block per bucket, LDS carved from shared buffer.
// rs[node] packed: (global row start << 9) | degree  (start < 2^21, deg < 512).
__device__ __forceinline__ void fine_body(int b, const unsigned* __restrict__ cnt_g, int CAP,
                                          const unsigned* __restrict__ pairs,
                                          unsigned* __restrict__ rs,
                                          unsigned* __restrict__ esrc, int nDst,
                                          char* __restrict__ lds) {
    unsigned* cnt = (unsigned*)lds;            // 1 KB
    unsigned* wsum = (unsigned*)(lds + 1024);  // 16 B
    unsigned* stg = (unsigned*)(lds + 2048);   // 10 KB (>= max CAP)
    const int tid = threadIdx.x;
    const unsigned start = (unsigned)b * CAP;
    const unsigned m = cnt_g[b];
    const unsigned end = start + m;

    cnt[tid] = 0;
    __syncthreads();
    for (unsigned k = start + tid; k < end; k += 256)
        atomicAdd(&cnt[pairs[k] >> 24], 1u);
    __syncthreads();
    unsigned c = cnt[tid];
    unsigned excl = block_excl_scan(c, wsum);  // contains one barrier
    int gd = b * 256 + tid;
    unsigned rowstart = start + excl;
    if (gd < nDst) rs[gd] = (rowstart << 9) | (c < 511u ? c : 511u);
    cnt[tid] = excl;  // exclusive offset -> cursor (own slot; all loads done)
    __syncthreads();
    for (unsigned k = start + tid; k < end; k += 256) {
        unsigned p = pairs[k];
        unsigned off = atomicAdd(&cnt[p >> 24], 1u);
        stg[off] = p & 0x00FFFFFFu;
    }
    __syncthreads();
    for (unsigned p = tid; p < m; p += 256) esrc[start + p] = stg[p];
}

// ---------------------------------------------------------------------------
// Layer-1 transform body: ROWS-row tile, stage x fp32 -> bf16, MFMA, epilogue.
// bf fragments loaded per-kt inside the loop to cut register liveness.
template <int K, int NOUT, int ROWS>
__device__ __forceinline__ void transform_body(
    int blk, const float* x, int n,
    const unsigned short* __restrict__ Wf, const float* __restrict__ bias,
    unsigned short* __restrict__ y0, unsigned short* __restrict__ y1, float* h,
    char* ldsraw)
{
    constexpr int XS = K + 8;  // shorts
    constexpr int KT = K / 32, NTN = NOUT / 16, NCH = NOUT / 32;
    constexpr int MTW = ROWS / 64;   // 16-row m-tiles per wave
    constexpr int OS = 34;           // floats
    short* lx = (short*)ldsraw;
    float* lo = (float*)ldsraw;
    const int tid = threadIdx.x;
    const int base = blk * ROWS;
    const int rows = min(ROWS, n - base);
    const int w = tid >> 6, l = tid & 63, quad = l >> 4, ln = l & 15;

    {   // stage
        const float4* xg = (const float4*)(x + (size_t)base * K);
        const int T4 = rows * (K / 4);
        for (int q = tid; q < T4; q += 256) {
            float4 v = xg[q];
            int r = q / (K / 4), c = (q % (K / 4)) * 4;
            short4 s4;
            s4.x = (short)f2bf(v.x); s4.y = (short)f2bf(v.y);
            s4.z = (short)f2bf(v.z); s4.w = (short)f2bf(v.w);
            *(short4*)&lx[r * XS + c] = s4;
        }
    }
    __syncthreads();

    const short8* wf8 = (const short8*)Wf;
    float bv[NTN];
#pragma unroll
    for (int nt = 0; nt < NTN; nt++) bv[nt] = bias[nt * 16 + ln];

    floatx4 acc[MTW][NTN];
#pragma unroll
    for (int mt = 0; mt < MTW; mt++)
#pragma unroll
        for (int nt = 0; nt < NTN; nt++) {
            floatx4 c0 = {bv[nt], bv[nt], bv[nt], bv[nt]};
            acc[mt][nt] = c0;
        }
#pragma unroll
    for (int mt = 0; mt < MTW; mt++) {
        const int row = w * (ROWS / 4) + mt * 16 + ln;
#pragma unroll
        for (int kt = 0; kt < KT; kt++) {
            short8 af = *(const short8*)&lx[row * XS + kt * 32 + quad * 8];
#pragma unroll
            for (int nt = 0; nt < NTN; nt++)
                acc[mt][nt] = __builtin_amdgcn_mfma_f32_16x16x32_bf16(
                    af, wf8[(kt * NTN + nt) * 64 + l], acc[mt][nt], 0, 0, 0);
        }
    }

    // epilogue: per-32-col chunk LDS transpose -> coalesced stores
#pragma unroll
    for (int c = 0; c < NCH; c++) {
        __syncthreads();
#pragma unroll
        for (int mt = 0; mt < MTW; mt++)
#pragma unroll
            for (int d = 0; d < 2; d++) {
                int nt = 2 * c + d;
#pragma unroll
                for (int r = 0; r < 4; r++)
                    lo[(w * (ROWS / 4) + mt * 16 + quad * 4 + r) * OS + d * 16 + ln] = acc[mt][nt][r];
            }
        __syncthreads();
        const int T4 = rows * 8;
        if (c == NCH - 1) {  // h chunk, fp32
            float* og = h + (size_t)base * 32;
            for (int q = tid; q < T4; q += 256) {
                int r = q >> 3, cc = (q & 7) * 4;
                const float* p = &lo[r * OS + cc];
                *(float4*)(og + q * 4) = make_float4(p[0], p[1], p[2], p[3]);
            }
        } else {  // y chunk, bf16
            unsigned short* og = ((c == 0) ? y0 : y1) + (size_t)base * 32;
            for (int q = tid; q < T4; q += 256) {
                int r = q >> 3, cc = (q & 7) * 4;
                const float* p = &lo[r * OS + cc];
                short4 s4;
                s4.x = (short)f2bf(p[0]); s4.y = (short)f2bf(p[1]);
                s4.z = (short)f2bf(p[2]); s4.w = (short)f2bf(p[3]);
                *(short4*)(og + q * 4) = s4;
            }
        }
    }
}

// Merged [tf1 (128-row tiles) | fine] launch.
__global__ __launch_bounds__(256) void tf1_fine_kernel(
    const float* xb, const unsigned short* __restrict__ Wfb, const float* __restrict__ Bb,
    unsigned short* __restrict__ yb0, unsigned short* __restrict__ yb1, float* hb,
    const float* xg, const unsigned short* __restrict__ Wfg, const float* __restrict__ Bg,
    unsigned short* __restrict__ yg0, float* hg,
    const unsigned* __restrict__ cbb, const unsigned* __restrict__ pbb, unsigned* __restrict__ rsbb, unsigned* __restrict__ ebb,
    const unsigned* __restrict__ cgb, const unsigned* __restrict__ pgb, unsigned* __restrict__ rsgb, unsigned* __restrict__ egb,
    const unsigned* __restrict__ cbg, const unsigned* __restrict__ pbg, unsigned* __restrict__ rsbg, unsigned* __restrict__ ebg)
{
    constexpr int XB = 128 * (64 + 8) * 2, OB = 128 * 34 * 4;  // 18432 / 17408
    __shared__ __align__(16) char ldsraw[(XB > OB) ? XB : OB];
    int b = blockIdx.x;
    if (b < NB_TF1_BUS)
        transform_body<64, 96, 128>(b, xb, N_BUS, Wfb, Bb, yb0, yb1, hb, ldsraw);
    else if (b < NB_TF1_ALL)
        transform_body<64, 64, 128>(b - NB_TF1_BUS, xg, N_GEN, Wfg, Bg, yg0, nullptr, hg, ldsraw);
    else {
        int f = b - NB_TF1_ALL;
        if (f < NBK_BUS) fine_body(f, cbb, CAP_BB, pbb, rsbb, ebb, N_BUS, ldsraw);
        else if (f < 2 * NBK_BUS) fine_body(f - NBK_BUS, cgb, CAP_GB, pgb, rsgb, egb, N_BUS, ldsraw);
        else fine_body(f - 2 * NBK_BUS, cbg, CAP_BG, pbg, rsbg, ebg, N_GEN, ldsraw);
    }
}

// ---------------------------------------------------------------------------
// One relation's mean-aggregate into a float4 (cols j..j+3); 4-deep pipeline
// with next-quad index prefetch.
__device__ __forceinline__ void agg_one(
    unsigned u, const unsigned* __restrict__ e,
    const unsigned short* __restrict__ y, int j, float4& r)
{
    unsigned k0 = u >> 9;
    unsigned c = u & 511u;
    unsigned k1 = k0 + c;
    float4 a0 = make_float4(0.f, 0.f, 0.f, 0.f);
    float4 a1 = a0, a2 = a0, a3 = a0;
    unsigned k = k0;
    if (k + 4 <= k1) {
        unsigned s0 = e[k], s1 = e[k + 1], s2 = e[k + 2], s3 = e[k + 3];
        for (; k + 8 <= k1; k += 4) {
            unsigned t0 = e[k + 4], t1 = e[k + 5], t2 = e[k + 6], t3 = e[k + 7];
            ushort4 v0 = *(const ushort4*)(y + (size_t)s0 * H + j);
            ushort4 v1 = *(const ushort4*)(y + (size_t)s1 * H + j);
            ushort4 v2 = *(const ushort4*)(y + (size_t)s2 * H + j);
            ushort4 v3 = *(const ushort4*)(y + (size_t)s3 * H + j);
            a0.x += bf2f(v0.x); a0.y += bf2f(v0.y); a0.z += bf2f(v0.z); a0.w += bf2f(v0.w);
            a1.x += bf2f(v1.x); a1.y += bf2f(v1.y); a1.z += bf2f(v1.z); a1.w += bf2f(v1.w);
            a2.x += bf2f(v2.x); a2.y += bf2f(v2.y); a2.z += bf2f(v2.z); a2.w += bf2f(v2.w);
            a3.x += bf2f(v3.x); a3.y += bf2f(v3.y); a3.z += bf2f(v3.z); a3.w += bf2f(v3.w);
            s0 = t0; s1 = t1; s2 = t2; s3 = t3;
        }
        {
            ushort4 v0 = *(const ushort4*)(y + (size_t)s0 * H + j);
            ushort4 v1 = *(const ushort4*)(y + (size_t)s1 * H + j);
            ushort4 v2 = *(const ushort4*)(y + (size_t)s2 * H + j);
            ushort4 v3 = *(const ushort4*)(y + (size_t)s3 * H + j);
            a0.x += bf2f(v0.x); a0.y += bf2f(v0.y); a0.z += bf2f(v0.z); a0.w += bf2f(v0.w);
            a1.x += bf2f(v1.x); a1.y += bf2f(v1.y); a1.z += bf2f(v1.z); a1.w += bf2f(v1.w);
            a2.x += bf2f(v2.x); a2.y += bf2f(v2.y); a2.z += bf2f(v2.z); a2.w += bf2f(v2.w);
            a3.x += bf2f(v3.x); a3.y += bf2f(v3.y); a3.z += bf2f(v3.z); a3.w += bf2f(v3.w);
            k += 4;
        }
    }
    for (; k < k1; ++k) {
        unsigned s = e[k];
        const ushort4 v = *(const ushort4*)(y + (size_t)s * H + j);
        a0.x += bf2f(v.x); a0.y += bf2f(v.y); a0.z += bf2f(v.z); a0.w += bf2f(v.w);
    }
    a0.x += a1.x + a2.x + a3.x; a0.y += a1.y + a2.y + a3.y;
    a0.z += a1.z + a2.z + a3.z; a0.w += a1.w + a2.w + a3.w;
    float inv = 1.0f / (float)(c > 1u ? c : 1u);
    r.x += a0.x * inv; r.y += a0.y * inv; r.z += a0.z * inv; r.w += a0.w * inv;
}

// ---------------------------------------------------------------------------
// FUSED layer-1 pull + layer-2 transform: 32 nodes/block, then a block-local
// [32 x 32] @ [32 x NOUT] MFMA tile. Single-barrier wide-lo epilogue.
template <int NTA, bool HASB>
__device__ __forceinline__ void pull_tf_body(
    int blk, int n,
    const unsigned* __restrict__ rsA, const unsigned* __restrict__ eA, const unsigned short* __restrict__ yA,
    const unsigned* __restrict__ rsB, const unsigned* __restrict__ eB, const unsigned short* __restrict__ yB,
    float* __restrict__ h,
    const unsigned short* __restrict__ Wf, const float* __restrict__ bias,
    unsigned short* __restrict__ z0, unsigned short* __restrict__ z1,
    short* __restrict__ lx, float* __restrict__ lo)
{
    constexpr int XS = 40;            // lx row stride (shorts)
    constexpr int OS2 = NTA * 32 + 4; // lo row stride (floats): 100 / 68
    const int tid = threadIdx.x;
    const int row = tid >> 3;
    const int j = (tid & 7) * 4;
    const int base = blk * 32;
    const int node = base + row;
    const bool act = node < n;

    float4 r = make_float4(0.f, 0.f, 0.f, 0.f);
    if (act) {
        r = *(const float4*)(h + (size_t)node * H + j);  // root term
        agg_one(rsA[node], eA, yA, j, r);
        if (HASB) agg_one(rsB[node], eB, yB, j, r);
    }
    short4 s4;
    s4.x = (short)f2bf(fmaxf(r.x, 0.f));
    s4.y = (short)f2bf(fmaxf(r.y, 0.f));
    s4.z = (short)f2bf(fmaxf(r.z, 0.f));
    s4.w = (short)f2bf(fmaxf(r.w, 0.f));
    *(short4*)&lx[row * XS + j] = s4;
    __syncthreads();

    // ---- MFMA: wave w -> m-tile (w&1), n-group (w>>1); acc[i] = n-tile 2i+ngrp
    const int w = tid >> 6, l = tid & 63, quad = l >> 4, ln = l & 15;
    const int mt = w & 1, ngrp = w >> 1;
    const short8* wf8 = (const short8*)Wf;
    floatx4 acc[NTA];
    short8 af = *(const short8*)&lx[(mt * 16 + ln) * XS + quad * 8];
#pragma unroll
    for (int i = 0; i < NTA; i++) {
        int nt = 2 * i + ngrp;
        float bv = bias[nt * 16 + ln];
        floatx4 c0 = {bv, bv, bv, bv};
        acc[i] = __builtin_amdgcn_mfma_f32_16x16x32_bf16(af, wf8[nt * 64 + l], c0, 0, 0, 0);
    }

    // ---- epilogue: single wide lo (32 x NTA*32), ONE barrier ----
#pragma unroll
    for (int i = 0; i < NTA; i++) {
        int colb = (2 * i + ngrp) * 16 + ln;
#pragma unroll
        for (int rr = 0; rr < 4; rr++)
            lo[(mt * 16 + quad * 4 + rr) * OS2 + colb] = acc[i][rr];
    }
    __syncthreads();
    const int rows = min(32, n - base);
    constexpr int NC4 = NTA * 8;  // float4s per row
#pragma unroll
    for (int t = 0; t < NTA; t++) {
        int q = tid + t * 256;    // q < 32*NC4 = 256*NTA
        int orow = q / NC4, c4 = (q % NC4) * 4;
        if (orow < rows) {
            const float* p = &lo[orow * OS2 + c4];
            int chunk = c4 >> 5;
            if (chunk == NTA - 1) {  // h chunk, fp32 (block-owned rows)
                *(float4*)(h + (size_t)(base + orow) * H + (c4 & 31)) =
                    make_float4(p[0], p[1], p[2], p[3]);
            } else {                 // y2 chunk, bf16
                unsigned short* og = (chunk == 0) ? z0 : z1;
                short4 o;
                o.x = (short)f2bf(p[0]); o.y = (short)f2bf(p[1]);
                o.z = (short)f2bf(p[2]); o.w = (short)f2bf(p[3]);
                *(short4*)(og + (size_t)(base + orow) * H + (c4 & 31)) = o;
            }
        }
    }
}

__global__ __launch_bounds__(256) void pull_tf2_kernel(
    const unsigned* __restrict__ rsbb, const unsigned* __restrict__ ebb, const unsigned short* __restrict__ ybb,
    const unsigned* __restrict__ rsgb, const unsigned* __restrict__ egb, const unsigned short* __restrict__ ygb,
    float* __restrict__ hb, const unsigned short* __restrict__ Wfb, const float* __restrict__ Bb,
    unsigned short* __restrict__ y2bb, unsigned short* __restrict__ y2bg,
    const unsigned* __restrict__ rsbg, const unsigned* __restrict__ ebg, const unsigned short* __restrict__ ybg,
    float* __restrict__ hg, const unsigned short* __restrict__ Wfg, const float* __restrict__ Bg,
    unsigned short* __restrict__ y2gb)
{
    __shared__ __align__(16) short lx[32 * 40];
    __shared__ __align__(16) float lo[32 * 100];
    int b = blockIdx.x;
    if (b < NB_PL_BUS)
        pull_tf_body<3, true>(b, N_BUS, rsbb, ebb, ybb, rsgb, egb, ygb,
                              hb, Wfb, Bb, y2bb, y2bg, lx, lo);
    else
        pull_tf_body<2, false>(b - NB_PL_BUS, N_GEN, rsbg, ebg, ybg,
                               nullptr, nullptr, nullptr,
                               hg, Wfg, Bg, y2gb, nullptr, lx, lo);
}

// ---------------------------------------------------------------------------
// Final pull + fused head -> d_out (8 threads/node, unchanged structure).
__device__ __forceinline__ void pull_head_body(
    int blk, bool hasB, int n,
    const unsigned* __restrict__ rsA, const unsigned* __restrict__ eA, const unsigned short* __restrict__ yA,
    const unsigned* __restrict__ rsB, const unsigned* __restrict__ eB, const unsigned short* __restrict__ yB,
    const float* __restrict__ h,
    const float* __restrict__ We, const float* __restrict__ be, int DOUT, float* __restrict__ outp)
{
    const int tid = threadIdx.x;
    unsigned node = blk * 32u + (tid >> 3);
    int j = (tid & 7) * 4;
    if (node >= (unsigned)n) return;

    float4 r = *(const float4*)(h + (size_t)node * H + j);  // root term

    agg_one(rsA[node], eA, yA, j, r);
    if (hasB) agg_one(rsB[node], eB, yB, j, r);

    float p0 = fmaxf(r.x, 0.f), p1 = fmaxf(r.y, 0.f), p2 = fmaxf(r.z, 0.f), p3 = fmaxf(r.w, 0.f);
    float tot[4];
#pragma unroll
    for (int c = 0; c < 4; c++) {
        if (c < DOUT) {
            tot[c] = p0 * We[(j + 0) * DOUT + c] + p1 * We[(j + 1) * DOUT + c]
                   + p2 * We[(j + 2) * DOUT + c] + p3 * We[(j + 3) * DOUT + c];
        } else tot[c] = 0.f;
    }
#pragma unroll
    for (int mask = 1; mask <= 4; mask <<= 1) {
#pragma unroll
        for (int c = 0; c < 4; c++) tot[c] += __shfl_xor(tot[c], mask);
    }
    if ((tid & 7) == 0) {
        if (DOUT == 4) {
            *(float4*)(outp + (size_t)node * 4) =
                make_float4(tot[0] + be[0], tot[1] + be[1], tot[2] + be[2], tot[3] + be[3]);
        } else {
            *(float2*)(outp + (size_t)node * 2) = make_float2(tot[0] + be[0], tot[1] + be[1]);
        }
    }
}

__global__ __launch_bounds__(256) void pull_head_kernel(
    const unsigned* __restrict__ rsbb, const unsigned* __restrict__ ebb, const unsigned short* __restrict__ y2bb,
    const unsigned* __restrict__ rsgb, const unsigned* __restrict__ egb, const unsigned short* __restrict__ y2gb,
    const float* __restrict__ hb, const float* __restrict__ WeB, const float* __restrict__ beB,
    const unsigned* __restrict__ rsbg, const unsigned* __restrict__ ebg, const unsigned short* __restrict__ y2bg,
    const float* __restrict__ hg, const float* __restrict__ WeG, const float* __restrict__ beG,
    float* __restrict__ outp)
{
    int b = blockIdx.x;
    if (b < NB_PL_BUS)
        pull_head_body(b, true, N_BUS, rsbb, ebb, y2bb, rsgb, egb, y2gb, hb, WeB, beB, 4, outp);
    else
        pull_head_body(b - NB_PL_BUS, false, N_GEN, rsbg, ebg, y2bg, nullptr, nullptr, nullptr,
                       hg, WeG, beG, 2, outp + (size_t)N_BUS * 4);
}

// ---------------------------------------------------------------------------
extern "C" void kernel_launch(void* const* d_in, const int* in_sizes, int n_in,
                              void* d_out, int out_size, void* d_ws, size_t ws_size,
                              hipStream_t stream) {
    const float* x_bus = (const float*)d_in[0];
    const float* x_gen = (const float*)d_in[1];
    const int* src_bb = (const int*)d_in[2];
    const int* dst_bb = (const int*)d_in[3];
    const int* src_gb = (const int*)d_in[4];
    const int* dst_gb = (const int*)d_in[5];
    const int* src_bg = (const int*)d_in[6];
    const int* dst_bg = (const int*)d_in[7];
    const float* l1_bb_Wl = (const float*)d_in[8];
    const float* l1_bb_bl = (const float*)d_in[9];
    const float* l1_bb_Wr = (const float*)d_in[10];
    const float* l1_gb_Wl = (const float*)d_in[11];
    const float* l1_gb_bl = (const float*)d_in[12];
    const float* l1_gb_Wr = (const float*)d_in[13];
    const float* l1_bg_Wl = (const float*)d_in[14];
    const float* l1_bg_bl = (const float*)d_in[15];
    const float* l1_bg_Wr = (const float*)d_in[16];
    const float* l2_bb_Wl = (const float*)d_in[17];
    const float* l2_bb_bl = (const float*)d_in[18];
    const float* l2_bb_Wr = (const float*)d_in[19];
    const float* l2_gb_Wl = (const float*)d_in[20];
    const float* l2_gb_bl = (const float*)d_in[21];
    const float* l2_gb_Wr = (const float*)d_in[22];
    const float* l2_bg_Wl = (const float*)d_in[23];
    const float* l2_bg_bl = (const float*)d_in[24];
    const float* l2_bg_Wr = (const float*)d_in[25];
    const float* lin0_bus_W = (const float*)d_in[26];
    const float* lin0_bus_b = (const float*)d_in[27];
    const float* linf_bus_W = (const float*)d_in[28];
    const float* linf_bus_b = (const float*)d_in[29];
    const float* lin0_gen_W = (const float*)d_in[30];
    const float* lin0_gen_b = (const float*)d_in[31];
    const float* linf_gen_W = (const float*)d_in[32];
    const float* linf_gen_b = (const float*)d_in[33];

    // Workspace layout (~125 MB).
    char* ws = (char*)d_ws;
    size_t off = 0;
    auto alloc = [&](size_t bytes) {
        char* p = ws + off;
        off += (bytes + 255) & ~(size_t)255;
        return p;
    };
    unsigned* rs_bb = (unsigned*)alloc((size_t)N_BUS * 4);
    unsigned* rs_gb = (unsigned*)alloc((size_t)N_BUS * 4);
    unsigned* rs_bg = (unsigned*)alloc((size_t)N_GEN * 4);
    unsigned* cur_bb = (unsigned*)alloc(NBINS * 4);   // three cursor arrays contiguous
    unsigned* cur_gb = (unsigned*)alloc(NBINS * 4);
    unsigned* cur_bg = (unsigned*)alloc(NBINS * 4);
    unsigned* e_bb = (unsigned*)alloc((size_t)NBK_BUS * CAP_BB * 4);
    unsigned* e_gb = (unsigned*)alloc((size_t)NBK_BUS * CAP_GB * 4);
    unsigned* e_bg = (unsigned*)alloc((size_t)NBK_GEN * CAP_BG * 4);
    unsigned* p_bb = (unsigned*)alloc((size_t)NBK_BUS * CAP_BB * 4);
    unsigned* p_gb = (unsigned*)alloc((size_t)NBK_BUS * CAP_GB * 4);
    unsigned* p_bg = (unsigned*)alloc((size_t)NBK_GEN * CAP_BG * 4);
    unsigned short* y_bb = (unsigned short*)alloc((size_t)N_BUS * H * 2);  // bf16
    unsigned short* y_bg = (unsigned short*)alloc((size_t)N_BUS * H * 2);  // bf16
    unsigned short* y_gb = (unsigned short*)alloc((size_t)N_GEN * H * 2);  // bf16
    unsigned short* y2_bb = (unsigned short*)alloc((size_t)N_BUS * H * 2); // layer-2 y
    unsigned short* y2_bg = (unsigned short*)alloc((size_t)N_BUS * H * 2);
    unsigned short* y2_gb = (unsigned short*)alloc((size_t)N_GEN * H * 2);
    float* h_bus = (float*)alloc((size_t)N_BUS * H * 4);
    float* h_gen = (float*)alloc((size_t)N_GEN * H * 4);
    unsigned short* Wf1b = (unsigned short*)alloc(2 * 6 * 64 * 8 * 2);
    float* B1b = (float*)alloc(96 * 4);
    unsigned short* Wf1g = (unsigned short*)alloc(2 * 4 * 64 * 8 * 2);
    float* B1g = (float*)alloc(64 * 4);
    unsigned short* Wf2b = (unsigned short*)alloc(6 * 64 * 8 * 2);
    float* B2b = (float*)alloc(96 * 4);
    unsigned short* Wf2g = (unsigned short*)alloc(4 * 64 * 8 * 2);
    float* B2g = (float*)alloc(64 * 4);
    float* WeB = (float*)alloc(128 * 4);
    float* beB = (float*)alloc(4 * 4);
    float* WeG = (float*)alloc(64 * 4);
    float* beG = (float*)alloc(2 * 4);

    // L0: zero the three contiguous cursor arrays.
    zero_kernel<<<12, 256, 0, stream>>>(cur_bb);

    // L1: [part | prep].
    prep_part_kernel<<<NB_PART_ALL + NB_PREP, 256, 0, stream>>>(
        src_bb, dst_bb, cur_bb, p_bb, src_gb, dst_gb, cur_gb, p_gb,
        src_bg, dst_bg, cur_bg, p_bg,
        l1_bb_Wl, l1_bb_bl, l1_bb_Wr, l1_gb_Wl, l1_gb_bl, l1_gb_Wr,
        l1_bg_Wl, l1_bg_bl, l1_bg_Wr, l2_bb_Wl, l2_bb_bl, l2_bb_Wr,
        l2_gb_Wl, l2_gb_bl, l2_gb_Wr, l2_bg_Wl, l2_bg_bl, l2_bg_Wr,
        lin0_bus_W, lin0_bus_b, linf_bus_W, linf_bus_b,
        lin0_gen_W, lin0_gen_b, linf_gen_W, linf_gen_b,
        Wf1b, B1b, Wf1g, B1g, Wf2b, B2b, Wf2g, B2g, WeB, beB, WeG, beG);

    // L2: [tf1 (128-row tiles) | fine].
    tf1_fine_kernel<<<NB_TF1_ALL + NB_FINE_ALL, 256, 0, stream>>>(
        x_bus, Wf1b, B1b, y_bb, y_bg, h_bus, x_gen, Wf1g, B1g, y_gb, h_gen,
        cur_bb, p_bb, rs_bb, e_bb, cur_gb, p_gb, rs_gb, e_gb, cur_bg, p_bg, rs_bg, e_bg);

    // L3: FUSED layer-1 pull + layer-2 transform (32-node blocks, in-block MFMA).
    pull_tf2_kernel<<<NB_PL_BUS + NB_PL_GEN, 256, 0, stream>>>(
        rs_bb, e_bb, y_bb, rs_gb, e_gb, y_gb, h_bus, Wf2b, B2b, y2_bb, y2_bg,
        rs_bg, e_bg, y_bg, h_gen, Wf2g, B2g, y2_gb);

    // L4: layer-2 pull + fused head -> d_out.
    pull_head_kernel<<<NB_PL_BUS + NB_PL_GEN, 256, 0, stream>>>(
        rs_bb, e_bb, y2_bb, rs_gb, e_gb, y2_gb, h_bus, WeB, beB,
        rs_bg, e_bg, y2_bg, h_gen, WeG, beG, (float*)d_out);
}

// Round 8
// 344.963 us; speedup vs baseline: 1.0413x; 1.0145x over previous
//
#include <hip/hip_runtime.h>
#include <hip/hip_bf16.h>

#define N_BUS 200000
#define N_GEN 50000
#define E_BB 1600000
#define E_GB 400000
#define E_BG 400000
#define H 32
#define NBINS 1024   // max coarse buckets (>= ceil(200000/256) = 782)
#define EPT 16       // edges per thread in partition (chunk = 4096)

#define NBK_BUS 782      // buckets for bus-dst relations
#define NBK_GEN 196      // buckets for gen-dst relations
#define CAP_BB 2560      // mean 2046 + >11 sigma
#define CAP_GB 768       // mean 512  + >11 sigma
#define CAP_BG 2560      // mean 2041 + >11 sigma

#define NB_PART_BB 391   // ceil(E_BB/4096)
#define NB_PART_GB 98
#define NB_PART_BG 98
#define NB_PART_ALL 587
#define NB_PREP 32
#define NB_TF1_BUS 1563  // ceil(200000/128)
#define NB_TF1_GEN 391   // ceil(50000/128)
#define NB_TF1_ALL 1954
#define NB_FINE_ALL 1760 // 2*NBK_BUS + NBK_GEN
#define NB_PL_BUS 6250   // ceil(N_BUS/32)
#define NB_PL_GEN 1563

#define PNONE 0xFFFFFFFFu

typedef __attribute__((ext_vector_type(8))) short short8;
typedef __attribute__((ext_vector_type(4))) float floatx4;

__device__ inline unsigned short f2bf(float f) {
    __hip_bfloat16 h = __float2bfloat16(f);   // RNE
    return *reinterpret_cast<unsigned short*>(&h);
}
__device__ inline float bf2f(unsigned short u) {
    return __uint_as_float(((unsigned)u) << 16);
}

// ---------------------------------------------------------------------------
// Block-wide exclusive scan over one unsigned per thread (256 threads).
// Wave-level shfl scan + 4-entry cross-wave LDS; ONE barrier (vs 20).
__device__ __forceinline__ unsigned block_excl_scan(unsigned s, unsigned* wsum) {
    const int lane = threadIdx.x & 63, wv = threadIdx.x >> 6;
    unsigned scan = s;
#pragma unroll
    for (int d = 1; d < 64; d <<= 1) {
        unsigned t = __shfl_up(scan, d, 64);
        if (lane >= d) scan += t;
    }
    if (lane == 63) wsum[wv] = scan;
    __syncthreads();
    unsigned base = 0;
    for (int i = 0; i < wv; i++) base += wsum[i];
    return base + scan - s;   // exclusive prefix for this thread's value
}

// ---------------------------------------------------------------------------
// Zero the 3 contiguous cursor arrays.
__global__ __launch_bounds__(256) void zero_kernel(unsigned* __restrict__ p) {
    int i = blockIdx.x * 256 + threadIdx.x;
    if (i < 3 * NBINS) p[i] = 0u;
}

// ---------------------------------------------------------------------------
// Partition into fixed-capacity buckets. Block-local LDS counting sort so the
// global pairs[] write streams out in position order. pairs = (dst&255)<<24|src.
__device__ __forceinline__ void part_body(int blk, const int* __restrict__ src,
                                          const int* __restrict__ dst, int nE,
                                          unsigned* __restrict__ cnt_g, int CAP,
                                          unsigned* __restrict__ pairs) {
    __shared__ unsigned hist[NBINS];
    __shared__ unsigned base[NBINS];    // global target base per bin
    __shared__ unsigned sbase[NBINS];   // block-local exclusive scan per bin
    __shared__ unsigned wsum[4];
    __shared__ unsigned pairv[256 * EPT];
    __shared__ unsigned short bid[256 * EPT];
    const int tid = threadIdx.x;
    const int cbase = blk * (256 * EPT);
    const int total = min(256 * EPT, nE - cbase);

    unsigned es[EPT], ed[EPT];
#pragma unroll
    for (int q = 0; q < EPT; q++) {
        int i = cbase + q * 256 + tid;
        if (i < nE) { es[q] = (unsigned)src[i]; ed[q] = (unsigned)dst[i]; }
        else ed[q] = PNONE;
    }
    for (int i = tid; i < NBINS; i += 256) hist[i] = 0;
    __syncthreads();
#pragma unroll
    for (int q = 0; q < EPT; q++)
        if (ed[q] != PNONE) atomicAdd(&hist[ed[q] >> 8], 1u);
    __syncthreads();

    // Block-local exclusive scan over the 1024 bins (4 bins/thread, wave scan).
    unsigned h4[4];
    unsigned s = 0;
#pragma unroll
    for (int k2 = 0; k2 < 4; k2++) { h4[k2] = hist[tid * 4 + k2]; s += h4[k2]; }
    unsigned run = block_excl_scan(s, wsum);
#pragma unroll
    for (int k2 = 0; k2 < 4; k2++) {
        int b = tid * 4 + k2;
        sbase[b] = run;
        base[b] = h4[k2] ? ((unsigned)b * CAP + atomicAdd(&cnt_g[b], h4[k2])) : 0u;
        hist[b] = 0;  // reuse as local cursor
        run += h4[k2];
    }
    __syncthreads();

    // Place pairs into the block-sorted LDS staging.
#pragma unroll
    for (int q = 0; q < EPT; q++) {
        if (ed[q] != PNONE) {
            unsigned b = ed[q] >> 8;
            unsigned off = atomicAdd(&hist[b], 1u);
            unsigned p = sbase[b] + off;
            pairv[p] = ((ed[q] & 255u) << 24) | es[q];
            bid[p] = (unsigned short)b;
        }
    }
    __syncthreads();

    // Stream out: consecutive p within a bucket -> consecutive global addr.
    for (int p = tid; p < total; p += 256) {
        unsigned b = bid[p];
        pairs[base[b] + ((unsigned)p - sbase[b])] = pairv[p];
    }
}

// ---------------------------------------------------------------------------
// Prep body (grid-striding over NB_PREP*256 threads): bf16 MFMA B-fragments +
// fused biases + fused head matrices.
__device__ __forceinline__ void prep_body(int pb,
    const float* __restrict__ l1_bb_Wl, const float* __restrict__ l1_bb_bl, const float* __restrict__ l1_bb_Wr,
    const float* __restrict__ l1_gb_Wl, const float* __restrict__ l1_gb_bl, const float* __restrict__ l1_gb_Wr,
    const float* __restrict__ l1_bg_Wl, const float* __restrict__ l1_bg_bl, const float* __restrict__ l1_bg_Wr,
    const float* __restrict__ l2_bb_Wl, const float* __restrict__ l2_bb_bl, const float* __restrict__ l2_bb_Wr,
    const float* __restrict__ l2_gb_Wl, const float* __restrict__ l2_gb_bl, const float* __restrict__ l2_gb_Wr,
    const float* __restrict__ l2_bg_Wl, const float* __restrict__ l2_bg_bl, const float* __restrict__ l2_bg_Wr,
    const float* __restrict__ lin0_bus_W, const float* __restrict__ lin0_bus_b,
    const float* __restrict__ linf_bus_W, const float* __restrict__ linf_bus_b,
    const float* __restrict__ lin0_gen_W, const float* __restrict__ lin0_gen_b,
    const float* __restrict__ linf_gen_W, const float* __restrict__ linf_gen_b,
    unsigned short* __restrict__ Wf1b, float* __restrict__ B1b,
    unsigned short* __restrict__ Wf1g, float* __restrict__ B1g,
    unsigned short* __restrict__ Wf2b, float* __restrict__ B2b,
    unsigned short* __restrict__ Wf2g, float* __restrict__ B2g,
    float* __restrict__ WeB, float* __restrict__ beB,
    float* __restrict__ WeG, float* __restrict__ beG)
{
    int t0 = pb * 256 + threadIdx.x;
    const int NT = NB_PREP * 256;

    // L1 bus: KT=2, NTN=6
    for (int f = t0; f < 2 * 6 * 64 * 8; f += NT) {
        int j = f & 7, l = (f >> 3) & 63, tile = f >> 9;
        int nt = tile % 6, kt = tile / 6;
        int k = kt * 32 + (l >> 4) * 8 + j, n = nt * 16 + (l & 15);
        float v;
        if (n < 32) v = l1_bb_Wl[k * 32 + n];
        else if (n < 64) v = l1_bg_Wl[k * 32 + n - 32];
        else v = l1_bb_Wr[k * 32 + n - 64] + l1_gb_Wr[k * 32 + n - 64];
        Wf1b[f] = f2bf(v);
    }
    // L1 gen: KT=2, NTN=4
    for (int f = t0; f < 2 * 4 * 64 * 8; f += NT) {
        int j = f & 7, l = (f >> 3) & 63, tile = f >> 9;
        int nt = tile % 4, kt = tile / 4;
        int k = kt * 32 + (l >> 4) * 8 + j, n = nt * 16 + (l & 15);
        float v = (n < 32) ? l1_gb_Wl[k * 32 + n] : l1_bg_Wr[k * 32 + n - 32];
        Wf1g[f] = f2bf(v);
    }
    // L2 bus: KT=1, NTN=6
    for (int f = t0; f < 6 * 64 * 8; f += NT) {
        int j = f & 7, l = (f >> 3) & 63, nt = f >> 9;
        int k = (l >> 4) * 8 + j, n = nt * 16 + (l & 15);
        float v;
        if (n < 32) v = l2_bb_Wl[k * 32 + n];
        else if (n < 64) v = l2_bg_Wl[k * 32 + n - 32];
        else v = l2_bb_Wr[k * 32 + n - 64] + l2_gb_Wr[k * 32 + n - 64];
        Wf2b[f] = f2bf(v);
    }
    // L2 gen: KT=1, NTN=4
    for (int f = t0; f < 4 * 64 * 8; f += NT) {
        int j = f & 7, l = (f >> 3) & 63, nt = f >> 9;
        int k = (l >> 4) * 8 + j, n = nt * 16 + (l & 15);
        float v = (n < 32) ? l2_gb_Wl[k * 32 + n] : l2_bg_Wr[k * 32 + n - 32];
        Wf2g[f] = f2bf(v);
    }
    if (t0 < 96) {
        B1b[t0] = (t0 < 64) ? 0.0f : l1_bb_bl[t0 - 64] + l1_gb_bl[t0 - 64];
        B2b[t0] = (t0 < 64) ? 0.0f : l2_bb_bl[t0 - 64] + l2_gb_bl[t0 - 64];
    }
    if (t0 < 64) {
        B1g[t0] = (t0 < 32) ? 0.0f : l1_bg_bl[t0 - 32];
        B2g[t0] = (t0 < 32) ? 0.0f : l2_bg_bl[t0 - 32];
    }
    // Fused head: bus We (32x4) + be(4); gen We (32x2) + be(2)
    if (t0 < 128) {
        int k = t0 >> 2, c = t0 & 3;
        float s = 0.0f;
        for (int m = 0; m < 32; m++) s += lin0_bus_W[k * 32 + m] * linf_bus_W[m * 4 + c];
        WeB[t0] = s;
    }
    if (t0 >= 128 && t0 < 132) {
        int c = t0 - 128;
        float s = linf_bus_b[c];
        for (int m = 0; m < 32; m++) s += lin0_bus_b[m] * linf_bus_W[m * 4 + c];
        beB[c] = s;
    }
    if (t0 >= 132 && t0 < 196) {
        int i = t0 - 132, k = i >> 1, c = i & 1;
        float s = 0.0f;
        for (int m = 0; m < 32; m++) s += lin0_gen_W[k * 32 + m] * linf_gen_W[m * 2 + c];
        WeG[i] = s;
    }
    if (t0 >= 196 && t0 < 198) {
        int c = t0 - 196;
        float s = linf_gen_b[c];
        for (int m = 0; m < 32; m++) s += lin0_gen_b[m] * linf_gen_W[m * 2 + c];
        beG[c] = s;
    }
}

// Merged [part | prep] launch.
__global__ __launch_bounds__(256) void prep_part_kernel(
    const int* __restrict__ sbb, const int* __restrict__ dbb, unsigned* __restrict__ cbb, unsigned* __restrict__ pbb,
    const int* __restrict__ sgb, const int* __restrict__ dgb, unsigned* __restrict__ cgb, unsigned* __restrict__ pgb,
    const int* __restrict__ sbg, const int* __restrict__ dbg, unsigned* __restrict__ cbg, unsigned* __restrict__ pbg,
    const float* __restrict__ l1_bb_Wl, const float* __restrict__ l1_bb_bl, const float* __restrict__ l1_bb_Wr,
    const float* __restrict__ l1_gb_Wl, const float* __restrict__ l1_gb_bl, const float* __restrict__ l1_gb_Wr,
    const float* __restrict__ l1_bg_Wl, const float* __restrict__ l1_bg_bl, const float* __restrict__ l1_bg_Wr,
    const float* __restrict__ l2_bb_Wl, const float* __restrict__ l2_bb_bl, const float* __restrict__ l2_bb_Wr,
    const float* __restrict__ l2_gb_Wl, const float* __restrict__ l2_gb_bl, const float* __restrict__ l2_gb_Wr,
    const float* __restrict__ l2_bg_Wl, const float* __restrict__ l2_bg_bl, const float* __restrict__ l2_bg_Wr,
    const float* __restrict__ lin0_bus_W, const float* __restrict__ lin0_bus_b,
    const float* __restrict__ linf_bus_W, const float* __restrict__ linf_bus_b,
    const float* __restrict__ lin0_gen_W, const float* __restrict__ lin0_gen_b,
    const float* __restrict__ linf_gen_W, const float* __restrict__ linf_gen_b,
    unsigned short* __restrict__ Wf1b, float* __restrict__ B1b,
    unsigned short* __restrict__ Wf1g, float* __restrict__ B1g,
    unsigned short* __restrict__ Wf2b, float* __restrict__ B2b,
    unsigned short* __restrict__ Wf2g, float* __restrict__ B2g,
    float* __restrict__ WeB, float* __restrict__ beB,
    float* __restrict__ WeG, float* __restrict__ beG)
{
    int b = blockIdx.x;
    if (b < NB_PART_BB) part_body(b, sbb, dbb, E_BB, cbb, CAP_BB, pbb);
    else if (b < NB_PART_BB + NB_PART_GB) part_body(b - NB_PART_BB, sgb, dgb, E_GB, cgb, CAP_GB, pgb);
    else if (b < NB_PART_ALL) part_body(b - NB_PART_BB - NB_PART_GB, sbg, dbg, E_BG, cbg, CAP_BG, pbg);
    else prep_body(b - NB_PART_ALL,
                   l1_bb_Wl, l1_bb_bl, l1_bb_Wr, l1_gb_Wl, l1_gb_bl, l1_gb_Wr,
                   l1_bg_Wl, l1_bg_bl, l1_bg_Wr, l2_bb_Wl, l2_bb_bl, l2_bb_Wr,
                   l2_gb_Wl, l2_gb_bl, l2_gb_Wr, l2_bg_Wl, l2_bg_bl, l2_bg_Wr,
                   lin0_bus_W, lin0_bus_b, linf_bus_W, linf_bus_b,
                   lin0_gen_W, lin0_gen_b, linf_gen_W, linf_gen_b,
                   Wf1b, B1b, Wf1g, B1g, Wf2b, B2b, Wf2g, B2g, WeB, beB, WeG, beG);
}

// ---------------------------------------------------------------------------
// Fine CSR: one block per bucket, LDS carved from shared buffer.
// rs[node] packed: (global row start << 9) | degree  (start < 2^21, deg < 512).
__device__ __forceinline__ void fine_body(int b, const unsigned* __restrict__ cnt_g, int CAP,
                                          const unsigned* __restrict__ pairs,
                                          unsigned* __restrict__ rs,
                                          unsigned* __restrict__ esrc, int nDst,
                                          char* __restrict__ lds) {
    unsigned* cnt = (unsigned*)lds;            // 1 KB
    unsigned* wsum = (unsigned*)(lds + 1024);  // 16 B
    unsigned* stg = (unsigned*)(lds + 2048);   // 10 KB (>= max CAP)
    const int tid = threadIdx.x;
    const unsigned start = (unsigned)b * CAP;
    const unsigned m = cnt_g[b];
    const unsigned end = start + m;

    cnt[tid] = 0;
    __syncthreads();
    for (unsigned k = start + tid; k < end; k += 256)
        atomicAdd(&cnt[pairs[k] >> 24], 1u);
    __syncthreads();
    unsigned c = cnt[tid];
    unsigned excl = block_excl_scan(c, wsum);  // contains one barrier
    int gd = b * 256 + tid;
    unsigned rowstart = start + excl;
    if (gd < nDst) rs[gd] = (rowstart << 9) | (c < 511u ? c : 511u);
    cnt[tid] = excl;  // exclusive offset -> cursor (own slot; all loads done)
    __syncthreads();
    for (unsigned k = start + tid; k < end; k += 256) {
        unsigned p = pairs[k];
        unsigned off = atomicAdd(&cnt[p >> 24], 1u);
        stg[off] = p & 0x00FFFFFFu;
    }
    __syncthreads();
    for (unsigned p = tid; p < m; p += 256) esrc[start + p] = stg[p];
}

// ---------------------------------------------------------------------------
// Layer-1 transform body: ROWS-row tile, stage x fp32 -> bf16, MFMA, epilogue.
// bf fragments loaded per-kt inside the loop to cut register liveness.
template <int K, int NOUT, int ROWS>
__device__ __forceinline__ void transform_body(
    int blk, const float* x, int n,
    const unsigned short* __restrict__ Wf, const float* __restrict__ bias,
    unsigned short* __restrict__ y0, unsigned short* __restrict__ y1, float* h,
    char* ldsraw)
{
    constexpr int XS = K + 8;  // shorts
    constexpr int KT = K / 32, NTN = NOUT / 16, NCH = NOUT / 32;
    constexpr int MTW = ROWS / 64;   // 16-row m-tiles per wave
    constexpr int OS = 34;           // floats
    short* lx = (short*)ldsraw;
    float* lo = (float*)ldsraw;
    const int tid = threadIdx.x;
    const int base = blk * ROWS;
    const int rows = min(ROWS, n - base);
    const int w = tid >> 6, l = tid & 63, quad = l >> 4, ln = l & 15;

    {   // stage
        const float4* xg = (const float4*)(x + (size_t)base * K);
        const int T4 = rows * (K / 4);
        for (int q = tid; q < T4; q += 256) {
            float4 v = xg[q];
            int r = q / (K / 4), c = (q % (K / 4)) * 4;
            short4 s4;
            s4.x = (short)f2bf(v.x); s4.y = (short)f2bf(v.y);
            s4.z = (short)f2bf(v.z); s4.w = (short)f2bf(v.w);
            *(short4*)&lx[r * XS + c] = s4;
        }
    }
    __syncthreads();

    const short8* wf8 = (const short8*)Wf;
    float bv[NTN];
#pragma unroll
    for (int nt = 0; nt < NTN; nt++) bv[nt] = bias[nt * 16 + ln];

    floatx4 acc[MTW][NTN];
#pragma unroll
    for (int mt = 0; mt < MTW; mt++)
#pragma unroll
        for (int nt = 0; nt < NTN; nt++) {
            floatx4 c0 = {bv[nt], bv[nt], bv[nt], bv[nt]};
            acc[mt][nt] = c0;
        }
#pragma unroll
    for (int mt = 0; mt < MTW; mt++) {
        const int row = w * (ROWS / 4) + mt * 16 + ln;
#pragma unroll
        for (int kt = 0; kt < KT; kt++) {
            short8 af = *(const short8*)&lx[row * XS + kt * 32 + quad * 8];
#pragma unroll
            for (int nt = 0; nt < NTN; nt++)
                acc[mt][nt] = __builtin_amdgcn_mfma_f32_16x16x32_bf16(
                    af, wf8[(kt * NTN + nt) * 64 + l], acc[mt][nt], 0, 0, 0);
        }
    }

    // epilogue: per-32-col chunk LDS transpose -> coalesced stores
#pragma unroll
    for (int c = 0; c < NCH; c++) {
        __syncthreads();
#pragma unroll
        for (int mt = 0; mt < MTW; mt++)
#pragma unroll
            for (int d = 0; d < 2; d++) {
                int nt = 2 * c + d;
#pragma unroll
                for (int r = 0; r < 4; r++)
                    lo[(w * (ROWS / 4) + mt * 16 + quad * 4 + r) * OS + d * 16 + ln] = acc[mt][nt][r];
            }
        __syncthreads();
        const int T4 = rows * 8;
        if (c == NCH - 1) {  // h chunk, fp32
            float* og = h + (size_t)base * 32;
            for (int q = tid; q < T4; q += 256) {
                int r = q >> 3, cc = (q & 7) * 4;
                const float* p = &lo[r * OS + cc];
                *(float4*)(og + q * 4) = make_float4(p[0], p[1], p[2], p[3]);
            }
        } else {  // y chunk, bf16
            unsigned short* og = ((c == 0) ? y0 : y1) + (size_t)base * 32;
            for (int q = tid; q < T4; q += 256) {
                int r = q >> 3, cc = (q & 7) * 4;
                const float* p = &lo[r * OS + cc];
                short4 s4;
                s4.x = (short)f2bf(p[0]); s4.y = (short)f2bf(p[1]);
                s4.z = (short)f2bf(p[2]); s4.w = (short)f2bf(p[3]);
                *(short4*)(og + q * 4) = s4;
            }
        }
    }
}

// Merged [tf1 (128-row tiles) | fine] launch.
__global__ __launch_bounds__(256) void tf1_fine_kernel(
    const float* xb, const unsigned short* __restrict__ Wfb, const float* __restrict__ Bb,
    unsigned short* __restrict__ yb0, unsigned short* __restrict__ yb1, float* hb,
    const float* xg, const unsigned short* __restrict__ Wfg, const float* __restrict__ Bg,
    unsigned short* __restrict__ yg0, float* hg,
    const unsigned* __restrict__ cbb, const unsigned* __restrict__ pbb, unsigned* __restrict__ rsbb, unsigned* __restrict__ ebb,
    const unsigned* __restrict__ cgb, const unsigned* __restrict__ pgb, unsigned* __restrict__ rsgb, unsigned* __restrict__ egb,
    const unsigned* __restrict__ cbg, const unsigned* __restrict__ pbg, unsigned* __restrict__ rsbg, unsigned* __restrict__ ebg)
{
    constexpr int XB = 128 * (64 + 8) * 2, OB = 128 * 34 * 4;  // 18432 / 17408
    __shared__ __align__(16) char ldsraw[(XB > OB) ? XB : OB];
    int b = blockIdx.x;
    if (b < NB_TF1_BUS)
        transform_body<64, 96, 128>(b, xb, N_BUS, Wfb, Bb, yb0, yb1, hb, ldsraw);
    else if (b < NB_TF1_ALL)
        transform_body<64, 64, 128>(b - NB_TF1_BUS, xg, N_GEN, Wfg, Bg, yg0, nullptr, hg, ldsraw);
    else {
        int f = b - NB_TF1_ALL;
        if (f < NBK_BUS) fine_body(f, cbb, CAP_BB, pbb, rsbb, ebb, N_BUS, ldsraw);
        else if (f < 2 * NBK_BUS) fine_body(f - NBK_BUS, cgb, CAP_GB, pgb, rsgb, egb, N_BUS, ldsraw);
        else fine_body(f - 2 * NBK_BUS, cbg, CAP_BG, pbg, rsbg, ebg, N_GEN, ldsraw);
    }
}

// ---------------------------------------------------------------------------
// One relation's mean-aggregate into a float4 (cols j..j+3); 4-deep pipeline
// with next-quad index prefetch.
__device__ __forceinline__ void agg_one(
    unsigned u, const unsigned* __restrict__ e,
    const unsigned short* __restrict__ y, int j, float4& r)
{
    unsigned k0 = u >> 9;
    unsigned c = u & 511u;
    unsigned k1 = k0 + c;
    float4 a0 = make_float4(0.f, 0.f, 0.f, 0.f);
    float4 a1 = a0, a2 = a0, a3 = a0;
    unsigned k = k0;
    if (k + 4 <= k1) {
        unsigned s0 = e[k], s1 = e[k + 1], s2 = e[k + 2], s3 = e[k + 3];
        for (; k + 8 <= k1; k += 4) {
            unsigned t0 = e[k + 4], t1 = e[k + 5], t2 = e[k + 6], t3 = e[k + 7];
            ushort4 v0 = *(const ushort4*)(y + (size_t)s0 * H + j);
            ushort4 v1 = *(const ushort4*)(y + (size_t)s1 * H + j);
            ushort4 v2 = *(const ushort4*)(y + (size_t)s2 * H + j);
            ushort4 v3 = *(const ushort4*)(y + (size_t)s3 * H + j);
            a0.x += bf2f(v0.x); a0.y += bf2f(v0.y); a0.z += bf2f(v0.z); a0.w += bf2f(v0.w);
            a1.x += bf2f(v1.x); a1.y += bf2f(v1.y); a1.z += bf2f(v1.z); a1.w += bf2f(v1.w);
            a2.x += bf2f(v2.x); a2.y += bf2f(v2.y); a2.z += bf2f(v2.z); a2.w += bf2f(v2.w);
            a3.x += bf2f(v3.x); a3.y += bf2f(v3.y); a3.z += bf2f(v3.z); a3.w += bf2f(v3.w);
            s0 = t0; s1 = t1; s2 = t2; s3 = t3;
        }
        {
            ushort4 v0 = *(const ushort4*)(y + (size_t)s0 * H + j);
            ushort4 v1 = *(const ushort4*)(y + (size_t)s1 * H + j);
            ushort4 v2 = *(const ushort4*)(y + (size_t)s2 * H + j);
            ushort4 v3 = *(const ushort4*)(y + (size_t)s3 * H + j);
            a0.x += bf2f(v0.x); a0.y += bf2f(v0.y); a0.z += bf2f(v0.z); a0.w += bf2f(v0.w);
            a1.x += bf2f(v1.x); a1.y += bf2f(v1.y); a1.z += bf2f(v1.z); a1.w += bf2f(v1.w);
            a2.x += bf2f(v2.x); a2.y += bf2f(v2.y); a2.z += bf2f(v2.z); a2.w += bf2f(v2.w);
            a3.x += bf2f(v3.x); a3.y += bf2f(v3.y); a3.z += bf2f(v3.z); a3.w += bf2f(v3.w);
            k += 4;
        }
    }
    for (; k < k1; ++k) {
        unsigned s = e[k];
        const ushort4 v = *(const ushort4*)(y + (size_t)s * H + j);
        a0.x += bf2f(v.x); a0.y += bf2f(v.y); a0.z += bf2f(v.z); a0.w += bf2f(v.w);
    }
    a0.x += a1.x + a2.x + a3.x; a0.y += a1.y + a2.y + a3.y;
    a0.z += a1.z + a2.z + a3.z; a0.w += a1.w + a2.w + a3.w;
    float inv = 1.0f / (float)(c > 1u ? c : 1u);
    r.x += a0.x * inv; r.y += a0.y * inv; r.z += a0.z * inv; r.w += a0.w * inv;
}

// ---------------------------------------------------------------------------
// FUSED layer-1 pull + layer-2 transform: 32 nodes/block (pull structure kept
// intact -- full TLP), then a block-local [32 x 32] @ [32 x NOUT] MFMA tile.
// Chunked 2-barrier epilogue (r6 version -- the r7 wide-lo variant regressed).
template <int NTA, bool HASB>
__device__ __forceinline__ void pull_tf_body(
    int blk, int n,
    const unsigned* __restrict__ rsA, const unsigned* __restrict__ eA, const unsigned short* __restrict__ yA,
    const unsigned* __restrict__ rsB, const unsigned* __restrict__ eB, const unsigned short* __restrict__ yB,
    float* __restrict__ h,
    const unsigned short* __restrict__ Wf, const float* __restrict__ bias,
    unsigned short* __restrict__ z0, unsigned short* __restrict__ z1,
    short* __restrict__ lx, float* __restrict__ lo)
{
    constexpr int XS = 40;   // lx row stride (shorts)
    constexpr int OS = 34;   // lo row stride (floats)
    const int tid = threadIdx.x;
    const int row = tid >> 3;
    const int j = (tid & 7) * 4;
    const int base = blk * 32;
    const int node = base + row;
    const bool act = node < n;

    float4 r = make_float4(0.f, 0.f, 0.f, 0.f);
    if (act) {
        r = *(const float4*)(h + (size_t)node * H + j);  // root term
        agg_one(rsA[node], eA, yA, j, r);
        if (HASB) agg_one(rsB[node], eB, yB, j, r);
    }
    short4 s4;
    s4.x = (short)f2bf(fmaxf(r.x, 0.f));
    s4.y = (short)f2bf(fmaxf(r.y, 0.f));
    s4.z = (short)f2bf(fmaxf(r.z, 0.f));
    s4.w = (short)f2bf(fmaxf(r.w, 0.f));
    *(short4*)&lx[row * XS + j] = s4;
    __syncthreads();

    // ---- MFMA: wave w -> m-tile (w&1), n-group (w>>1); acc[i] = n-tile 2i+ngrp
    const int w = tid >> 6, l = tid & 63, quad = l >> 4, ln = l & 15;
    const int mt = w & 1, ngrp = w >> 1;
    const short8* wf8 = (const short8*)Wf;
    floatx4 acc[NTA];
    short8 af = *(const short8*)&lx[(mt * 16 + ln) * XS + quad * 8];
#pragma unroll
    for (int i = 0; i < NTA; i++) {
        int nt = 2 * i + ngrp;
        float bv = bias[nt * 16 + ln];
        floatx4 c0 = {bv, bv, bv, bv};
        acc[i] = __builtin_amdgcn_mfma_f32_16x16x32_bf16(af, wf8[nt * 64 + l], c0, 0, 0, 0);
    }

    // ---- epilogue: per-32-col chunk LDS transpose -> coalesced stores ----
    const int rows = min(32, n - base);
    const int orow = tid >> 3, oc = (tid & 7) * 4;
#pragma unroll
    for (int c = 0; c < NTA; c++) {
        __syncthreads();
#pragma unroll
        for (int rr = 0; rr < 4; rr++)
            lo[(mt * 16 + quad * 4 + rr) * OS + ngrp * 16 + ln] = acc[c][rr];
        __syncthreads();
        if (orow < rows) {
            const float* p = &lo[orow * OS + oc];
            if (c == NTA - 1) {  // h chunk, fp32 (block-owned rows: in-place OK)
                *(float4*)(h + (size_t)(base + orow) * H + oc) =
                    make_float4(p[0], p[1], p[2], p[3]);
            } else {             // y2 chunk, bf16
                unsigned short* og = (c == 0) ? z0 : z1;
                short4 o;
                o.x = (short)f2bf(p[0]); o.y = (short)f2bf(p[1]);
                o.z = (short)f2bf(p[2]); o.w = (short)f2bf(p[3]);
                *(short4*)(og + (size_t)(base + orow) * H + oc) = o;
            }
        }
    }
}

__global__ __launch_bounds__(256) void pull_tf2_kernel(
    const unsigned* __restrict__ rsbb, const unsigned* __restrict__ ebb, const unsigned short* __restrict__ ybb,
    const unsigned* __restrict__ rsgb, const unsigned* __restrict__ egb, const unsigned short* __restrict__ ygb,
    float* __restrict__ hb, const unsigned short* __restrict__ Wfb, const float* __restrict__ Bb,
    unsigned short* __restrict__ y2bb, unsigned short* __restrict__ y2bg,
    const unsigned* __restrict__ rsbg, const unsigned* __restrict__ ebg, const unsigned short* __restrict__ ybg,
    float* __restrict__ hg, const unsigned short* __restrict__ Wfg, const float* __restrict__ Bg,
    unsigned short* __restrict__ y2gb)
{
    __shared__ __align__(16) short lx[32 * 40];
    __shared__ __align__(16) float lo[32 * 34];
    int b = blockIdx.x;
    if (b < NB_PL_BUS)
        pull_tf_body<3, true>(b, N_BUS, rsbb, ebb, ybb, rsgb, egb, ygb,
                              hb, Wfb, Bb, y2bb, y2bg, lx, lo);
    else
        pull_tf_body<2, false>(b - NB_PL_BUS, N_GEN, rsbg, ebg, ybg,
                               nullptr, nullptr, nullptr,
                               hg, Wfg, Bg, y2gb, nullptr, lx, lo);
}

// ---------------------------------------------------------------------------
// Final pull + fused head -> d_out (8 threads/node, unchanged structure).
__device__ __forceinline__ void pull_head_body(
    int blk, bool hasB, int n,
    const unsigned* __restrict__ rsA, const unsigned* __restrict__ eA, const unsigned short* __restrict__ yA,
    const unsigned* __restrict__ rsB, const unsigned* __restrict__ eB, const unsigned short* __restrict__ yB,
    const float* __restrict__ h,
    const float* __restrict__ We, const float* __restrict__ be, int DOUT, float* __restrict__ outp)
{
    const int tid = threadIdx.x;
    unsigned node = blk * 32u + (tid >> 3);
    int j = (tid & 7) * 4;
    if (node >= (unsigned)n) return;

    float4 r = *(const float4*)(h + (size_t)node * H + j);  // root term

    agg_one(rsA[node], eA, yA, j, r);
    if (hasB) agg_one(rsB[node], eB, yB, j, r);

    float p0 = fmaxf(r.x, 0.f), p1 = fmaxf(r.y, 0.f), p2 = fmaxf(r.z, 0.f), p3 = fmaxf(r.w, 0.f);
    float tot[4];
#pragma unroll
    for (int c = 0; c < 4; c++) {
        if (c < DOUT) {
            tot[c] = p0 * We[(j + 0) * DOUT + c] + p1 * We[(j + 1) * DOUT + c]
                   + p2 * We[(j + 2) * DOUT + c] + p3 * We[(j + 3) * DOUT + c];
        } else tot[c] = 0.f;
    }
#pragma unroll
    for (int mask = 1; mask <= 4; mask <<= 1) {
#pragma unroll
        for (int c = 0; c < 4; c++) tot[c] += __shfl_xor(tot[c], mask);
    }
    if ((tid & 7) == 0) {
        if (DOUT == 4) {
            *(float4*)(outp + (size_t)node * 4) =
                make_float4(tot[0] + be[0], tot[1] + be[1], tot[2] + be[2], tot[3] + be[3]);
        } else {
            *(float2*)(outp + (size_t)node * 2) = make_float2(tot[0] + be[0], tot[1] + be[1]);
        }
    }
}

__global__ __launch_bounds__(256) void pull_head_kernel(
    const unsigned* __restrict__ rsbb, const unsigned* __restrict__ ebb, const unsigned short* __restrict__ y2bb,
    const unsigned* __restrict__ rsgb, const unsigned* __restrict__ egb, const unsigned short* __restrict__ y2gb,
    const float* __restrict__ hb, const float* __restrict__ WeB, const float* __restrict__ beB,
    const unsigned* __restrict__ rsbg, const unsigned* __restrict__ ebg, const unsigned short* __restrict__ y2bg,
    const float* __restrict__ hg, const float* __restrict__ WeG, const float* __restrict__ beG,
    float* __restrict__ outp)
{
    int b = blockIdx.x;
    if (b < NB_PL_BUS)
        pull_head_body(b, true, N_BUS, rsbb, ebb, y2bb, rsgb, egb, y2gb, hb, WeB, beB, 4, outp);
    else
        pull_head_body(b - NB_PL_BUS, false, N_GEN, rsbg, ebg, y2bg, nullptr, nullptr, nullptr,
                       hg, WeG, beG, 2, outp + (size_t)N_BUS * 4);
}

// ---------------------------------------------------------------------------
extern "C" void kernel_launch(void* const* d_in, const int* in_sizes, int n_in,
                              void* d_out, int out_size, void* d_ws, size_t ws_size,
                              hipStream_t stream) {
    const float* x_bus = (const float*)d_in[0];
    const float* x_gen = (const float*)d_in[1];
    const int* src_bb = (const int*)d_in[2];
    const int* dst_bb = (const int*)d_in[3];
    const int* src_gb = (const int*)d_in[4];
    const int* dst_gb = (const int*)d_in[5];
    const int* src_bg = (const int*)d_in[6];
    const int* dst_bg = (const int*)d_in[7];
    const float* l1_bb_Wl = (const float*)d_in[8];
    const float* l1_bb_bl = (const float*)d_in[9];
    const float* l1_bb_Wr = (const float*)d_in[10];
    const float* l1_gb_Wl = (const float*)d_in[11];
    const float* l1_gb_bl = (const float*)d_in[12];
    const float* l1_gb_Wr = (const float*)d_in[13];
    const float* l1_bg_Wl = (const float*)d_in[14];
    const float* l1_bg_bl = (const float*)d_in[15];
    const float* l1_bg_Wr = (const float*)d_in[16];
    const float* l2_bb_Wl = (const float*)d_in[17];
    const float* l2_bb_bl = (const float*)d_in[18];
    const float* l2_bb_Wr = (const float*)d_in[19];
    const float* l2_gb_Wl = (const float*)d_in[20];
    const float* l2_gb_bl = (const float*)d_in[21];
    const float* l2_gb_Wr = (const float*)d_in[22];
    const float* l2_bg_Wl = (const float*)d_in[23];
    const float* l2_bg_bl = (const float*)d_in[24];
    const float* l2_bg_Wr = (const float*)d_in[25];
    const float* lin0_bus_W = (const float*)d_in[26];
    const float* lin0_bus_b = (const float*)d_in[27];
    const float* linf_bus_W = (const float*)d_in[28];
    const float* linf_bus_b = (const float*)d_in[29];
    const float* lin0_gen_W = (const float*)d_in[30];
    const float* lin0_gen_b = (const float*)d_in[31];
    const float* linf_gen_W = (const float*)d_in[32];
    const float* linf_gen_b = (const float*)d_in[33];

    // Workspace layout (~125 MB).
    char* ws = (char*)d_ws;
    size_t off = 0;
    auto alloc = [&](size_t bytes) {
        char* p = ws + off;
        off += (bytes + 255) & ~(size_t)255;
        return p;
    };
    unsigned* rs_bb = (unsigned*)alloc((size_t)N_BUS * 4);
    unsigned* rs_gb = (unsigned*)alloc((size_t)N_BUS * 4);
    unsigned* rs_bg = (unsigned*)alloc((size_t)N_GEN * 4);
    unsigned* cur_bb = (unsigned*)alloc(NBINS * 4);   // three cursor arrays contiguous
    unsigned* cur_gb = (unsigned*)alloc(NBINS * 4);
    unsigned* cur_bg = (unsigned*)alloc(NBINS * 4);
    unsigned* e_bb = (unsigned*)alloc((size_t)NBK_BUS * CAP_BB * 4);
    unsigned* e_gb = (unsigned*)alloc((size_t)NBK_BUS * CAP_GB * 4);
    unsigned* e_bg = (unsigned*)alloc((size_t)NBK_GEN * CAP_BG * 4);
    unsigned* p_bb = (unsigned*)alloc((size_t)NBK_BUS * CAP_BB * 4);
    unsigned* p_gb = (unsigned*)alloc((size_t)NBK_BUS * CAP_GB * 4);
    unsigned* p_bg = (unsigned*)alloc((size_t)NBK_GEN * CAP_BG * 4);
    unsigned short* y_bb = (unsigned short*)alloc((size_t)N_BUS * H * 2);  // bf16
    unsigned short* y_bg = (unsigned short*)alloc((size_t)N_BUS * H * 2);  // bf16
    unsigned short* y_gb = (unsigned short*)alloc((size_t)N_GEN * H * 2);  // bf16
    unsigned short* y2_bb = (unsigned short*)alloc((size_t)N_BUS * H * 2); // layer-2 y
    unsigned short* y2_bg = (unsigned short*)alloc((size_t)N_BUS * H * 2);
    unsigned short* y2_gb = (unsigned short*)alloc((size_t)N_GEN * H * 2);
    float* h_bus = (float*)alloc((size_t)N_BUS * H * 4);
    float* h_gen = (float*)alloc((size_t)N_GEN * H * 4);
    unsigned short* Wf1b = (unsigned short*)alloc(2 * 6 * 64 * 8 * 2);
    float* B1b = (float*)alloc(96 * 4);
    unsigned short* Wf1g = (unsigned short*)alloc(2 * 4 * 64 * 8 * 2);
    float* B1g = (float*)alloc(64 * 4);
    unsigned short* Wf2b = (unsigned short*)alloc(6 * 64 * 8 * 2);
    float* B2b = (float*)alloc(96 * 4);
    unsigned short* Wf2g = (unsigned short*)alloc(4 * 64 * 8 * 2);
    float* B2g = (float*)alloc(64 * 4);
    float* WeB = (float*)alloc(128 * 4);
    float* beB = (float*)alloc(4 * 4);
    float* WeG = (float*)alloc(64 * 4);
    float* beG = (float*)alloc(2 * 4);

    // L0: zero the three contiguous cursor arrays.
    zero_kernel<<<12, 256, 0, stream>>>(cur_bb);

    // L1: [part | prep].
    prep_part_kernel<<<NB_PART_ALL + NB_PREP, 256, 0, stream>>>(
        src_bb, dst_bb, cur_bb, p_bb, src_gb, dst_gb, cur_gb, p_gb,
        src_bg, dst_bg, cur_bg, p_bg,
        l1_bb_Wl, l1_bb_bl, l1_bb_Wr, l1_gb_Wl, l1_gb_bl, l1_gb_Wr,
        l1_bg_Wl, l1_bg_bl, l1_bg_Wr, l2_bb_Wl, l2_bb_bl, l2_bb_Wr,
        l2_gb_Wl, l2_gb_bl, l2_gb_Wr, l2_bg_Wl, l2_bg_bl, l2_bg_Wr,
        lin0_bus_W, lin0_bus_b, linf_bus_W, linf_bus_b,
        lin0_gen_W, lin0_gen_b, linf_gen_W, linf_gen_b,
        Wf1b, B1b, Wf1g, B1g, Wf2b, B2b, Wf2g, B2g, WeB, beB, WeG, beG);

    // L2: [tf1 (128-row tiles) | fine].
    tf1_fine_kernel<<<NB_TF1_ALL + NB_FINE_ALL, 256, 0, stream>>>(
        x_bus, Wf1b, B1b, y_bb, y_bg, h_bus, x_gen, Wf1g, B1g, y_gb, h_gen,
        cur_bb, p_bb, rs_bb, e_bb, cur_gb, p_gb, rs_gb, e_gb, cur_bg, p_bg, rs_bg, e_bg);

    // L3: FUSED layer-1 pull + layer-2 transform (32-node blocks, in-block MFMA).
    pull_tf2_kernel<<<NB_PL_BUS + NB_PL_GEN, 256, 0, stream>>>(
        rs_bb, e_bb, y_bb, rs_gb, e_gb, y_gb, h_bus, Wf2b, B2b, y2_bb, y2_bg,
        rs_bg, e_bg, y_bg, h_gen, Wf2g, B2g, y2_gb);

    // L4: layer-2 pull + fused head -> d_out.
    pull_head_kernel<<<NB_PL_BUS + NB_PL_GEN, 256, 0, stream>>>(
        rs_bb, e_bb, y2_bb, rs_gb, e_gb, y2_gb, h_bus, WeB, beB,
        rs_bg, e_bg, y2_bg, h_gen, WeG, beG, (float*)d_out);
}

// Round 9
// 342.107 us; speedup vs baseline: 1.0499x; 1.0083x over previous
//
#include <hip/hip_runtime.h>
#include <hip/hip_bf16.h>

#define N_BUS 200000
#define N_GEN 50000
#define E_BB 1600000
#define E_GB 400000
#define E_BG 400000
#define H 32
#define NBINS 1024   // max coarse buckets (>= ceil(200000/256) = 782)
#define EPT 16       // edges per thread in partition (chunk = 4096)

#define NBK_BUS 782      // buckets for bus-dst relations
#define NBK_GEN 196      // buckets for gen-dst relations
#define CAP_BB 2560      // mean 2046 + >11 sigma
#define CAP_GB 768       // mean 512  + >11 sigma
#define CAP_BG 2560      // mean 2041 + >11 sigma

#define NB_PART_BB 391   // ceil(E_BB/4096)
#define NB_PART_GB 98
#define NB_PART_BG 98
#define NB_PART_ALL 587
#define NB_PREP 32
#define NB_TF1_BUS 1563  // ceil(200000/128)
#define NB_TF1_GEN 391   // ceil(50000/128)
#define NB_TF1_ALL 1954
#define NB_FINE_ALL 1760 // 2*NBK_BUS + NBK_GEN
#define NB_PL_BUS 6250   // ceil(N_BUS/32)
#define NB_PL_GEN 1563

#define PNONE 0xFFFFFFFFu

typedef __attribute__((ext_vector_type(8))) short short8;
typedef __attribute__((ext_vector_type(4))) float floatx4;

__device__ inline unsigned short f2bf(float f) {
    __hip_bfloat16 h = __float2bfloat16(f);   // RNE
    return *reinterpret_cast<unsigned short*>(&h);
}
__device__ inline float bf2f(unsigned short u) {
    return __uint_as_float(((unsigned)u) << 16);
}

// ---------------------------------------------------------------------------
// Block-wide exclusive scan over one unsigned per thread (256 threads).
// Wave-level shfl scan + 4-entry cross-wave LDS; ONE barrier (vs 20).
__device__ __forceinline__ unsigned block_excl_scan(unsigned s, unsigned* wsum) {
    const int lane = threadIdx.x & 63, wv = threadIdx.x >> 6;
    unsigned scan = s;
#pragma unroll
    for (int d = 1; d < 64; d <<= 1) {
        unsigned t = __shfl_up(scan, d, 64);
        if (lane >= d) scan += t;
    }
    if (lane == 63) wsum[wv] = scan;
    __syncthreads();
    unsigned base = 0;
    for (int i = 0; i < wv; i++) base += wsum[i];
    return base + scan - s;   // exclusive prefix for this thread's value
}

// ---------------------------------------------------------------------------
// Zero the 3 contiguous cursor arrays.
__global__ __launch_bounds__(256) void zero_kernel(unsigned* __restrict__ p) {
    int i = blockIdx.x * 256 + threadIdx.x;
    if (i < 3 * NBINS) p[i] = 0u;
}

// ---------------------------------------------------------------------------
// Partition into fixed-capacity buckets. Block-local LDS counting sort so the
// global pairs[] write streams out in position order. pairs = (dst&255)<<24|src.
__device__ __forceinline__ void part_body(int blk, const int* __restrict__ src,
                                          const int* __restrict__ dst, int nE,
                                          unsigned* __restrict__ cnt_g, int CAP,
                                          unsigned* __restrict__ pairs) {
    __shared__ unsigned hist[NBINS];
    __shared__ unsigned base[NBINS];    // global target base per bin
    __shared__ unsigned sbase[NBINS];   // block-local exclusive scan per bin
    __shared__ unsigned wsum[4];
    __shared__ unsigned pairv[256 * EPT];
    __shared__ unsigned short bid[256 * EPT];
    const int tid = threadIdx.x;
    const int cbase = blk * (256 * EPT);
    const int total = min(256 * EPT, nE - cbase);

    unsigned es[EPT], ed[EPT];
#pragma unroll
    for (int q = 0; q < EPT; q++) {
        int i = cbase + q * 256 + tid;
        if (i < nE) { es[q] = (unsigned)src[i]; ed[q] = (unsigned)dst[i]; }
        else ed[q] = PNONE;
    }
    for (int i = tid; i < NBINS; i += 256) hist[i] = 0;
    __syncthreads();
#pragma unroll
    for (int q = 0; q < EPT; q++)
        if (ed[q] != PNONE) atomicAdd(&hist[ed[q] >> 8], 1u);
    __syncthreads();

    // Block-local exclusive scan over the 1024 bins (4 bins/thread, wave scan).
    unsigned h4[4];
    unsigned s = 0;
#pragma unroll
    for (int k2 = 0; k2 < 4; k2++) { h4[k2] = hist[tid * 4 + k2]; s += h4[k2]; }
    unsigned run = block_excl_scan(s, wsum);
#pragma unroll
    for (int k2 = 0; k2 < 4; k2++) {
        int b = tid * 4 + k2;
        sbase[b] = run;
        base[b] = h4[k2] ? ((unsigned)b * CAP + atomicAdd(&cnt_g[b], h4[k2])) : 0u;
        hist[b] = 0;  // reuse as local cursor
        run += h4[k2];
    }
    __syncthreads();

    // Place pairs into the block-sorted LDS staging.
#pragma unroll
    for (int q = 0; q < EPT; q++) {
        if (ed[q] != PNONE) {
            unsigned b = ed[q] >> 8;
            unsigned off = atomicAdd(&hist[b], 1u);
            unsigned p = sbase[b] + off;
            pairv[p] = ((ed[q] & 255u) << 24) | es[q];
            bid[p] = (unsigned short)b;
        }
    }
    __syncthreads();

    // Stream out: consecutive p within a bucket -> consecutive global addr.
    for (int p = tid; p < total; p += 256) {
        unsigned b = bid[p];
        pairs[base[b] + ((unsigned)p - sbase[b])] = pairv[p];
    }
}

// ---------------------------------------------------------------------------
// Prep body (grid-striding over NB_PREP*256 threads): bf16 MFMA B-fragments +
// fused biases + fused head matrices.
__device__ __forceinline__ void prep_body(int pb,
    const float* __restrict__ l1_bb_Wl, const float* __restrict__ l1_bb_bl, const float* __restrict__ l1_bb_Wr,
    const float* __restrict__ l1_gb_Wl, const float* __restrict__ l1_gb_bl, const float* __restrict__ l1_gb_Wr,
    const float* __restrict__ l1_bg_Wl, const float* __restrict__ l1_bg_bl, const float* __restrict__ l1_bg_Wr,
    const float* __restrict__ l2_bb_Wl, const float* __restrict__ l2_bb_bl, const float* __restrict__ l2_bb_Wr,
    const float* __restrict__ l2_gb_Wl, const float* __restrict__ l2_gb_bl, const float* __restrict__ l2_gb_Wr,
    const float* __restrict__ l2_bg_Wl, const float* __restrict__ l2_bg_bl, const float* __restrict__ l2_bg_Wr,
    const float* __restrict__ lin0_bus_W, const float* __restrict__ lin0_bus_b,
    const float* __restrict__ linf_bus_W, const float* __restrict__ linf_bus_b,
    const float* __restrict__ lin0_gen_W, const float* __restrict__ lin0_gen_b,
    const float* __restrict__ linf_gen_W, const float* __restrict__ linf_gen_b,
    unsigned short* __restrict__ Wf1b, float* __restrict__ B1b,
    unsigned short* __restrict__ Wf1g, float* __restrict__ B1g,
    unsigned short* __restrict__ Wf2b, float* __restrict__ B2b,
    unsigned short* __restrict__ Wf2g, float* __restrict__ B2g,
    float* __restrict__ WeB, float* __restrict__ beB,
    float* __restrict__ WeG, float* __restrict__ beG)
{
    int t0 = pb * 256 + threadIdx.x;
    const int NT = NB_PREP * 256;

    // L1 bus: KT=2, NTN=6
    for (int f = t0; f < 2 * 6 * 64 * 8; f += NT) {
        int j = f & 7, l = (f >> 3) & 63, tile = f >> 9;
        int nt = tile % 6, kt = tile / 6;
        int k = kt * 32 + (l >> 4) * 8 + j, n = nt * 16 + (l & 15);
        float v;
        if (n < 32) v = l1_bb_Wl[k * 32 + n];
        else if (n < 64) v = l1_bg_Wl[k * 32 + n - 32];
        else v = l1_bb_Wr[k * 32 + n - 64] + l1_gb_Wr[k * 32 + n - 64];
        Wf1b[f] = f2bf(v);
    }
    // L1 gen: KT=2, NTN=4
    for (int f = t0; f < 2 * 4 * 64 * 8; f += NT) {
        int j = f & 7, l = (f >> 3) & 63, tile = f >> 9;
        int nt = tile % 4, kt = tile / 4;
        int k = kt * 32 + (l >> 4) * 8 + j, n = nt * 16 + (l & 15);
        float v = (n < 32) ? l1_gb_Wl[k * 32 + n] : l1_bg_Wr[k * 32 + n - 32];
        Wf1g[f] = f2bf(v);
    }
    // L2 bus: KT=1, NTN=6
    for (int f = t0; f < 6 * 64 * 8; f += NT) {
        int j = f & 7, l = (f >> 3) & 63, nt = f >> 9;
        int k = (l >> 4) * 8 + j, n = nt * 16 + (l & 15);
        float v;
        if (n < 32) v = l2_bb_Wl[k * 32 + n];
        else if (n < 64) v = l2_bg_Wl[k * 32 + n - 32];
        else v = l2_bb_Wr[k * 32 + n - 64] + l2_gb_Wr[k * 32 + n - 64];
        Wf2b[f] = f2bf(v);
    }
    // L2 gen: KT=1, NTN=4
    for (int f = t0; f < 4 * 64 * 8; f += NT) {
        int j = f & 7, l = (f >> 3) & 63, nt = f >> 9;
        int k = (l >> 4) * 8 + j, n = nt * 16 + (l & 15);
        float v = (n < 32) ? l2_gb_Wl[k * 32 + n] : l2_bg_Wr[k * 32 + n - 32];
        Wf2g[f] = f2bf(v);
    }
    if (t0 < 96) {
        B1b[t0] = (t0 < 64) ? 0.0f : l1_bb_bl[t0 - 64] + l1_gb_bl[t0 - 64];
        B2b[t0] = (t0 < 64) ? 0.0f : l2_bb_bl[t0 - 64] + l2_gb_bl[t0 - 64];
    }
    if (t0 < 64) {
        B1g[t0] = (t0 < 32) ? 0.0f : l1_bg_bl[t0 - 32];
        B2g[t0] = (t0 < 32) ? 0.0f : l2_bg_bl[t0 - 32];
    }
    // Fused head: bus We (32x4) + be(4); gen We (32x2) + be(2)
    if (t0 < 128) {
        int k = t0 >> 2, c = t0 & 3;
        float s = 0.0f;
        for (int m = 0; m < 32; m++) s += lin0_bus_W[k * 32 + m] * linf_bus_W[m * 4 + c];
        WeB[t0] = s;
    }
    if (t0 >= 128 && t0 < 132) {
        int c = t0 - 128;
        float s = linf_bus_b[c];
        for (int m = 0; m < 32; m++) s += lin0_bus_b[m] * linf_bus_W[m * 4 + c];
        beB[c] = s;
    }
    if (t0 >= 132 && t0 < 196) {
        int i = t0 - 132, k = i >> 1, c = i & 1;
        float s = 0.0f;
        for (int m = 0; m < 32; m++) s += lin0_gen_W[k * 32 + m] * linf_gen_W[m * 2 + c];
        WeG[i] = s;
    }
    if (t0 >= 196 && t0 < 198) {
        int c = t0 - 196;
        float s = linf_gen_b[c];
        for (int m = 0; m < 32; m++) s += lin0_gen_b[m] * linf_gen_W[m * 2 + c];
        beG[c] = s;
    }
}

// Merged [part | prep] launch.
__global__ __launch_bounds__(256) void prep_part_kernel(
    const int* __restrict__ sbb, const int* __restrict__ dbb, unsigned* __restrict__ cbb, unsigned* __restrict__ pbb,
    const int* __restrict__ sgb, const int* __restrict__ dgb, unsigned* __restrict__ cgb, unsigned* __restrict__ pgb,
    const int* __restrict__ sbg, const int* __restrict__ dbg, unsigned* __restrict__ cbg, unsigned* __restrict__ pbg,
    const float* __restrict__ l1_bb_Wl, const float* __restrict__ l1_bb_bl, const float* __restrict__ l1_bb_Wr,
    const float* __restrict__ l1_gb_Wl, const float* __restrict__ l1_gb_bl, const float* __restrict__ l1_gb_Wr,
    const float* __restrict__ l1_bg_Wl, const float* __restrict__ l1_bg_bl, const float* __restrict__ l1_bg_Wr,
    const float* __restrict__ l2_bb_Wl, const float* __restrict__ l2_bb_bl, const float* __restrict__ l2_bb_Wr,
    const float* __restrict__ l2_gb_Wl, const float* __restrict__ l2_gb_bl, const float* __restrict__ l2_gb_Wr,
    const float* __restrict__ l2_bg_Wl, const float* __restrict__ l2_bg_bl, const float* __restrict__ l2_bg_Wr,
    const float* __restrict__ lin0_bus_W, const float* __restrict__ lin0_bus_b,
    const float* __restrict__ linf_bus_W, const float* __restrict__ linf_bus_b,
    const float* __restrict__ lin0_gen_W, const float* __restrict__ lin0_gen_b,
    const float* __restrict__ linf_gen_W, const float* __restrict__ linf_gen_b,
    unsigned short* __restrict__ Wf1b, float* __restrict__ B1b,
    unsigned short* __restrict__ Wf1g, float* __restrict__ B1g,
    unsigned short* __restrict__ Wf2b, float* __restrict__ B2b,
    unsigned short* __restrict__ Wf2g, float* __restrict__ B2g,
    float* __restrict__ WeB, float* __restrict__ beB,
    float* __restrict__ WeG, float* __restrict__ beG)
{
    int b = blockIdx.x;
    if (b < NB_PART_BB) part_body(b, sbb, dbb, E_BB, cbb, CAP_BB, pbb);
    else if (b < NB_PART_BB + NB_PART_GB) part_body(b - NB_PART_BB, sgb, dgb, E_GB, cgb, CAP_GB, pgb);
    else if (b < NB_PART_ALL) part_body(b - NB_PART_BB - NB_PART_GB, sbg, dbg, E_BG, cbg, CAP_BG, pbg);
    else prep_body(b - NB_PART_ALL,
                   l1_bb_Wl, l1_bb_bl, l1_bb_Wr, l1_gb_Wl, l1_gb_bl, l1_gb_Wr,
                   l1_bg_Wl, l1_bg_bl, l1_bg_Wr, l2_bb_Wl, l2_bb_bl, l2_bb_Wr,
                   l2_gb_Wl, l2_gb_bl, l2_gb_Wr, l2_bg_Wl, l2_bg_bl, l2_bg_Wr,
                   lin0_bus_W, lin0_bus_b, linf_bus_W, linf_bus_b,
                   lin0_gen_W, lin0_gen_b, linf_gen_W, linf_gen_b,
                   Wf1b, B1b, Wf1g, B1g, Wf2b, B2b, Wf2g, B2g, WeB, beB, WeG, beG);
}

// ---------------------------------------------------------------------------
// Fine CSR: one block per bucket, LDS carved from shared buffer.
// rs[node] packed: (global row start << 9) | degree  (start < 2^21, deg < 512).
__device__ __forceinline__ void fine_body(int b, const unsigned* __restrict__ cnt_g, int CAP,
                                          const unsigned* __restrict__ pairs,
                                          unsigned* __restrict__ rs,
                                          unsigned* __restrict__ esrc, int nDst,
                                          char* __restrict__ lds) {
    unsigned* cnt = (unsigned*)lds;            // 1 KB
    unsigned* wsum = (unsigned*)(lds + 1024);  // 16 B
    unsigned* stg = (unsigned*)(lds + 2048);   // 10 KB (>= max CAP)
    const int tid = threadIdx.x;
    const unsigned start = (unsigned)b * CAP;
    const unsigned m = cnt_g[b];
    const unsigned end = start + m;

    cnt[tid] = 0;
    __syncthreads();
    for (unsigned k = start + tid; k < end; k += 256)
        atomicAdd(&cnt[pairs[k] >> 24], 1u);
    __syncthreads();
    unsigned c = cnt[tid];
    unsigned excl = block_excl_scan(c, wsum);  // contains one barrier
    int gd = b * 256 + tid;
    unsigned rowstart = start + excl;
    if (gd < nDst) rs[gd] = (rowstart << 9) | (c < 511u ? c : 511u);
    cnt[tid] = excl;  // exclusive offset -> cursor (own slot; all loads done)
    __syncthreads();
    for (unsigned k = start + tid; k < end; k += 256) {
        unsigned p = pairs[k];
        unsigned off = atomicAdd(&cnt[p >> 24], 1u);
        stg[off] = p & 0x00FFFFFFu;
    }
    __syncthreads();
    for (unsigned p = tid; p < m; p += 256) esrc[start + p] = stg[p];
}

// ---------------------------------------------------------------------------
// Layer-1 transform body: ROWS-row tile, stage x fp32 -> bf16, MFMA, epilogue.
// ALL outputs (y0, y1, h) now bf16 -- h fp32->bf16 saves 16 MB write here and
// 16 MB read in pull_tf2.
template <int K, int NOUT, int ROWS>
__device__ __forceinline__ void transform_body(
    int blk, const float* x, int n,
    const unsigned short* __restrict__ Wf, const float* __restrict__ bias,
    unsigned short* __restrict__ y0, unsigned short* __restrict__ y1,
    unsigned short* __restrict__ h,
    char* ldsraw)
{
    constexpr int XS = K + 8;  // shorts
    constexpr int KT = K / 32, NTN = NOUT / 16, NCH = NOUT / 32;
    constexpr int MTW = ROWS / 64;   // 16-row m-tiles per wave
    constexpr int OS = 34;           // floats
    short* lx = (short*)ldsraw;
    float* lo = (float*)ldsraw;
    const int tid = threadIdx.x;
    const int base = blk * ROWS;
    const int rows = min(ROWS, n - base);
    const int w = tid >> 6, l = tid & 63, quad = l >> 4, ln = l & 15;

    {   // stage
        const float4* xg = (const float4*)(x + (size_t)base * K);
        const int T4 = rows * (K / 4);
        for (int q = tid; q < T4; q += 256) {
            float4 v = xg[q];
            int r = q / (K / 4), c = (q % (K / 4)) * 4;
            short4 s4;
            s4.x = (short)f2bf(v.x); s4.y = (short)f2bf(v.y);
            s4.z = (short)f2bf(v.z); s4.w = (short)f2bf(v.w);
            *(short4*)&lx[r * XS + c] = s4;
        }
    }
    __syncthreads();

    const short8* wf8 = (const short8*)Wf;
    float bv[NTN];
#pragma unroll
    for (int nt = 0; nt < NTN; nt++) bv[nt] = bias[nt * 16 + ln];

    floatx4 acc[MTW][NTN];
#pragma unroll
    for (int mt = 0; mt < MTW; mt++)
#pragma unroll
        for (int nt = 0; nt < NTN; nt++) {
            floatx4 c0 = {bv[nt], bv[nt], bv[nt], bv[nt]};
            acc[mt][nt] = c0;
        }
#pragma unroll
    for (int mt = 0; mt < MTW; mt++) {
        const int row = w * (ROWS / 4) + mt * 16 + ln;
#pragma unroll
        for (int kt = 0; kt < KT; kt++) {
            short8 af = *(const short8*)&lx[row * XS + kt * 32 + quad * 8];
#pragma unroll
            for (int nt = 0; nt < NTN; nt++)
                acc[mt][nt] = __builtin_amdgcn_mfma_f32_16x16x32_bf16(
                    af, wf8[(kt * NTN + nt) * 64 + l], acc[mt][nt], 0, 0, 0);
        }
    }

    // epilogue: per-32-col chunk LDS transpose -> coalesced bf16 stores
#pragma unroll
    for (int c = 0; c < NCH; c++) {
        __syncthreads();
#pragma unroll
        for (int mt = 0; mt < MTW; mt++)
#pragma unroll
            for (int d = 0; d < 2; d++) {
                int nt = 2 * c + d;
#pragma unroll
                for (int r = 0; r < 4; r++)
                    lo[(w * (ROWS / 4) + mt * 16 + quad * 4 + r) * OS + d * 16 + ln] = acc[mt][nt][r];
            }
        __syncthreads();
        const int T4 = rows * 8;
        unsigned short* og = ((c == 0) ? y0 : (c == NCH - 1) ? h : y1) + (size_t)base * 32;
        for (int q = tid; q < T4; q += 256) {
            int r = q >> 3, cc = (q & 7) * 4;
            const float* p = &lo[r * OS + cc];
            short4 s4;
            s4.x = (short)f2bf(p[0]); s4.y = (short)f2bf(p[1]);
            s4.z = (short)f2bf(p[2]); s4.w = (short)f2bf(p[3]);
            *(short4*)(og + q * 4) = s4;
        }
    }
}

// Merged [tf1 (128-row tiles) | fine] launch.
__global__ __launch_bounds__(256) void tf1_fine_kernel(
    const float* xb, const unsigned short* __restrict__ Wfb, const float* __restrict__ Bb,
    unsigned short* __restrict__ yb0, unsigned short* __restrict__ yb1, unsigned short* hb,
    const float* xg, const unsigned short* __restrict__ Wfg, const float* __restrict__ Bg,
    unsigned short* __restrict__ yg0, unsigned short* hg,
    const unsigned* __restrict__ cbb, const unsigned* __restrict__ pbb, unsigned* __restrict__ rsbb, unsigned* __restrict__ ebb,
    const unsigned* __restrict__ cgb, const unsigned* __restrict__ pgb, unsigned* __restrict__ rsgb, unsigned* __restrict__ egb,
    const unsigned* __restrict__ cbg, const unsigned* __restrict__ pbg, unsigned* __restrict__ rsbg, unsigned* __restrict__ ebg)
{
    constexpr int XB = 128 * (64 + 8) * 2, OB = 128 * 34 * 4;  // 18432 / 17408
    __shared__ __align__(16) char ldsraw[(XB > OB) ? XB : OB];
    int b = blockIdx.x;
    if (b < NB_TF1_BUS)
        transform_body<64, 96, 128>(b, xb, N_BUS, Wfb, Bb, yb0, yb1, hb, ldsraw);
    else if (b < NB_TF1_ALL)
        transform_body<64, 64, 128>(b - NB_TF1_BUS, xg, N_GEN, Wfg, Bg, yg0, nullptr, hg, ldsraw);
    else {
        int f = b - NB_TF1_ALL;
        if (f < NBK_BUS) fine_body(f, cbb, CAP_BB, pbb, rsbb, ebb, N_BUS, ldsraw);
        else if (f < 2 * NBK_BUS) fine_body(f - NBK_BUS, cgb, CAP_GB, pgb, rsgb, egb, N_BUS, ldsraw);
        else fine_body(f - 2 * NBK_BUS, cbg, CAP_BG, pbg, rsbg, ebg, N_GEN, ldsraw);
    }
}

// ---------------------------------------------------------------------------
// One relation's mean-aggregate into a float4 (cols j..j+3); 4-deep pipeline
// with next-quad index prefetch.
__device__ __forceinline__ void agg_one(
    unsigned u, const unsigned* __restrict__ e,
    const unsigned short* __restrict__ y, int j, float4& r)
{
    unsigned k0 = u >> 9;
    unsigned c = u & 511u;
    unsigned k1 = k0 + c;
    float4 a0 = make_float4(0.f, 0.f, 0.f, 0.f);
    float4 a1 = a0, a2 = a0, a3 = a0;
    unsigned k = k0;
    if (k + 4 <= k1) {
        unsigned s0 = e[k], s1 = e[k + 1], s2 = e[k + 2], s3 = e[k + 3];
        for (; k + 8 <= k1; k += 4) {
            unsigned t0 = e[k + 4], t1 = e[k + 5], t2 = e[k + 6], t3 = e[k + 7];
            ushort4 v0 = *(const ushort4*)(y + (size_t)s0 * H + j);
            ushort4 v1 = *(const ushort4*)(y + (size_t)s1 * H + j);
            ushort4 v2 = *(const ushort4*)(y + (size_t)s2 * H + j);
            ushort4 v3 = *(const ushort4*)(y + (size_t)s3 * H + j);
            a0.x += bf2f(v0.x); a0.y += bf2f(v0.y); a0.z += bf2f(v0.z); a0.w += bf2f(v0.w);
            a1.x += bf2f(v1.x); a1.y += bf2f(v1.y); a1.z += bf2f(v1.z); a1.w += bf2f(v1.w);
            a2.x += bf2f(v2.x); a2.y += bf2f(v2.y); a2.z += bf2f(v2.z); a2.w += bf2f(v2.w);
            a3.x += bf2f(v3.x); a3.y += bf2f(v3.y); a3.z += bf2f(v3.z); a3.w += bf2f(v3.w);
            s0 = t0; s1 = t1; s2 = t2; s3 = t3;
        }
        {
            ushort4 v0 = *(const ushort4*)(y + (size_t)s0 * H + j);
            ushort4 v1 = *(const ushort4*)(y + (size_t)s1 * H + j);
            ushort4 v2 = *(const ushort4*)(y + (size_t)s2 * H + j);
            ushort4 v3 = *(const ushort4*)(y + (size_t)s3 * H + j);
            a0.x += bf2f(v0.x); a0.y += bf2f(v0.y); a0.z += bf2f(v0.z); a0.w += bf2f(v0.w);
            a1.x += bf2f(v1.x); a1.y += bf2f(v1.y); a1.z += bf2f(v1.z); a1.w += bf2f(v1.w);
            a2.x += bf2f(v2.x); a2.y += bf2f(v2.y); a2.z += bf2f(v2.z); a2.w += bf2f(v2.w);
            a3.x += bf2f(v3.x); a3.y += bf2f(v3.y); a3.z += bf2f(v3.z); a3.w += bf2f(v3.w);
            k += 4;
        }
    }
    for (; k < k1; ++k) {
        unsigned s = e[k];
        const ushort4 v = *(const ushort4*)(y + (size_t)s * H + j);
        a0.x += bf2f(v.x); a0.y += bf2f(v.y); a0.z += bf2f(v.z); a0.w += bf2f(v.w);
    }
    a0.x += a1.x + a2.x + a3.x; a0.y += a1.y + a2.y + a3.y;
    a0.z += a1.z + a2.z + a3.z; a0.w += a1.w + a2.w + a3.w;
    float inv = 1.0f / (float)(c > 1u ? c : 1u);
    r.x += a0.x * inv; r.y += a0.y * inv; r.z += a0.z * inv; r.w += a0.w * inv;
}

// ---------------------------------------------------------------------------
// FUSED layer-1 pull + layer-2 transform: 32 nodes/block (pull structure kept
// intact -- full TLP), then a block-local [32 x 32] @ [32 x NOUT] MFMA tile.
// h is now bf16 (root read + h2 write): -32 MB of traffic in this kernel.
template <int NTA, bool HASB>
__device__ __forceinline__ void pull_tf_body(
    int blk, int n,
    const unsigned* __restrict__ rsA, const unsigned* __restrict__ eA, const unsigned short* __restrict__ yA,
    const unsigned* __restrict__ rsB, const unsigned* __restrict__ eB, const unsigned short* __restrict__ yB,
    unsigned short* __restrict__ h,
    const unsigned short* __restrict__ Wf, const float* __restrict__ bias,
    unsigned short* __restrict__ z0, unsigned short* __restrict__ z1,
    short* __restrict__ lx, float* __restrict__ lo)
{
    constexpr int XS = 40;   // lx row stride (shorts)
    constexpr int OS = 34;   // lo row stride (floats)
    const int tid = threadIdx.x;
    const int row = tid >> 3;
    const int j = (tid & 7) * 4;
    const int base = blk * 32;
    const int node = base + row;
    const bool act = node < n;

    float4 r = make_float4(0.f, 0.f, 0.f, 0.f);
    if (act) {
        ushort4 rv = *(const ushort4*)(h + (size_t)node * H + j);  // bf16 root
        r = make_float4(bf2f(rv.x), bf2f(rv.y), bf2f(rv.z), bf2f(rv.w));
        agg_one(rsA[node], eA, yA, j, r);
        if (HASB) agg_one(rsB[node], eB, yB, j, r);
    }
    short4 s4;
    s4.x = (short)f2bf(fmaxf(r.x, 0.f));
    s4.y = (short)f2bf(fmaxf(r.y, 0.f));
    s4.z = (short)f2bf(fmaxf(r.z, 0.f));
    s4.w = (short)f2bf(fmaxf(r.w, 0.f));
    *(short4*)&lx[row * XS + j] = s4;
    __syncthreads();

    // ---- MFMA: wave w -> m-tile (w&1), n-group (w>>1); acc[i] = n-tile 2i+ngrp
    const int w = tid >> 6, l = tid & 63, quad = l >> 4, ln = l & 15;
    const int mt = w & 1, ngrp = w >> 1;
    const short8* wf8 = (const short8*)Wf;
    floatx4 acc[NTA];
    short8 af = *(const short8*)&lx[(mt * 16 + ln) * XS + quad * 8];
#pragma unroll
    for (int i = 0; i < NTA; i++) {
        int nt = 2 * i + ngrp;
        float bv = bias[nt * 16 + ln];
        floatx4 c0 = {bv, bv, bv, bv};
        acc[i] = __builtin_amdgcn_mfma_f32_16x16x32_bf16(af, wf8[nt * 64 + l], c0, 0, 0, 0);
    }

    // ---- epilogue: per-32-col chunk LDS transpose -> coalesced bf16 stores ----
    const int rows = min(32, n - base);
    const int orow = tid >> 3, oc = (tid & 7) * 4;
#pragma unroll
    for (int c = 0; c < NTA; c++) {
        __syncthreads();
#pragma unroll
        for (int rr = 0; rr < 4; rr++)
            lo[(mt * 16 + quad * 4 + rr) * OS + ngrp * 16 + ln] = acc[c][rr];
        __syncthreads();
        if (orow < rows) {
            const float* p = &lo[orow * OS + oc];
            // chunk order: z0, [z1,] h  (h last; block owns rows -> in-place OK)
            unsigned short* og = (c == 0) ? z0 : (c == NTA - 1) ? h : z1;
            short4 o;
            o.x = (short)f2bf(p[0]); o.y = (short)f2bf(p[1]);
            o.z = (short)f2bf(p[2]); o.w = (short)f2bf(p[3]);
            *(short4*)(og + (size_t)(base + orow) * H + oc) = o;
        }
    }
}

__global__ __launch_bounds__(256) void pull_tf2_kernel(
    const unsigned* __restrict__ rsbb, const unsigned* __restrict__ ebb, const unsigned short* __restrict__ ybb,
    const unsigned* __restrict__ rsgb, const unsigned* __restrict__ egb, const unsigned short* __restrict__ ygb,
    unsigned short* __restrict__ hb, const unsigned short* __restrict__ Wfb, const float* __restrict__ Bb,
    unsigned short* __restrict__ y2bb, unsigned short* __restrict__ y2bg,
    const unsigned* __restrict__ rsbg, const unsigned* __restrict__ ebg, const unsigned short* __restrict__ ybg,
    unsigned short* __restrict__ hg, const unsigned short* __restrict__ Wfg, const float* __restrict__ Bg,
    unsigned short* __restrict__ y2gb)
{
    __shared__ __align__(16) short lx[32 * 40];
    __shared__ __align__(16) float lo[32 * 34];
    int b = blockIdx.x;
    if (b < NB_PL_BUS)
        pull_tf_body<3, true>(b, N_BUS, rsbb, ebb, ybb, rsgb, egb, ygb,
                              hb, Wfb, Bb, y2bb, y2bg, lx, lo);
    else
        pull_tf_body<2, false>(b - NB_PL_BUS, N_GEN, rsbg, ebg, ybg,
                               nullptr, nullptr, nullptr,
                               hg, Wfg, Bg, y2gb, nullptr, lx, lo);
}

// ---------------------------------------------------------------------------
// Final pull + fused head -> d_out (8 threads/node; bf16 h2 root).
__device__ __forceinline__ void pull_head_body(
    int blk, bool hasB, int n,
    const unsigned* __restrict__ rsA, const unsigned* __restrict__ eA, const unsigned short* __restrict__ yA,
    const unsigned* __restrict__ rsB, const unsigned* __restrict__ eB, const unsigned short* __restrict__ yB,
    const unsigned short* __restrict__ h,
    const float* __restrict__ We, const float* __restrict__ be, int DOUT, float* __restrict__ outp)
{
    const int tid = threadIdx.x;
    unsigned node = blk * 32u + (tid >> 3);
    int j = (tid & 7) * 4;
    if (node >= (unsigned)n) return;

    ushort4 rv = *(const ushort4*)(h + (size_t)node * H + j);  // bf16 root
    float4 r = make_float4(bf2f(rv.x), bf2f(rv.y), bf2f(rv.z), bf2f(rv.w));

    agg_one(rsA[node], eA, yA, j, r);
    if (hasB) agg_one(rsB[node], eB, yB, j, r);

    float p0 = fmaxf(r.x, 0.f), p1 = fmaxf(r.y, 0.f), p2 = fmaxf(r.z, 0.f), p3 = fmaxf(r.w, 0.f);
    float tot[4];
#pragma unroll
    for (int c = 0; c < 4; c++) {
        if (c < DOUT) {
            tot[c] = p0 * We[(j + 0) * DOUT + c] + p1 * We[(j + 1) * DOUT + c]
                   + p2 * We[(j + 2) * DOUT + c] + p3 * We[(j + 3) * DOUT + c];
        } else tot[c] = 0.f;
    }
#pragma unroll
    for (int mask = 1; mask <= 4; mask <<= 1) {
#pragma unroll
        for (int c = 0; c < 4; c++) tot[c] += __shfl_xor(tot[c], mask);
    }
    if ((tid & 7) == 0) {
        if (DOUT == 4) {
            *(float4*)(outp + (size_t)node * 4) =
                make_float4(tot[0] + be[0], tot[1] + be[1], tot[2] + be[2], tot[3] + be[3]);
        } else {
            *(float2*)(outp + (size_t)node * 2) = make_float2(tot[0] + be[0], tot[1] + be[1]);
        }
    }
}

__global__ __launch_bounds__(256) void pull_head_kernel(
    const unsigned* __restrict__ rsbb, const unsigned* __restrict__ ebb, const unsigned short* __restrict__ y2bb,
    const unsigned* __restrict__ rsgb, const unsigned* __restrict__ egb, const unsigned short* __restrict__ y2gb,
    const unsigned short* __restrict__ hb, const float* __restrict__ WeB, const float* __restrict__ beB,
    const unsigned* __restrict__ rsbg, const unsigned* __restrict__ ebg, const unsigned short* __restrict__ y2bg,
    const unsigned short* __restrict__ hg, const float* __restrict__ WeG, const float* __restrict__ beG,
    float* __restrict__ outp)
{
    int b = blockIdx.x;
    if (b < NB_PL_BUS)
        pull_head_body(b, true, N_BUS, rsbb, ebb, y2bb, rsgb, egb, y2gb, hb, WeB, beB, 4, outp);
    else
        pull_head_body(b - NB_PL_BUS, false, N_GEN, rsbg, ebg, y2bg, nullptr, nullptr, nullptr,
                       hg, WeG, beG, 2, outp + (size_t)N_BUS * 4);
}

// ---------------------------------------------------------------------------
extern "C" void kernel_launch(void* const* d_in, const int* in_sizes, int n_in,
                              void* d_out, int out_size, void* d_ws, size_t ws_size,
                              hipStream_t stream) {
    const float* x_bus = (const float*)d_in[0];
    const float* x_gen = (const float*)d_in[1];
    const int* src_bb = (const int*)d_in[2];
    const int* dst_bb = (const int*)d_in[3];
    const int* src_gb = (const int*)d_in[4];
    const int* dst_gb = (const int*)d_in[5];
    const int* src_bg = (const int*)d_in[6];
    const int* dst_bg = (const int*)d_in[7];
    const float* l1_bb_Wl = (const float*)d_in[8];
    const float* l1_bb_bl = (const float*)d_in[9];
    const float* l1_bb_Wr = (const float*)d_in[10];
    const float* l1_gb_Wl = (const float*)d_in[11];
    const float* l1_gb_bl = (const float*)d_in[12];
    const float* l1_gb_Wr = (const float*)d_in[13];
    const float* l1_bg_Wl = (const float*)d_in[14];
    const float* l1_bg_bl = (const float*)d_in[15];
    const float* l1_bg_Wr = (const float*)d_in[16];
    const float* l2_bb_Wl = (const float*)d_in[17];
    const float* l2_bb_bl = (const float*)d_in[18];
    const float* l2_bb_Wr = (const float*)d_in[19];
    const float* l2_gb_Wl = (const float*)d_in[20];
    const float* l2_gb_bl = (const float*)d_in[21];
    const float* l2_gb_Wr = (const float*)d_in[22];
    const float* l2_bg_Wl = (const float*)d_in[23];
    const float* l2_bg_bl = (const float*)d_in[24];
    const float* l2_bg_Wr = (const float*)d_in[25];
    const float* lin0_bus_W = (const float*)d_in[26];
    const float* lin0_bus_b = (const float*)d_in[27];
    const float* linf_bus_W = (const float*)d_in[28];
    const float* linf_bus_b = (const float*)d_in[29];
    const float* lin0_gen_W = (const float*)d_in[30];
    const float* lin0_gen_b = (const float*)d_in[31];
    const float* linf_gen_W = (const float*)d_in[32];
    const float* linf_gen_b = (const float*)d_in[33];

    // Workspace layout (~101 MB).
    char* ws = (char*)d_ws;
    size_t off = 0;
    auto alloc = [&](size_t bytes) {
        char* p = ws + off;
        off += (bytes + 255) & ~(size_t)255;
        return p;
    };
    unsigned* rs_bb = (unsigned*)alloc((size_t)N_BUS * 4);
    unsigned* rs_gb = (unsigned*)alloc((size_t)N_BUS * 4);
    unsigned* rs_bg = (unsigned*)alloc((size_t)N_GEN * 4);
    unsigned* cur_bb = (unsigned*)alloc(NBINS * 4);   // three cursor arrays contiguous
    unsigned* cur_gb = (unsigned*)alloc(NBINS * 4);
    unsigned* cur_bg = (unsigned*)alloc(NBINS * 4);
    unsigned* e_bb = (unsigned*)alloc((size_t)NBK_BUS * CAP_BB * 4);
    unsigned* e_gb = (unsigned*)alloc((size_t)NBK_BUS * CAP_GB * 4);
    unsigned* e_bg = (unsigned*)alloc((size_t)NBK_GEN * CAP_BG * 4);
    unsigned* p_bb = (unsigned*)alloc((size_t)NBK_BUS * CAP_BB * 4);
    unsigned* p_gb = (unsigned*)alloc((size_t)NBK_BUS * CAP_GB * 4);
    unsigned* p_bg = (unsigned*)alloc((size_t)NBK_GEN * CAP_BG * 4);
    unsigned short* y_bb = (unsigned short*)alloc((size_t)N_BUS * H * 2);  // bf16
    unsigned short* y_bg = (unsigned short*)alloc((size_t)N_BUS * H * 2);  // bf16
    unsigned short* y_gb = (unsigned short*)alloc((size_t)N_GEN * H * 2);  // bf16
    unsigned short* y2_bb = (unsigned short*)alloc((size_t)N_BUS * H * 2); // layer-2 y
    unsigned short* y2_bg = (unsigned short*)alloc((size_t)N_BUS * H * 2);
    unsigned short* y2_gb = (unsigned short*)alloc((size_t)N_GEN * H * 2);
    unsigned short* h_bus = (unsigned short*)alloc((size_t)N_BUS * H * 2); // bf16 root
    unsigned short* h_gen = (unsigned short*)alloc((size_t)N_GEN * H * 2);
    unsigned short* Wf1b = (unsigned short*)alloc(2 * 6 * 64 * 8 * 2);
    float* B1b = (float*)alloc(96 * 4);
    unsigned short* Wf1g = (unsigned short*)alloc(2 * 4 * 64 * 8 * 2);
    float* B1g = (float*)alloc(64 * 4);
    unsigned short* Wf2b = (unsigned short*)alloc(6 * 64 * 8 * 2);
    float* B2b = (float*)alloc(96 * 4);
    unsigned short* Wf2g = (unsigned short*)alloc(4 * 64 * 8 * 2);
    float* B2g = (float*)alloc(64 * 4);
    float* WeB = (float*)alloc(128 * 4);
    float* beB = (float*)alloc(4 * 4);
    float* WeG = (float*)alloc(64 * 4);
    float* beG = (float*)alloc(2 * 4);

    // L0: zero the three contiguous cursor arrays.
    zero_kernel<<<12, 256, 0, stream>>>(cur_bb);

    // L1: [part | prep].
    prep_part_kernel<<<NB_PART_ALL + NB_PREP, 256, 0, stream>>>(
        src_bb, dst_bb, cur_bb, p_bb, src_gb, dst_gb, cur_gb, p_gb,
        src_bg, dst_bg, cur_bg, p_bg,
        l1_bb_Wl, l1_bb_bl, l1_bb_Wr, l1_gb_Wl, l1_gb_bl, l1_gb_Wr,
        l1_bg_Wl, l1_bg_bl, l1_bg_Wr, l2_bb_Wl, l2_bb_bl, l2_bb_Wr,
        l2_gb_Wl, l2_gb_bl, l2_gb_Wr, l2_bg_Wl, l2_bg_bl, l2_bg_Wr,
        lin0_bus_W, lin0_bus_b, linf_bus_W, linf_bus_b,
        lin0_gen_W, lin0_gen_b, linf_gen_W, linf_gen_b,
        Wf1b, B1b, Wf1g, B1g, Wf2b, B2b, Wf2g, B2g, WeB, beB, WeG, beG);

    // L2: [tf1 (128-row tiles) | fine].
    tf1_fine_kernel<<<NB_TF1_ALL + NB_FINE_ALL, 256, 0, stream>>>(
        x_bus, Wf1b, B1b, y_bb, y_bg, h_bus, x_gen, Wf1g, B1g, y_gb, h_gen,
        cur_bb, p_bb, rs_bb, e_bb, cur_gb, p_gb, rs_gb, e_gb, cur_bg, p_bg, rs_bg, e_bg);

    // L3: FUSED layer-1 pull + layer-2 transform (32-node blocks, in-block MFMA).
    pull_tf2_kernel<<<NB_PL_BUS + NB_PL_GEN, 256, 0, stream>>>(
        rs_bb, e_bb, y_bb, rs_gb, e_gb, y_gb, h_bus, Wf2b, B2b, y2_bb, y2_bg,
        rs_bg, e_bg, y_bg, h_gen, Wf2g, B2g, y2_gb);

    // L4: layer-2 pull + fused head -> d_out.
    pull_head_kernel<<<NB_PL_BUS + NB_PL_GEN, 256, 0, stream>>>(
        rs_bb, e_bb, y2_bb, rs_gb, e_gb, y2_gb, h_bus, WeB, beB,
        rs_bg, e_bg, y2_bg, h_gen, WeG, beG, (float*)d_out);
}

// Round 10
// 339.911 us; speedup vs baseline: 1.0567x; 1.0065x over previous
//
#include <hip/hip_runtime.h>
#include <hip/hip_bf16.h>

#define N_BUS 200000
#define N_GEN 50000
#define E_BB 1600000
#define E_GB 400000
#define E_BG 400000
#define H 32
#define NBINS 1024   // max coarse buckets (>= ceil(200000/256) = 782)
#define EPT 16       // edges per thread in partition (chunk = 4096)

#define NBK_BUS 782      // buckets for bus-dst relations
#define NBK_GEN 196      // buckets for gen-dst relations
#define CAP_BB 2560      // mean 2046 + >11 sigma
#define CAP_GB 768       // mean 512  + >11 sigma
#define CAP_BG 2560      // mean 2041 + >11 sigma

#define NB_PART_BB 391   // ceil(E_BB/4096)
#define NB_PART_GB 98
#define NB_PART_BG 98
#define NB_PART_ALL 587
#define NB_PREP 32
#define NB_TF1_BUS 1563  // ceil(200000/128)
#define NB_TF1_GEN 391   // ceil(50000/128)
#define NB_TF1_ALL 1954
#define NB_FINE_ALL 1760 // 2*NBK_BUS + NBK_GEN
#define NB_PL_BUS 6250   // ceil(N_BUS/32)  (pull_head, 32 nodes/block)
#define NB_PL_GEN 1563
#define NB_PT_BUS 12500  // N_BUS/16 (pull_tf2, 16 nodes/block, exact)
#define NB_PT_GEN 3125   // N_GEN/16 (exact)

#define PNONE 0xFFFFFFFFu

typedef __attribute__((ext_vector_type(8))) short short8;
typedef __attribute__((ext_vector_type(4))) float floatx4;

__device__ inline unsigned short f2bf(float f) {
    __hip_bfloat16 h = __float2bfloat16(f);   // RNE
    return *reinterpret_cast<unsigned short*>(&h);
}
__device__ inline float bf2f(unsigned short u) {
    return __uint_as_float(((unsigned)u) << 16);
}

// ---------------------------------------------------------------------------
// Block-wide exclusive scan over one unsigned per thread (256 threads).
// Wave-level shfl scan + 4-entry cross-wave LDS; ONE barrier (vs 20).
__device__ __forceinline__ unsigned block_excl_scan(unsigned s, unsigned* wsum) {
    const int lane = threadIdx.x & 63, wv = threadIdx.x >> 6;
    unsigned scan = s;
#pragma unroll
    for (int d = 1; d < 64; d <<= 1) {
        unsigned t = __shfl_up(scan, d, 64);
        if (lane >= d) scan += t;
    }
    if (lane == 63) wsum[wv] = scan;
    __syncthreads();
    unsigned base = 0;
    for (int i = 0; i < wv; i++) base += wsum[i];
    return base + scan - s;   // exclusive prefix for this thread's value
}

// ---------------------------------------------------------------------------
// Zero the 3 contiguous cursor arrays.
__global__ __launch_bounds__(256) void zero_kernel(unsigned* __restrict__ p) {
    int i = blockIdx.x * 256 + threadIdx.x;
    if (i < 3 * NBINS) p[i] = 0u;
}

// ---------------------------------------------------------------------------
// Partition into fixed-capacity buckets. Block-local LDS counting sort so the
// global pairs[] write streams out in position order. pairs = (dst&255)<<24|src.
__device__ __forceinline__ void part_body(int blk, const int* __restrict__ src,
                                          const int* __restrict__ dst, int nE,
                                          unsigned* __restrict__ cnt_g, int CAP,
                                          unsigned* __restrict__ pairs) {
    __shared__ unsigned hist[NBINS];
    __shared__ unsigned base[NBINS];    // global target base per bin
    __shared__ unsigned sbase[NBINS];   // block-local exclusive scan per bin
    __shared__ unsigned wsum[4];
    __shared__ unsigned pairv[256 * EPT];
    __shared__ unsigned short bid[256 * EPT];
    const int tid = threadIdx.x;
    const int cbase = blk * (256 * EPT);
    const int total = min(256 * EPT, nE - cbase);

    unsigned es[EPT], ed[EPT];
#pragma unroll
    for (int q = 0; q < EPT; q++) {
        int i = cbase + q * 256 + tid;
        if (i < nE) { es[q] = (unsigned)src[i]; ed[q] = (unsigned)dst[i]; }
        else ed[q] = PNONE;
    }
    for (int i = tid; i < NBINS; i += 256) hist[i] = 0;
    __syncthreads();
#pragma unroll
    for (int q = 0; q < EPT; q++)
        if (ed[q] != PNONE) atomicAdd(&hist[ed[q] >> 8], 1u);
    __syncthreads();

    // Block-local exclusive scan over the 1024 bins (4 bins/thread, wave scan).
    unsigned h4[4];
    unsigned s = 0;
#pragma unroll
    for (int k2 = 0; k2 < 4; k2++) { h4[k2] = hist[tid * 4 + k2]; s += h4[k2]; }
    unsigned run = block_excl_scan(s, wsum);
#pragma unroll
    for (int k2 = 0; k2 < 4; k2++) {
        int b = tid * 4 + k2;
        sbase[b] = run;
        base[b] = h4[k2] ? ((unsigned)b * CAP + atomicAdd(&cnt_g[b], h4[k2])) : 0u;
        hist[b] = 0;  // reuse as local cursor
        run += h4[k2];
    }
    __syncthreads();

    // Place pairs into the block-sorted LDS staging.
#pragma unroll
    for (int q = 0; q < EPT; q++) {
        if (ed[q] != PNONE) {
            unsigned b = ed[q] >> 8;
            unsigned off = atomicAdd(&hist[b], 1u);
            unsigned p = sbase[b] + off;
            pairv[p] = ((ed[q] & 255u) << 24) | es[q];
            bid[p] = (unsigned short)b;
        }
    }
    __syncthreads();

    // Stream out: consecutive p within a bucket -> consecutive global addr.
    for (int p = tid; p < total; p += 256) {
        unsigned b = bid[p];
        pairs[base[b] + ((unsigned)p - sbase[b])] = pairv[p];
    }
}

// ---------------------------------------------------------------------------
// Prep body (grid-striding over NB_PREP*256 threads): bf16 MFMA B-fragments +
// fused biases + fused head matrices.
__device__ __forceinline__ void prep_body(int pb,
    const float* __restrict__ l1_bb_Wl, const float* __restrict__ l1_bb_bl, const float* __restrict__ l1_bb_Wr,
    const float* __restrict__ l1_gb_Wl, const float* __restrict__ l1_gb_bl, const float* __restrict__ l1_gb_Wr,
    const float* __restrict__ l1_bg_Wl, const float* __restrict__ l1_bg_bl, const float* __restrict__ l1_bg_Wr,
    const float* __restrict__ l2_bb_Wl, const float* __restrict__ l2_bb_bl, const float* __restrict__ l2_bb_Wr,
    const float* __restrict__ l2_gb_Wl, const float* __restrict__ l2_gb_bl, const float* __restrict__ l2_gb_Wr,
    const float* __restrict__ l2_bg_Wl, const float* __restrict__ l2_bg_bl, const float* __restrict__ l2_bg_Wr,
    const float* __restrict__ lin0_bus_W, const float* __restrict__ lin0_bus_b,
    const float* __restrict__ linf_bus_W, const float* __restrict__ linf_bus_b,
    const float* __restrict__ lin0_gen_W, const float* __restrict__ lin0_gen_b,
    const float* __restrict__ linf_gen_W, const float* __restrict__ linf_gen_b,
    unsigned short* __restrict__ Wf1b, float* __restrict__ B1b,
    unsigned short* __restrict__ Wf1g, float* __restrict__ B1g,
    unsigned short* __restrict__ Wf2b, float* __restrict__ B2b,
    unsigned short* __restrict__ Wf2g, float* __restrict__ B2g,
    float* __restrict__ WeB, float* __restrict__ beB,
    float* __restrict__ WeG, float* __restrict__ beG)
{
    int t0 = pb * 256 + threadIdx.x;
    const int NT = NB_PREP * 256;

    // L1 bus: KT=2, NTN=6
    for (int f = t0; f < 2 * 6 * 64 * 8; f += NT) {
        int j = f & 7, l = (f >> 3) & 63, tile = f >> 9;
        int nt = tile % 6, kt = tile / 6;
        int k = kt * 32 + (l >> 4) * 8 + j, n = nt * 16 + (l & 15);
        float v;
        if (n < 32) v = l1_bb_Wl[k * 32 + n];
        else if (n < 64) v = l1_bg_Wl[k * 32 + n - 32];
        else v = l1_bb_Wr[k * 32 + n - 64] + l1_gb_Wr[k * 32 + n - 64];
        Wf1b[f] = f2bf(v);
    }
    // L1 gen: KT=2, NTN=4
    for (int f = t0; f < 2 * 4 * 64 * 8; f += NT) {
        int j = f & 7, l = (f >> 3) & 63, tile = f >> 9;
        int nt = tile % 4, kt = tile / 4;
        int k = kt * 32 + (l >> 4) * 8 + j, n = nt * 16 + (l & 15);
        float v = (n < 32) ? l1_gb_Wl[k * 32 + n] : l1_bg_Wr[k * 32 + n - 32];
        Wf1g[f] = f2bf(v);
    }
    // L2 bus: KT=1, NTN=6
    for (int f = t0; f < 6 * 64 * 8; f += NT) {
        int j = f & 7, l = (f >> 3) & 63, nt = f >> 9;
        int k = (l >> 4) * 8 + j, n = nt * 16 + (l & 15);
        float v;
        if (n < 32) v = l2_bb_Wl[k * 32 + n];
        else if (n < 64) v = l2_bg_Wl[k * 32 + n - 32];
        else v = l2_bb_Wr[k * 32 + n - 64] + l2_gb_Wr[k * 32 + n - 64];
        Wf2b[f] = f2bf(v);
    }
    // L2 gen: KT=1, NTN=4
    for (int f = t0; f < 4 * 64 * 8; f += NT) {
        int j = f & 7, l = (f >> 3) & 63, nt = f >> 9;
        int k = (l >> 4) * 8 + j, n = nt * 16 + (l & 15);
        float v = (n < 32) ? l2_gb_Wl[k * 32 + n] : l2_bg_Wr[k * 32 + n - 32];
        Wf2g[f] = f2bf(v);
    }
    if (t0 < 96) {
        B1b[t0] = (t0 < 64) ? 0.0f : l1_bb_bl[t0 - 64] + l1_gb_bl[t0 - 64];
        B2b[t0] = (t0 < 64) ? 0.0f : l2_bb_bl[t0 - 64] + l2_gb_bl[t0 - 64];
    }
    if (t0 < 64) {
        B1g[t0] = (t0 < 32) ? 0.0f : l1_bg_bl[t0 - 32];
        B2g[t0] = (t0 < 32) ? 0.0f : l2_bg_bl[t0 - 32];
    }
    // Fused head: bus We (32x4) + be(4); gen We (32x2) + be(2)
    if (t0 < 128) {
        int k = t0 >> 2, c = t0 & 3;
        float s = 0.0f;
        for (int m = 0; m < 32; m++) s += lin0_bus_W[k * 32 + m] * linf_bus_W[m * 4 + c];
        WeB[t0] = s;
    }
    if (t0 >= 128 && t0 < 132) {
        int c = t0 - 128;
        float s = linf_bus_b[c];
        for (int m = 0; m < 32; m++) s += lin0_bus_b[m] * linf_bus_W[m * 4 + c];
        beB[c] = s;
    }
    if (t0 >= 132 && t0 < 196) {
        int i = t0 - 132, k = i >> 1, c = i & 1;
        float s = 0.0f;
        for (int m = 0; m < 32; m++) s += lin0_gen_W[k * 32 + m] * linf_gen_W[m * 2 + c];
        WeG[i] = s;
    }
    if (t0 >= 196 && t0 < 198) {
        int c = t0 - 196;
        float s = linf_gen_b[c];
        for (int m = 0; m < 32; m++) s += lin0_gen_b[m] * linf_gen_W[m * 2 + c];
        beG[c] = s;
    }
}

// Merged [part | prep] launch.
__global__ __launch_bounds__(256) void prep_part_kernel(
    const int* __restrict__ sbb, const int* __restrict__ dbb, unsigned* __restrict__ cbb, unsigned* __restrict__ pbb,
    const int* __restrict__ sgb, const int* __restrict__ dgb, unsigned* __restrict__ cgb, unsigned* __restrict__ pgb,
    const int* __restrict__ sbg, const int* __restrict__ dbg, unsigned* __restrict__ cbg, unsigned* __restrict__ pbg,
    const float* __restrict__ l1_bb_Wl, const float* __restrict__ l1_bb_bl, const float* __restrict__ l1_bb_Wr,
    const float* __restrict__ l1_gb_Wl, const float* __restrict__ l1_gb_bl, const float* __restrict__ l1_gb_Wr,
    const float* __restrict__ l1_bg_Wl, const float* __restrict__ l1_bg_bl, const float* __restrict__ l1_bg_Wr,
    const float* __restrict__ l2_bb_Wl, const float* __restrict__ l2_bb_bl, const float* __restrict__ l2_bb_Wr,
    const float* __restrict__ l2_gb_Wl, const float* __restrict__ l2_gb_bl, const float* __restrict__ l2_gb_Wr,
    const float* __restrict__ l2_bg_Wl, const float* __restrict__ l2_bg_bl, const float* __restrict__ l2_bg_Wr,
    const float* __restrict__ lin0_bus_W, const float* __restrict__ lin0_bus_b,
    const float* __restrict__ linf_bus_W, const float* __restrict__ linf_bus_b,
    const float* __restrict__ lin0_gen_W, const float* __restrict__ lin0_gen_b,
    const float* __restrict__ linf_gen_W, const float* __restrict__ linf_gen_b,
    unsigned short* __restrict__ Wf1b, float* __restrict__ B1b,
    unsigned short* __restrict__ Wf1g, float* __restrict__ B1g,
    unsigned short* __restrict__ Wf2b, float* __restrict__ B2b,
    unsigned short* __restrict__ Wf2g, float* __restrict__ B2g,
    float* __restrict__ WeB, float* __restrict__ beB,
    float* __restrict__ WeG, float* __restrict__ beG)
{
    int b = blockIdx.x;
    if (b < NB_PART_BB) part_body(b, sbb, dbb, E_BB, cbb, CAP_BB, pbb);
    else if (b < NB_PART_BB + NB_PART_GB) part_body(b - NB_PART_BB, sgb, dgb, E_GB, cgb, CAP_GB, pgb);
    else if (b < NB_PART_ALL) part_body(b - NB_PART_BB - NB_PART_GB, sbg, dbg, E_BG, cbg, CAP_BG, pbg);
    else prep_body(b - NB_PART_ALL,
                   l1_bb_Wl, l1_bb_bl, l1_bb_Wr, l1_gb_Wl, l1_gb_bl, l1_gb_Wr,
                   l1_bg_Wl, l1_bg_bl, l1_bg_Wr, l2_bb_Wl, l2_bb_bl, l2_bb_Wr,
                   l2_gb_Wl, l2_gb_bl, l2_gb_Wr, l2_bg_Wl, l2_bg_bl, l2_bg_Wr,
                   lin0_bus_W, lin0_bus_b, linf_bus_W, linf_bus_b,
                   lin0_gen_W, lin0_gen_b, linf_gen_W, linf_gen_b,
                   Wf1b, B1b, Wf1g, B1g, Wf2b, B2b, Wf2g, B2g, WeB, beB, WeG, beG);
}

// ---------------------------------------------------------------------------
// Fine CSR: one block per bucket, LDS carved from shared buffer.
// rs[node] packed: (global row start << 9) | degree  (start < 2^21, deg < 512).
__device__ __forceinline__ void fine_body(int b, const unsigned* __restrict__ cnt_g, int CAP,
                                          const unsigned* __restrict__ pairs,
                                          unsigned* __restrict__ rs,
                                          unsigned* __restrict__ esrc, int nDst,
                                          char* __restrict__ lds) {
    unsigned* cnt = (unsigned*)lds;            // 1 KB
    unsigned* wsum = (unsigned*)(lds + 1024);  // 16 B
    unsigned* stg = (unsigned*)(lds + 2048);   // 10 KB (>= max CAP)
    const int tid = threadIdx.x;
    const unsigned start = (unsigned)b * CAP;
    const unsigned m = cnt_g[b];
    const unsigned end = start + m;

    cnt[tid] = 0;
    __syncthreads();
    for (unsigned k = start + tid; k < end; k += 256)
        atomicAdd(&cnt[pairs[k] >> 24], 1u);
    __syncthreads();
    unsigned c = cnt[tid];
    unsigned excl = block_excl_scan(c, wsum);  // contains one barrier
    int gd = b * 256 + tid;
    unsigned rowstart = start + excl;
    if (gd < nDst) rs[gd] = (rowstart << 9) | (c < 511u ? c : 511u);
    cnt[tid] = excl;  // exclusive offset -> cursor (own slot; all loads done)
    __syncthreads();
    for (unsigned k = start + tid; k < end; k += 256) {
        unsigned p = pairs[k];
        unsigned off = atomicAdd(&cnt[p >> 24], 1u);
        stg[off] = p & 0x00FFFFFFu;
    }
    __syncthreads();
    for (unsigned p = tid; p < m; p += 256) esrc[start + p] = stg[p];
}

// ---------------------------------------------------------------------------
// Layer-1 transform body: ROWS-row tile, stage x fp32 -> bf16, MFMA, epilogue.
// ALL outputs (y0, y1, h) bf16.
template <int K, int NOUT, int ROWS>
__device__ __forceinline__ void transform_body(
    int blk, const float* x, int n,
    const unsigned short* __restrict__ Wf, const float* __restrict__ bias,
    unsigned short* __restrict__ y0, unsigned short* __restrict__ y1,
    unsigned short* __restrict__ h,
    char* ldsraw)
{
    constexpr int XS = K + 8;  // shorts
    constexpr int KT = K / 32, NTN = NOUT / 16, NCH = NOUT / 32;
    constexpr int MTW = ROWS / 64;   // 16-row m-tiles per wave
    constexpr int OS = 34;           // floats
    short* lx = (short*)ldsraw;
    float* lo = (float*)ldsraw;
    const int tid = threadIdx.x;
    const int base = blk * ROWS;
    const int rows = min(ROWS, n - base);
    const int w = tid >> 6, l = tid & 63, quad = l >> 4, ln = l & 15;

    {   // stage
        const float4* xg = (const float4*)(x + (size_t)base * K);
        const int T4 = rows * (K / 4);
        for (int q = tid; q < T4; q += 256) {
            float4 v = xg[q];
            int r = q / (K / 4), c = (q % (K / 4)) * 4;
            short4 s4;
            s4.x = (short)f2bf(v.x); s4.y = (short)f2bf(v.y);
            s4.z = (short)f2bf(v.z); s4.w = (short)f2bf(v.w);
            *(short4*)&lx[r * XS + c] = s4;
        }
    }
    __syncthreads();

    const short8* wf8 = (const short8*)Wf;
    float bv[NTN];
#pragma unroll
    for (int nt = 0; nt < NTN; nt++) bv[nt] = bias[nt * 16 + ln];

    floatx4 acc[MTW][NTN];
#pragma unroll
    for (int mt = 0; mt < MTW; mt++)
#pragma unroll
        for (int nt = 0; nt < NTN; nt++) {
            floatx4 c0 = {bv[nt], bv[nt], bv[nt], bv[nt]};
            acc[mt][nt] = c0;
        }
#pragma unroll
    for (int mt = 0; mt < MTW; mt++) {
        const int row = w * (ROWS / 4) + mt * 16 + ln;
#pragma unroll
        for (int kt = 0; kt < KT; kt++) {
            short8 af = *(const short8*)&lx[row * XS + kt * 32 + quad * 8];
#pragma unroll
            for (int nt = 0; nt < NTN; nt++)
                acc[mt][nt] = __builtin_amdgcn_mfma_f32_16x16x32_bf16(
                    af, wf8[(kt * NTN + nt) * 64 + l], acc[mt][nt], 0, 0, 0);
        }
    }

    // epilogue: per-32-col chunk LDS transpose -> coalesced bf16 stores
#pragma unroll
    for (int c = 0; c < NCH; c++) {
        __syncthreads();
#pragma unroll
        for (int mt = 0; mt < MTW; mt++)
#pragma unroll
            for (int d = 0; d < 2; d++) {
                int nt = 2 * c + d;
#pragma unroll
                for (int r = 0; r < 4; r++)
                    lo[(w * (ROWS / 4) + mt * 16 + quad * 4 + r) * OS + d * 16 + ln] = acc[mt][nt][r];
            }
        __syncthreads();
        const int T4 = rows * 8;
        unsigned short* og = ((c == 0) ? y0 : (c == NCH - 1) ? h : y1) + (size_t)base * 32;
        for (int q = tid; q < T4; q += 256) {
            int r = q >> 3, cc = (q & 7) * 4;
            const float* p = &lo[r * OS + cc];
            short4 s4;
            s4.x = (short)f2bf(p[0]); s4.y = (short)f2bf(p[1]);
            s4.z = (short)f2bf(p[2]); s4.w = (short)f2bf(p[3]);
            *(short4*)(og + q * 4) = s4;
        }
    }
}

// Merged [tf1 (128-row tiles) | fine] launch.
__global__ __launch_bounds__(256) void tf1_fine_kernel(
    const float* xb, const unsigned short* __restrict__ Wfb, const float* __restrict__ Bb,
    unsigned short* __restrict__ yb0, unsigned short* __restrict__ yb1, unsigned short* hb,
    const float* xg, const unsigned short* __restrict__ Wfg, const float* __restrict__ Bg,
    unsigned short* __restrict__ yg0, unsigned short* hg,
    const unsigned* __restrict__ cbb, const unsigned* __restrict__ pbb, unsigned* __restrict__ rsbb, unsigned* __restrict__ ebb,
    const unsigned* __restrict__ cgb, const unsigned* __restrict__ pgb, unsigned* __restrict__ rsgb, unsigned* __restrict__ egb,
    const unsigned* __restrict__ cbg, const unsigned* __restrict__ pbg, unsigned* __restrict__ rsbg, unsigned* __restrict__ ebg)
{
    constexpr int XB = 128 * (64 + 8) * 2, OB = 128 * 34 * 4;  // 18432 / 17408
    __shared__ __align__(16) char ldsraw[(XB > OB) ? XB : OB];
    int b = blockIdx.x;
    if (b < NB_TF1_BUS)
        transform_body<64, 96, 128>(b, xb, N_BUS, Wfb, Bb, yb0, yb1, hb, ldsraw);
    else if (b < NB_TF1_ALL)
        transform_body<64, 64, 128>(b - NB_TF1_BUS, xg, N_GEN, Wfg, Bg, yg0, nullptr, hg, ldsraw);
    else {
        int f = b - NB_TF1_ALL;
        if (f < NBK_BUS) fine_body(f, cbb, CAP_BB, pbb, rsbb, ebb, N_BUS, ldsraw);
        else if (f < 2 * NBK_BUS) fine_body(f - NBK_BUS, cgb, CAP_GB, pgb, rsgb, egb, N_BUS, ldsraw);
        else fine_body(f - 2 * NBK_BUS, cbg, CAP_BG, pbg, rsbg, ebg, N_GEN, ldsraw);
    }
}

// ---------------------------------------------------------------------------
// One relation's mean-aggregate into a float4 (cols j..j+3); 4-deep pipeline
// with next-quad index prefetch.
__device__ __forceinline__ void agg_one(
    unsigned u, const unsigned* __restrict__ e,
    const unsigned short* __restrict__ y, int j, float4& r)
{
    unsigned k0 = u >> 9;
    unsigned c = u & 511u;
    unsigned k1 = k0 + c;
    float4 a0 = make_float4(0.f, 0.f, 0.f, 0.f);
    float4 a1 = a0, a2 = a0, a3 = a0;
    unsigned k = k0;
    if (k + 4 <= k1) {
        unsigned s0 = e[k], s1 = e[k + 1], s2 = e[k + 2], s3 = e[k + 3];
        for (; k + 8 <= k1; k += 4) {
            unsigned t0 = e[k + 4], t1 = e[k + 5], t2 = e[k + 6], t3 = e[k + 7];
            ushort4 v0 = *(const ushort4*)(y + (size_t)s0 * H + j);
            ushort4 v1 = *(const ushort4*)(y + (size_t)s1 * H + j);
            ushort4 v2 = *(const ushort4*)(y + (size_t)s2 * H + j);
            ushort4 v3 = *(const ushort4*)(y + (size_t)s3 * H + j);
            a0.x += bf2f(v0.x); a0.y += bf2f(v0.y); a0.z += bf2f(v0.z); a0.w += bf2f(v0.w);
            a1.x += bf2f(v1.x); a1.y += bf2f(v1.y); a1.z += bf2f(v1.z); a1.w += bf2f(v1.w);
            a2.x += bf2f(v2.x); a2.y += bf2f(v2.y); a2.z += bf2f(v2.z); a2.w += bf2f(v2.w);
            a3.x += bf2f(v3.x); a3.y += bf2f(v3.y); a3.z += bf2f(v3.z); a3.w += bf2f(v3.w);
            s0 = t0; s1 = t1; s2 = t2; s3 = t3;
        }
        {
            ushort4 v0 = *(const ushort4*)(y + (size_t)s0 * H + j);
            ushort4 v1 = *(const ushort4*)(y + (size_t)s1 * H + j);
            ushort4 v2 = *(const ushort4*)(y + (size_t)s2 * H + j);
            ushort4 v3 = *(const ushort4*)(y + (size_t)s3 * H + j);
            a0.x += bf2f(v0.x); a0.y += bf2f(v0.y); a0.z += bf2f(v0.z); a0.w += bf2f(v0.w);
            a1.x += bf2f(v1.x); a1.y += bf2f(v1.y); a1.z += bf2f(v1.z); a1.w += bf2f(v1.w);
            a2.x += bf2f(v2.x); a2.y += bf2f(v2.y); a2.z += bf2f(v2.z); a2.w += bf2f(v2.w);
            a3.x += bf2f(v3.x); a3.y += bf2f(v3.y); a3.z += bf2f(v3.z); a3.w += bf2f(v3.w);
            k += 4;
        }
    }
    for (; k < k1; ++k) {
        unsigned s = e[k];
        const ushort4 v = *(const ushort4*)(y + (size_t)s * H + j);
        a0.x += bf2f(v.x); a0.y += bf2f(v.y); a0.z += bf2f(v.z); a0.w += bf2f(v.w);
    }
    a0.x += a1.x + a2.x + a3.x; a0.y += a1.y + a2.y + a3.y;
    a0.z += a1.z + a2.z + a3.z; a0.w += a1.w + a2.w + a3.w;
    float inv = 1.0f / (float)(c > 1u ? c : 1u);
    r.x += a0.x * inv; r.y += a0.y * inv; r.z += a0.z * inv; r.w += a0.w * inv;
}

// ---------------------------------------------------------------------------
// FUSED layer-1 pull + layer-2 transform: 16 nodes/block, 128 threads (2 waves)
// -- halves the barrier straggler set vs 32-node blocks; tiles are exact
// (200000%16 == 50000%16 == 0). One 16-row MFMA m-tile; wave w owns n-tiles
// [w*NTA, (w+1)*NTA). Chunked 2-barrier epilogue. Math bit-identical.
template <int NTA, bool HASB>
__device__ __forceinline__ void pull_tf_body(
    int blk, int n,
    const unsigned* __restrict__ rsA, const unsigned* __restrict__ eA, const unsigned short* __restrict__ yA,
    const unsigned* __restrict__ rsB, const unsigned* __restrict__ eB, const unsigned short* __restrict__ yB,
    unsigned short* __restrict__ h,
    const unsigned short* __restrict__ Wf, const float* __restrict__ bias,
    unsigned short* __restrict__ z0, unsigned short* __restrict__ z1,
    short* __restrict__ lx, float* __restrict__ lo)
{
    constexpr int XS = 40;   // lx row stride (shorts)
    constexpr int OS = 34;   // lo row stride (floats)
    constexpr int NCH = NTA; // 32-col output chunks (bus 3, gen 2)
    const int tid = threadIdx.x;
    const int row = tid >> 3;        // 0..15
    const int j = (tid & 7) * 4;
    const int base = blk * 16;
    const int node = base + row;
    const bool act = node < n;

    float4 r = make_float4(0.f, 0.f, 0.f, 0.f);
    if (act) {
        ushort4 rv = *(const ushort4*)(h + (size_t)node * H + j);  // bf16 root
        r = make_float4(bf2f(rv.x), bf2f(rv.y), bf2f(rv.z), bf2f(rv.w));
        agg_one(rsA[node], eA, yA, j, r);
        if (HASB) agg_one(rsB[node], eB, yB, j, r);
    }
    short4 s4;
    s4.x = (short)f2bf(fmaxf(r.x, 0.f));
    s4.y = (short)f2bf(fmaxf(r.y, 0.f));
    s4.z = (short)f2bf(fmaxf(r.z, 0.f));
    s4.w = (short)f2bf(fmaxf(r.w, 0.f));
    *(short4*)&lx[row * XS + j] = s4;
    __syncthreads();

    // ---- MFMA: single 16-row m-tile; wave w owns n-tiles w*NTA..w*NTA+NTA-1
    const int w = tid >> 6, l = tid & 63, quad = l >> 4, ln = l & 15;
    const short8* wf8 = (const short8*)Wf;
    floatx4 acc[NTA];
    short8 af = *(const short8*)&lx[ln * XS + quad * 8];
#pragma unroll
    for (int i = 0; i < NTA; i++) {
        int nt = w * NTA + i;
        float bv = bias[nt * 16 + ln];
        floatx4 c0 = {bv, bv, bv, bv};
        acc[i] = __builtin_amdgcn_mfma_f32_16x16x32_bf16(af, wf8[nt * 64 + l], c0, 0, 0, 0);
    }

    // ---- epilogue: per-32-col chunk LDS transpose -> coalesced bf16 stores ----
    const int rows = min(16, n - base);
    const int orow = tid >> 3, oc = (tid & 7) * 4;
#pragma unroll
    for (int c = 0; c < NCH; c++) {
        __syncthreads();
#pragma unroll
        for (int d = 0; d < 2; d++) {
            int nt = 2 * c + d;
            if (nt >= w * NTA && nt < (w + 1) * NTA) {
                int i = nt - w * NTA;
#pragma unroll
                for (int rr = 0; rr < 4; rr++)
                    lo[(quad * 4 + rr) * OS + d * 16 + ln] = acc[i][rr];
            }
        }
        __syncthreads();
        if (orow < rows) {
            const float* p = &lo[orow * OS + oc];
            // chunk order: z0, [z1,] h  (h last; block owns rows -> in-place OK)
            unsigned short* og = (c == 0) ? z0 : (c == NCH - 1) ? h : z1;
            short4 o;
            o.x = (short)f2bf(p[0]); o.y = (short)f2bf(p[1]);
            o.z = (short)f2bf(p[2]); o.w = (short)f2bf(p[3]);
            *(short4*)(og + (size_t)(base + orow) * H + oc) = o;
        }
    }
}

__global__ __launch_bounds__(128) void pull_tf2_kernel(
    const unsigned* __restrict__ rsbb, const unsigned* __restrict__ ebb, const unsigned short* __restrict__ ybb,
    const unsigned* __restrict__ rsgb, const unsigned* __restrict__ egb, const unsigned short* __restrict__ ygb,
    unsigned short* __restrict__ hb, const unsigned short* __restrict__ Wfb, const float* __restrict__ Bb,
    unsigned short* __restrict__ y2bb, unsigned short* __restrict__ y2bg,
    const unsigned* __restrict__ rsbg, const unsigned* __restrict__ ebg, const unsigned short* __restrict__ ybg,
    unsigned short* __restrict__ hg, const unsigned short* __restrict__ Wfg, const float* __restrict__ Bg,
    unsigned short* __restrict__ y2gb)
{
    __shared__ __align__(16) short lx[16 * 40];
    __shared__ __align__(16) float lo[16 * 34];
    int b = blockIdx.x;
    if (b < NB_PT_BUS)
        pull_tf_body<3, true>(b, N_BUS, rsbb, ebb, ybb, rsgb, egb, ygb,
                              hb, Wfb, Bb, y2bb, y2bg, lx, lo);
    else
        pull_tf_body<2, false>(b - NB_PT_BUS, N_GEN, rsbg, ebg, ybg,
                               nullptr, nullptr, nullptr,
                               hg, Wfg, Bg, y2gb, nullptr, lx, lo);
}

// ---------------------------------------------------------------------------
// Final pull + fused head -> d_out (8 threads/node; bf16 h2 root; no barrier).
__device__ __forceinline__ void pull_head_body(
    int blk, bool hasB, int n,
    const unsigned* __restrict__ rsA, const unsigned* __restrict__ eA, const unsigned short* __restrict__ yA,
    const unsigned* __restrict__ rsB, const unsigned* __restrict__ eB, const unsigned short* __restrict__ yB,
    const unsigned short* __restrict__ h,
    const float* __restrict__ We, const float* __restrict__ be, int DOUT, float* __restrict__ outp)
{
    const int tid = threadIdx.x;
    unsigned node = blk * 32u + (tid >> 3);
    int j = (tid & 7) * 4;
    if (node >= (unsigned)n) return;

    ushort4 rv = *(const ushort4*)(h + (size_t)node * H + j);  // bf16 root
    float4 r = make_float4(bf2f(rv.x), bf2f(rv.y), bf2f(rv.z), bf2f(rv.w));

    agg_one(rsA[node], eA, yA, j, r);
    if (hasB) agg_one(rsB[node], eB, yB, j, r);

    float p0 = fmaxf(r.x, 0.f), p1 = fmaxf(r.y, 0.f), p2 = fmaxf(r.z, 0.f), p3 = fmaxf(r.w, 0.f);
    float tot[4];
#pragma unroll
    for (int c = 0; c < 4; c++) {
        if (c < DOUT) {
            tot[c] = p0 * We[(j + 0) * DOUT + c] + p1 * We[(j + 1) * DOUT + c]
                   + p2 * We[(j + 2) * DOUT + c] + p3 * We[(j + 3) * DOUT + c];
        } else tot[c] = 0.f;
    }
#pragma unroll
    for (int mask = 1; mask <= 4; mask <<= 1) {
#pragma unroll
        for (int c = 0; c < 4; c++) tot[c] += __shfl_xor(tot[c], mask);
    }
    if ((tid & 7) == 0) {
        if (DOUT == 4) {
            *(float4*)(outp + (size_t)node * 4) =
                make_float4(tot[0] + be[0], tot[1] + be[1], tot[2] + be[2], tot[3] + be[3]);
        } else {
            *(float2*)(outp + (size_t)node * 2) = make_float2(tot[0] + be[0], tot[1] + be[1]);
        }
    }
}

__global__ __launch_bounds__(256) void pull_head_kernel(
    const unsigned* __restrict__ rsbb, const unsigned* __restrict__ ebb, const unsigned short* __restrict__ y2bb,
    const unsigned* __restrict__ rsgb, const unsigned* __restrict__ egb, const unsigned short* __restrict__ y2gb,
    const unsigned short* __restrict__ hb, const float* __restrict__ WeB, const float* __restrict__ beB,
    const unsigned* __restrict__ rsbg, const unsigned* __restrict__ ebg, const unsigned short* __restrict__ y2bg,
    const unsigned short* __restrict__ hg, const float* __restrict__ WeG, const float* __restrict__ beG,
    float* __restrict__ outp)
{
    int b = blockIdx.x;
    if (b < NB_PL_BUS)
        pull_head_body(b, true, N_BUS, rsbb, ebb, y2bb, rsgb, egb, y2gb, hb, WeB, beB, 4, outp);
    else
        pull_head_body(b - NB_PL_BUS, false, N_GEN, rsbg, ebg, y2bg, nullptr, nullptr, nullptr,
                       hg, WeG, beG, 2, outp + (size_t)N_BUS * 4);
}

// ---------------------------------------------------------------------------
extern "C" void kernel_launch(void* const* d_in, const int* in_sizes, int n_in,
                              void* d_out, int out_size, void* d_ws, size_t ws_size,
                              hipStream_t stream) {
    const float* x_bus = (const float*)d_in[0];
    const float* x_gen = (const float*)d_in[1];
    const int* src_bb = (const int*)d_in[2];
    const int* dst_bb = (const int*)d_in[3];
    const int* src_gb = (const int*)d_in[4];
    const int* dst_gb = (const int*)d_in[5];
    const int* src_bg = (const int*)d_in[6];
    const int* dst_bg = (const int*)d_in[7];
    const float* l1_bb_Wl = (const float*)d_in[8];
    const float* l1_bb_bl = (const float*)d_in[9];
    const float* l1_bb_Wr = (const float*)d_in[10];
    const float* l1_gb_Wl = (const float*)d_in[11];
    const float* l1_gb_bl = (const float*)d_in[12];
    const float* l1_gb_Wr = (const float*)d_in[13];
    const float* l1_bg_Wl = (const float*)d_in[14];
    const float* l1_bg_bl = (const float*)d_in[15];
    const float* l1_bg_Wr = (const float*)d_in[16];
    const float* l2_bb_Wl = (const float*)d_in[17];
    const float* l2_bb_bl = (const float*)d_in[18];
    const float* l2_bb_Wr = (const float*)d_in[19];
    const float* l2_gb_Wl = (const float*)d_in[20];
    const float* l2_gb_bl = (const float*)d_in[21];
    const float* l2_gb_Wr = (const float*)d_in[22];
    const float* l2_bg_Wl = (const float*)d_in[23];
    const float* l2_bg_bl = (const float*)d_in[24];
    const float* l2_bg_Wr = (const float*)d_in[25];
    const float* lin0_bus_W = (const float*)d_in[26];
    const float* lin0_bus_b = (const float*)d_in[27];
    const float* linf_bus_W = (const float*)d_in[28];
    const float* linf_bus_b = (const float*)d_in[29];
    const float* lin0_gen_W = (const float*)d_in[30];
    const float* lin0_gen_b = (const float*)d_in[31];
    const float* linf_gen_W = (const float*)d_in[32];
    const float* linf_gen_b = (const float*)d_in[33];

    // Workspace layout (~101 MB).
    char* ws = (char*)d_ws;
    size_t off = 0;
    auto alloc = [&](size_t bytes) {
        char* p = ws + off;
        off += (bytes + 255) & ~(size_t)255;
        return p;
    };
    unsigned* rs_bb = (unsigned*)alloc((size_t)N_BUS * 4);
    unsigned* rs_gb = (unsigned*)alloc((size_t)N_BUS * 4);
    unsigned* rs_bg = (unsigned*)alloc((size_t)N_GEN * 4);
    unsigned* cur_bb = (unsigned*)alloc(NBINS * 4);   // three cursor arrays contiguous
    unsigned* cur_gb = (unsigned*)alloc(NBINS * 4);
    unsigned* cur_bg = (unsigned*)alloc(NBINS * 4);
    unsigned* e_bb = (unsigned*)alloc((size_t)NBK_BUS * CAP_BB * 4);
    unsigned* e_gb = (unsigned*)alloc((size_t)NBK_BUS * CAP_GB * 4);
    unsigned* e_bg = (unsigned*)alloc((size_t)NBK_GEN * CAP_BG * 4);
    unsigned* p_bb = (unsigned*)alloc((size_t)NBK_BUS * CAP_BB * 4);
    unsigned* p_gb = (unsigned*)alloc((size_t)NBK_BUS * CAP_GB * 4);
    unsigned* p_bg = (unsigned*)alloc((size_t)NBK_GEN * CAP_BG * 4);
    unsigned short* y_bb = (unsigned short*)alloc((size_t)N_BUS * H * 2);  // bf16
    unsigned short* y_bg = (unsigned short*)alloc((size_t)N_BUS * H * 2);  // bf16
    unsigned short* y_gb = (unsigned short*)alloc((size_t)N_GEN * H * 2);  // bf16
    unsigned short* y2_bb = (unsigned short*)alloc((size_t)N_BUS * H * 2); // layer-2 y
    unsigned short* y2_bg = (unsigned short*)alloc((size_t)N_BUS * H * 2);
    unsigned short* y2_gb = (unsigned short*)alloc((size_t)N_GEN * H * 2);
    unsigned short* h_bus = (unsigned short*)alloc((size_t)N_BUS * H * 2); // bf16 root
    unsigned short* h_gen = (unsigned short*)alloc((size_t)N_GEN * H * 2);
    unsigned short* Wf1b = (unsigned short*)alloc(2 * 6 * 64 * 8 * 2);
    float* B1b = (float*)alloc(96 * 4);
    unsigned short* Wf1g = (unsigned short*)alloc(2 * 4 * 64 * 8 * 2);
    float* B1g = (float*)alloc(64 * 4);
    unsigned short* Wf2b = (unsigned short*)alloc(6 * 64 * 8 * 2);
    float* B2b = (float*)alloc(96 * 4);
    unsigned short* Wf2g = (unsigned short*)alloc(4 * 64 * 8 * 2);
    float* B2g = (float*)alloc(64 * 4);
    float* WeB = (float*)alloc(128 * 4);
    float* beB = (float*)alloc(4 * 4);
    float* WeG = (float*)alloc(64 * 4);
    float* beG = (float*)alloc(2 * 4);

    // L0: zero the three contiguous cursor arrays.
    zero_kernel<<<12, 256, 0, stream>>>(cur_bb);

    // L1: [part | prep].
    prep_part_kernel<<<NB_PART_ALL + NB_PREP, 256, 0, stream>>>(
        src_bb, dst_bb, cur_bb, p_bb, src_gb, dst_gb, cur_gb, p_gb,
        src_bg, dst_bg, cur_bg, p_bg,
        l1_bb_Wl, l1_bb_bl, l1_bb_Wr, l1_gb_Wl, l1_gb_bl, l1_gb_Wr,
        l1_bg_Wl, l1_bg_bl, l1_bg_Wr, l2_bb_Wl, l2_bb_bl, l2_bb_Wr,
        l2_gb_Wl, l2_gb_bl, l2_gb_Wr, l2_bg_Wl, l2_bg_bl, l2_bg_Wr,
        lin0_bus_W, lin0_bus_b, linf_bus_W, linf_bus_b,
        lin0_gen_W, lin0_gen_b, linf_gen_W, linf_gen_b,
        Wf1b, B1b, Wf1g, B1g, Wf2b, B2b, Wf2g, B2g, WeB, beB, WeG, beG);

    // L2: [tf1 (128-row tiles) | fine].
    tf1_fine_kernel<<<NB_TF1_ALL + NB_FINE_ALL, 256, 0, stream>>>(
        x_bus, Wf1b, B1b, y_bb, y_bg, h_bus, x_gen, Wf1g, B1g, y_gb, h_gen,
        cur_bb, p_bb, rs_bb, e_bb, cur_gb, p_gb, rs_gb, e_gb, cur_bg, p_bg, rs_bg, e_bg);

    // L3: FUSED layer-1 pull + layer-2 transform (16-node blocks, 128 threads).
    pull_tf2_kernel<<<NB_PT_BUS + NB_PT_GEN, 128, 0, stream>>>(
        rs_bb, e_bb, y_bb, rs_gb, e_gb, y_gb, h_bus, Wf2b, B2b, y2_bb, y2_bg,
        rs_bg, e_bg, y_bg, h_gen, Wf2g, B2g, y2_gb);

    // L4: layer-2 pull + fused head -> d_out.
    pull_head_kernel<<<NB_PL_BUS + NB_PL_GEN, 256, 0, stream>>>(
        rs_bb, e_bb, y2_bb, rs_gb, e_gb, y2_gb, h_bus, WeB, beB,
        rs_bg, e_bg, y2_bg, h_gen, WeG, beG, (float*)d_out);
}